// Round 3
// baseline (6820.071 us; speedup 1.0000x reference)
//
#include <hip/hip_runtime.h>
#include <math.h>

#define BDIM 256
constexpr int B_ = 4, H_ = 768, W_ = 768;
constexpr int HW_ = H_ * W_;                 // 589824
constexpr int PX = 4;                        // pixels per thread (conv kernels)
constexpr int CBLK = BDIM * PX;              // 1024 px per conv block
constexpr int NCONVBLK = HW_ / CBLK;         // 576
constexpr int IH = H_ + 1, IW = W_ + 1;      // 769

// ---------------------------------------------------------------------------
// Conv 3x3 (dilated, SAME) + bias, NHWC, single sample, 4 px/thread.
// Optionally applies InstanceNorm+ReLU of the PREVIOUS layer to loaded values
// (prevStats[c*2]=mean, [c*2+1]=invstd), so separate norm passes are not
// needed. Writes RAW conv output + per-block partial sums for this layer's
// InstanceNorm.
// ---------------------------------------------------------------------------
template <int CIN, int COUT, int DIL, bool NORM>
__global__ __launch_bounds__(BDIM) void conv_px4(
    const float* __restrict__ in,        // [H][W][CIN] raw prev activations
    const float* __restrict__ prevStats, // [CIN][2] or unused
    const float* __restrict__ wgt,       // [COUT][CIN][3][3]
    const float* __restrict__ bias,      // [COUT]
    float* __restrict__ y,               // [H][W][COUT] raw out
    float* __restrict__ partials)        // [NCONVBLK][2*COUT]
{
    constexpr int NCOL = PX + 2 * DIL;   // tap-column span per thread
    const int pix0 = (blockIdx.x * BDIM + threadIdx.x) * PX;
    const int i = pix0 / W_;
    const int j = pix0 - i * W_;         // multiple of 4; all 4 px same row

    float na[CIN], nb[CIN];
    if constexpr (NORM) {
#pragma unroll
        for (int ci = 0; ci < CIN; ++ci) {
            const float m = prevStats[2 * ci], s = prevStats[2 * ci + 1];
            na[ci] = s; nb[ci] = -m * s;
        }
    }

    float acc[PX][COUT];
#pragma unroll
    for (int p = 0; p < PX; ++p)
#pragma unroll
        for (int co = 0; co < COUT; ++co) acc[p][co] = bias[co];

#pragma unroll
    for (int ky = 0; ky < 3; ++ky) {
        const int r = i + (ky - 1) * DIL;
        if (r < 0 || r >= H_) continue;
        const float* rowp = in + (size_t)r * W_ * CIN;
#pragma unroll
        for (int cf = 0; cf < NCOL; ++cf) {
            const int coff = cf - DIL;   // column offset relative to j
            const int c = j + coff;
            if (c < 0 || c >= W_) continue;
            const float* pp = rowp + (size_t)c * CIN;
            float iv[CIN];
            if constexpr (CIN % 4 == 0) {
#pragma unroll
                for (int q = 0; q < CIN / 4; ++q) {
                    float4 t = reinterpret_cast<const float4*>(pp)[q];
                    iv[4 * q + 0] = t.x; iv[4 * q + 1] = t.y;
                    iv[4 * q + 2] = t.z; iv[4 * q + 3] = t.w;
                }
            } else {
#pragma unroll
                for (int ci = 0; ci < CIN; ++ci) iv[ci] = pp[ci];
            }
            if constexpr (NORM) {
#pragma unroll
                for (int ci = 0; ci < CIN; ++ci)
                    iv[ci] = fmaxf(fmaf(iv[ci], na[ci], nb[ci]), 0.f);
            }
#pragma unroll
            for (int p = 0; p < PX; ++p) {
#pragma unroll
                for (int kx = 0; kx < 3; ++kx) {
                    if ((kx - 1) * DIL + p == coff) {   // constexpr-folded
#pragma unroll
                        for (int ci = 0; ci < CIN; ++ci)
#pragma unroll
                            for (int co = 0; co < COUT; ++co)
                                acc[p][co] = fmaf(iv[ci],
                                    wgt[(co * CIN + ci) * 9 + ky * 3 + kx],
                                    acc[p][co]);
                    }
                }
            }
        }
    }

    float* yp = y + (size_t)pix0 * COUT;
#pragma unroll
    for (int p = 0; p < PX; ++p)
#pragma unroll
        for (int q = 0; q < COUT / 4; ++q) {
            float4 t;
            t.x = acc[p][4 * q]; t.y = acc[p][4 * q + 1];
            t.z = acc[p][4 * q + 2]; t.w = acc[p][4 * q + 3];
            reinterpret_cast<float4*>(yp + p * COUT)[q] = t;
        }

    __shared__ float sred[4][2 * COUT];
    const int lane = threadIdx.x & 63, wave = threadIdx.x >> 6;
#pragma unroll
    for (int co = 0; co < COUT; ++co) {
        float s1 = 0.f, s2 = 0.f;
#pragma unroll
        for (int p = 0; p < PX; ++p) {
            s1 += acc[p][co];
            s2 += acc[p][co] * acc[p][co];
        }
#pragma unroll
        for (int off = 32; off; off >>= 1) {
            s1 += __shfl_xor(s1, off);
            s2 += __shfl_xor(s2, off);
        }
        if (lane == 0) { sred[wave][co] = s1; sred[wave][COUT + co] = s2; }
    }
    __syncthreads();
    if (threadIdx.x < 2 * COUT) {
        float v = sred[0][threadIdx.x] + sred[1][threadIdx.x] +
                  sred[2][threadIdx.x] + sred[3][threadIdx.x];
        partials[(size_t)blockIdx.x * (2 * COUT) + threadIdx.x] = v;
    }
}

// ---------------------------------------------------------------------------
// Reduce per-block partials -> mean, invstd per channel (single sample)
// ---------------------------------------------------------------------------
template <int COUT>
__global__ __launch_bounds__(BDIM) void reduce_stats(
    const float* __restrict__ partials, float* __restrict__ stats)  // [COUT][2]
{
    const int co = blockIdx.x;
    float s1 = 0.f, s2 = 0.f;
    for (int k = threadIdx.x; k < NCONVBLK; k += BDIM) {
        const float* p = partials + (size_t)k * (2 * COUT);
        s1 += p[co];
        s2 += p[COUT + co];
    }
#pragma unroll
    for (int off = 32; off; off >>= 1) {
        s1 += __shfl_xor(s1, off);
        s2 += __shfl_xor(s2, off);
    }
    __shared__ float l1[4], l2[4];
    const int lane = threadIdx.x & 63, wave = threadIdx.x >> 6;
    if (lane == 0) { l1[wave] = s1; l2[wave] = s2; }
    __syncthreads();
    if (threadIdx.x == 0) {
        float t1 = l1[0] + l1[1] + l1[2] + l1[3];
        float t2 = l2[0] + l2[1] + l2[2] + l2[3];
        float m = t1 / (float)HW_;
        float var = t2 / (float)HW_ - m * m;
        stats[co * 2 + 0] = m;
        stats[co * 2 + 1] = rsqrtf(var + 1e-5f);
    }
}

// ---------------------------------------------------------------------------
// conv2 (24->6, dil 1) with folded InstanceNorm+ReLU of layer 5, + channel
// softmax -> f [H][W][6], 4 px/thread.
// ---------------------------------------------------------------------------
__global__ __launch_bounds__(BDIM) void conv2_softmax_px4(
    const float* __restrict__ in, const float* __restrict__ prevStats,
    const float* __restrict__ wgt, const float* __restrict__ bias,
    float* __restrict__ f)
{
    constexpr int CIN = 24, COUT = 6, DIL = 1;
    constexpr int NCOL = PX + 2 * DIL;  // 6
    const int pix0 = (blockIdx.x * BDIM + threadIdx.x) * PX;
    const int i = pix0 / W_;
    const int j = pix0 - i * W_;

    float na[CIN], nb[CIN];
#pragma unroll
    for (int ci = 0; ci < CIN; ++ci) {
        const float m = prevStats[2 * ci], s = prevStats[2 * ci + 1];
        na[ci] = s; nb[ci] = -m * s;
    }

    float acc[PX][COUT];
#pragma unroll
    for (int p = 0; p < PX; ++p)
#pragma unroll
        for (int co = 0; co < COUT; ++co) acc[p][co] = bias[co];

#pragma unroll
    for (int ky = 0; ky < 3; ++ky) {
        const int r = i + (ky - 1);
        if (r < 0 || r >= H_) continue;
        const float* rowp = in + (size_t)r * W_ * CIN;
#pragma unroll
        for (int cf = 0; cf < NCOL; ++cf) {
            const int coff = cf - DIL;
            const int c = j + coff;
            if (c < 0 || c >= W_) continue;
            const float* pp = rowp + (size_t)c * CIN;
            float iv[CIN];
#pragma unroll
            for (int q = 0; q < CIN / 4; ++q) {
                float4 t = reinterpret_cast<const float4*>(pp)[q];
                iv[4 * q + 0] = t.x; iv[4 * q + 1] = t.y;
                iv[4 * q + 2] = t.z; iv[4 * q + 3] = t.w;
            }
#pragma unroll
            for (int ci = 0; ci < CIN; ++ci)
                iv[ci] = fmaxf(fmaf(iv[ci], na[ci], nb[ci]), 0.f);
#pragma unroll
            for (int p = 0; p < PX; ++p) {
#pragma unroll
                for (int kx = 0; kx < 3; ++kx) {
                    if ((kx - 1) + p == coff) {
#pragma unroll
                        for (int ci = 0; ci < CIN; ++ci)
#pragma unroll
                            for (int co = 0; co < COUT; ++co)
                                acc[p][co] = fmaf(iv[ci],
                                    wgt[(co * CIN + ci) * 9 + ky * 3 + kx],
                                    acc[p][co]);
                    }
                }
            }
        }
    }

    float o[PX * COUT];
#pragma unroll
    for (int p = 0; p < PX; ++p) {
        float mx = acc[p][0];
#pragma unroll
        for (int co = 1; co < COUT; ++co) mx = fmaxf(mx, acc[p][co]);
        float e[COUT], s = 0.f;
#pragma unroll
        for (int co = 0; co < COUT; ++co) { e[co] = __expf(acc[p][co] - mx); s += e[co]; }
        const float inv = 1.f / s;
#pragma unroll
        for (int co = 0; co < COUT; ++co) o[p * COUT + co] = e[co] * inv;
    }
    float4* fp4 = reinterpret_cast<float4*>(f + (size_t)pix0 * 6);  // 24 floats contig
#pragma unroll
    for (int q = 0; q < 6; ++q)
        fp4[q] = make_float4(o[4 * q], o[4 * q + 1], o[4 * q + 2], o[4 * q + 3]);
}

// ---------------------------------------------------------------------------
// Integral images of x and x^2 (fp64), single sample.  ii[r][c] = sum x[<r][<c]
// ---------------------------------------------------------------------------
__global__ __launch_bounds__(BDIM) void rowscan(
    const float* __restrict__ x, double* __restrict__ ii1, double* __restrict__ ii2)
{
    const int gwave = (int)((blockIdx.x * (size_t)BDIM + threadIdx.x) >> 6);
    if (gwave >= IH) return;
    const int lane = threadIdx.x & 63;
    const int r = gwave;
    double* r1 = ii1 + (size_t)r * IW;
    double* r2 = ii2 + (size_t)r * IW;
    if (r == 0) {
        for (int j = lane; j < IW; j += 64) { r1[j] = 0.0; r2[j] = 0.0; }
        return;
    }
    const float* xr = x + (size_t)(r - 1) * W_;
    if (lane == 0) { r1[0] = 0.0; r2[0] = 0.0; }
    double c1 = 0.0, c2 = 0.0;
    for (int seg = 0; seg < W_ / 64; ++seg) {
        const float xv = xr[seg * 64 + lane];
        double v1 = (double)xv, v2 = (double)xv * (double)xv;
#pragma unroll
        for (int d = 1; d < 64; d <<= 1) {
            double t1 = __shfl_up(v1, d);
            double t2 = __shfl_up(v2, d);
            if (lane >= d) { v1 += t1; v2 += t2; }
        }
        v1 += c1; v2 += c2;
        r1[seg * 64 + lane + 1] = v1;
        r2[seg * 64 + lane + 1] = v2;
        c1 = __shfl(v1, 63);
        c2 = __shfl(v2, 63);
    }
}

__global__ __launch_bounds__(BDIM) void colscan(
    double* __restrict__ ii1, double* __restrict__ ii2)
{
    const int t = blockIdx.x * BDIM + threadIdx.x;
    if (t >= 2 * IW) return;
    const int which = t / IW;
    const int j = t - which * IW;
    double* p = which ? ii2 : ii1;
    double acc = p[(size_t)1 * IW + j];
    for (int i = 2; i <= H_; ++i) {
        acc += p[(size_t)i * IW + j];
        p[(size_t)i * IW + j] = acc;
    }
}

// ---------------------------------------------------------------------------
// Final: 6 Sauvola thresholds, softmax-weighted sum, out = (x - th1)*alpha
// ---------------------------------------------------------------------------
__global__ __launch_bounds__(BDIM) void sauvola_out(
    const float* __restrict__ x, const float* __restrict__ f,
    const double* __restrict__ ii1, const double* __restrict__ ii2,
    const float* __restrict__ kArr, const float* __restrict__ RArr,
    const float* __restrict__ alphaP, float* __restrict__ outp)
{
    const int pix = blockIdx.x * BDIM + threadIdx.x;  // [0, HW)
    const int i = pix / W_, j = pix - i * W_;
    const float xv = x[pix];
    const float* fp = f + (size_t)pix * 6;
    const float alpha = alphaP[0];

    const int wins[6] = {3, 5, 7, 11, 15, 19};
    float th1 = 0.f;
#pragma unroll
    for (int wi = 0; wi < 6; ++wi) {
        const int r = wins[wi] >> 1;
        const int r0 = max(i - r, 0), r1i = min(i + r, H_ - 1);
        const int c0 = max(j - r, 0), c1 = min(j + r, W_ - 1);
        const float cnt = (float)((r1i - r0 + 1) * (c1 - c0 + 1));
        const double* rt1 = ii1 + (size_t)r0 * IW;
        const double* rb1 = ii1 + (size_t)(r1i + 1) * IW;
        const double* rt2 = ii2 + (size_t)r0 * IW;
        const double* rb2 = ii2 + (size_t)(r1i + 1) * IW;
        const double s1 = rb1[c1 + 1] - rt1[c1 + 1] - rb1[c0] + rt1[c0];
        const double s2 = rb2[c1 + 1] - rt2[c1 + 1] - rb2[c0] + rt2[c0];
        const float invc = 1.f / cnt;
        const float Ex = (float)s1 * invc;
        const float Ex2 = (float)s2 * invc;
        const float dev = sqrtf(fmaxf(Ex2 - Ex * Ex, 1e-6f));
        const float th = Ex * (1.f + kArr[wi] * (dev / RArr[wi] - 1.f));
        th1 = fmaf(fp[wi], th, th1);
    }
    outp[pix] = (xv - th1) * alpha;
}

// ---------------------------------------------------------------------------
extern "C" void kernel_launch(void* const* d_in, const int* in_sizes, int n_in,
                              void* d_out, int out_size, void* d_ws, size_t ws_size,
                              hipStream_t stream) {
    const float* x   = (const float*)d_in[0];
    const float* w0  = (const float*)d_in[1];  const float* b0 = (const float*)d_in[2];
    const float* w1  = (const float*)d_in[3];  const float* b1 = (const float*)d_in[4];
    const float* w2  = (const float*)d_in[5];  const float* b2 = (const float*)d_in[6];
    const float* w3  = (const float*)d_in[7];  const float* b3 = (const float*)d_in[8];
    const float* w4  = (const float*)d_in[9];  const float* b4 = (const float*)d_in[10];
    const float* w5  = (const float*)d_in[11]; const float* b5 = (const float*)d_in[12];
    const float* wf  = (const float*)d_in[13]; const float* bf = (const float*)d_in[14];
    const float* kA  = (const float*)d_in[15];
    const float* RA  = (const float*)d_in[16];
    const float* alp = (const float*)d_in[17];
    float* out = (float*)d_out;
    (void)ws_size; (void)n_in; (void)in_sizes; (void)out_size;

    // -------- single-sample workspace (≈104.8 MB total) --------
    char* ws = (char*)d_ws;
    size_t off = 0;
    auto alloc = [&](size_t bytes) -> void* {
        void* p = ws + off;
        off += (bytes + 255) & ~(size_t)255;
        return p;
    };
    float* bufA     = (float*)alloc((size_t)HW_ * 20 * sizeof(float)); // C=4,12,20
    float* bufB     = (float*)alloc((size_t)HW_ * 24 * sizeof(float)); // C=8,16,24
    float* partials = (float*)alloc((size_t)NCONVBLK * 48 * sizeof(float));
    float* stats    = (float*)alloc(48 * sizeof(float));
    // fbuf + integral images alias the dead bufA region after the last conv:
    float*  fbuf = bufA;                                               // 14.2 MB
    double* ii1  = (double*)((char*)bufA + 14155776);                  // 4.73 MB
    double* ii2  = (double*)((char*)bufA + 14155776 + 4731136);        // 4.73 MB

    const dim3 blk(BDIM);

    for (int b = 0; b < B_; ++b) {
        const float* xb   = x   + (size_t)b * HW_;
        float*       outb = out + (size_t)b * HW_;

        conv_px4<1, 4, 1, false><<<NCONVBLK, blk, 0, stream>>>(xb, nullptr, w0, b0, bufA, partials);
        reduce_stats<4><<<4, blk, 0, stream>>>(partials, stats);

        conv_px4<4, 8, 2, true><<<NCONVBLK, blk, 0, stream>>>(bufA, stats, w1, b1, bufB, partials);
        reduce_stats<8><<<8, blk, 0, stream>>>(partials, stats);

        conv_px4<8, 12, 2, true><<<NCONVBLK, blk, 0, stream>>>(bufB, stats, w2, b2, bufA, partials);
        reduce_stats<12><<<12, blk, 0, stream>>>(partials, stats);

        conv_px4<12, 16, 2, true><<<NCONVBLK, blk, 0, stream>>>(bufA, stats, w3, b3, bufB, partials);
        reduce_stats<16><<<16, blk, 0, stream>>>(partials, stats);

        conv_px4<16, 20, 2, true><<<NCONVBLK, blk, 0, stream>>>(bufB, stats, w4, b4, bufA, partials);
        reduce_stats<20><<<20, blk, 0, stream>>>(partials, stats);

        conv_px4<20, 24, 2, true><<<NCONVBLK, blk, 0, stream>>>(bufA, stats, w5, b5, bufB, partials);
        reduce_stats<24><<<24, blk, 0, stream>>>(partials, stats);

        // bufA region is now dead -> fbuf / ii1 / ii2 alias into it
        conv2_softmax_px4<<<NCONVBLK, blk, 0, stream>>>(bufB, stats, wf, bf, fbuf);

        rowscan<<<(IH * 64 + BDIM - 1) / BDIM, blk, 0, stream>>>(xb, ii1, ii2);
        colscan<<<(2 * IW + BDIM - 1) / BDIM, blk, 0, stream>>>(ii1, ii2);

        sauvola_out<<<HW_ / BDIM, blk, 0, stream>>>(xb, fbuf, ii1, ii2, kA, RA, alp, outb);
    }
}

// Round 4
// 1687.769 us; speedup vs baseline: 4.0409x; 4.0409x over previous
//
#include <hip/hip_runtime.h>
#include <math.h>

#define BDIM 256
constexpr int B_ = 4, H_ = 768, W_ = 768;
constexpr int HW_ = H_ * W_;                 // 589824
constexpr int TS = 16;                       // conv tile side (16x16 px/block)
constexpr int NTB = W_ / TS;                 // 48 tiles per row
constexpr int NBLK = HW_ / (TS * TS);        // 2304 conv blocks
constexpr int IH = H_ + 1, IW = W_ + 1;      // 769

// ---------------------------------------------------------------------------
// Weight repack: [COUT][CIN][3][3] -> [CIN][9][COUT]  (one tiny block)
// ---------------------------------------------------------------------------
template <int CIN, int COUT>
__global__ __launch_bounds__(BDIM) void repack_w(
    const float* __restrict__ src, float* __restrict__ dst)
{
    const int n = CIN * COUT * 9;
    for (int idx = threadIdx.x; idx < n; idx += BDIM) {
        const int co = idx / (CIN * 9);
        const int r = idx - co * (CIN * 9);
        const int ci = r / 9, k = r - ci * 9;
        dst[(ci * 9 + k) * COUT + co] = src[idx];
    }
}

// ---------------------------------------------------------------------------
// LDS-staged conv 3x3 (dilated, SAME) + bias, NHWC, single sample.
// 16x16 tile per block, 1 px/thread. Previous layer's InstanceNorm+ReLU is
// applied while staging into LDS (OOB staged as exact 0 = pad-after-norm).
// Emits raw conv out + per-block partial sums for this layer's InstanceNorm.
// ---------------------------------------------------------------------------
template <int CIN, int COUT, int DIL, bool NORM>
__global__ __launch_bounds__(BDIM) void conv_tile(
    const float* __restrict__ in,        // [H][W][CIN] raw prev activations
    const float* __restrict__ prevStats, // [CIN][2] (mean, invstd) or unused
    const float* __restrict__ w2,        // [CIN][9][COUT] repacked
    const float* __restrict__ bias,      // [COUT]
    float* __restrict__ y,               // [H][W][COUT] raw out
    float* __restrict__ partials)        // [NBLK][2*COUT]
{
    constexpr int TW = TS + 2 * DIL;     // staged tile side (18 or 20)
    constexpr int RS = 24;               // LDS row stride -> 2 lanes/bank reads
    constexpr int PLANE = RS * TW;
    __shared__ float tile[CIN * PLANE];
    __shared__ float sred[4][2 * COUT];

    const int blk = blockIdx.x;
    const int ti = blk / NTB, tj = blk - ti * NTB;
    const int i0 = ti * TS - DIL, j0 = tj * TS - DIL;  // staged-region origin
    const int t = threadIdx.x;

    // ---- stage TWxTW x CIN (normalized) into LDS ----
    for (int loc = t; loc < TW * TW; loc += BDIM) {
        const int rr = loc / TW, cc = loc - rr * TW;
        const int gi = i0 + rr, gj = j0 + cc;
        const bool ok = (gi >= 0) & (gi < H_) & (gj >= 0) & (gj < W_);
        const float* gp = in + ((size_t)gi * W_ + gj) * CIN;
        float* lp = tile + rr * RS + cc;
        if constexpr (CIN % 4 == 0) {
#pragma unroll
            for (int q = 0; q < CIN / 4; ++q) {
                float vv[4] = {0.f, 0.f, 0.f, 0.f};
                if (ok) {
                    const float4 raw = reinterpret_cast<const float4*>(gp)[q];
                    vv[0] = raw.x; vv[1] = raw.y; vv[2] = raw.z; vv[3] = raw.w;
                    if constexpr (NORM) {
#pragma unroll
                        for (int u = 0; u < 4; ++u) {
                            const int ci = 4 * q + u;
                            vv[u] = fmaxf((vv[u] - prevStats[2 * ci]) *
                                          prevStats[2 * ci + 1], 0.f);
                        }
                    }
                }
#pragma unroll
                for (int u = 0; u < 4; ++u)
                    lp[(4 * q + u) * PLANE] = vv[u];
            }
        } else {  // CIN == 1 (first layer, no norm)
            float v = 0.f;
            if (ok) v = gp[0];
            lp[0] = v;
        }
    }
    __syncthreads();

    // ---- compute: 1 px/thread, all COUT channels ----
    const int tx = t & (TS - 1), ty = t >> 4;   // TS == 16
    float acc[COUT];
#pragma unroll
    for (int co = 0; co < COUT; ++co) acc[co] = bias[co];

#pragma unroll 2
    for (int ci = 0; ci < CIN; ++ci) {
        const float* pl = tile + ci * PLANE + ty * RS + tx;
        float v[9];
#pragma unroll
        for (int ky = 0; ky < 3; ++ky)
#pragma unroll
            for (int kx = 0; kx < 3; ++kx)
                v[ky * 3 + kx] = pl[(ky * DIL) * RS + kx * DIL];
        const float* wp = w2 + (size_t)ci * 9 * COUT;
#pragma unroll
        for (int k = 0; k < 9; ++k)
#pragma unroll
            for (int co = 0; co < COUT; ++co)
                acc[co] = fmaf(v[k], wp[k * COUT + co], acc[co]);
    }

    // ---- write raw out ----
    const int oi = ti * TS + ty, oj = tj * TS + tx;
    float* yp = y + ((size_t)oi * W_ + oj) * COUT;
#pragma unroll
    for (int q = 0; q < COUT / 4; ++q) {
        float4 o;
        o.x = acc[4 * q]; o.y = acc[4 * q + 1];
        o.z = acc[4 * q + 2]; o.w = acc[4 * q + 3];
        reinterpret_cast<float4*>(yp)[q] = o;
    }

    // ---- per-block partial sums for this layer's InstanceNorm ----
    const int lane = t & 63, wave = t >> 6;
#pragma unroll
    for (int co = 0; co < COUT; ++co) {
        float s1 = acc[co], s2 = acc[co] * acc[co];
#pragma unroll
        for (int off = 32; off; off >>= 1) {
            s1 += __shfl_xor(s1, off);
            s2 += __shfl_xor(s2, off);
        }
        if (lane == 0) { sred[wave][co] = s1; sred[wave][COUT + co] = s2; }
    }
    __syncthreads();
    if (t < 2 * COUT) {
        float v = sred[0][t] + sred[1][t] + sred[2][t] + sred[3][t];
        partials[(size_t)blk * (2 * COUT) + t] = v;
    }
}

// ---------------------------------------------------------------------------
// Reduce per-block partials -> mean, invstd per channel (single sample)
// ---------------------------------------------------------------------------
template <int COUT>
__global__ __launch_bounds__(BDIM) void reduce_stats(
    const float* __restrict__ partials, float* __restrict__ stats)  // [COUT][2]
{
    const int co = blockIdx.x;
    float s1 = 0.f, s2 = 0.f;
    for (int k = threadIdx.x; k < NBLK; k += BDIM) {
        const float* p = partials + (size_t)k * (2 * COUT);
        s1 += p[co];
        s2 += p[COUT + co];
    }
#pragma unroll
    for (int off = 32; off; off >>= 1) {
        s1 += __shfl_xor(s1, off);
        s2 += __shfl_xor(s2, off);
    }
    __shared__ float l1[4], l2[4];
    const int lane = threadIdx.x & 63, wave = threadIdx.x >> 6;
    if (lane == 0) { l1[wave] = s1; l2[wave] = s2; }
    __syncthreads();
    if (threadIdx.x == 0) {
        float t1 = l1[0] + l1[1] + l1[2] + l1[3];
        float t2 = l2[0] + l2[1] + l2[2] + l2[3];
        float m = t1 / (float)HW_;
        float var = t2 / (float)HW_ - m * m;
        stats[co * 2 + 0] = m;
        stats[co * 2 + 1] = rsqrtf(var + 1e-5f);
    }
}

// ---------------------------------------------------------------------------
// conv2 (24->6, dil 1) with folded InstanceNorm+ReLU of layer 5, + channel
// softmax -> f [H][W][6]. Same LDS tiling.
// ---------------------------------------------------------------------------
__global__ __launch_bounds__(BDIM) void conv2_softmax_tile(
    const float* __restrict__ in, const float* __restrict__ prevStats,
    const float* __restrict__ w2, const float* __restrict__ bias,
    float* __restrict__ f)
{
    constexpr int CIN = 24, COUT = 6, DIL = 1;
    constexpr int TW = TS + 2 * DIL;     // 18
    constexpr int RS = 24;
    constexpr int PLANE = RS * TW;
    __shared__ float tile[CIN * PLANE];

    const int blk = blockIdx.x;
    const int ti = blk / NTB, tj = blk - ti * NTB;
    const int i0 = ti * TS - DIL, j0 = tj * TS - DIL;
    const int t = threadIdx.x;

    for (int loc = t; loc < TW * TW; loc += BDIM) {
        const int rr = loc / TW, cc = loc - rr * TW;
        const int gi = i0 + rr, gj = j0 + cc;
        const bool ok = (gi >= 0) & (gi < H_) & (gj >= 0) & (gj < W_);
        const float* gp = in + ((size_t)gi * W_ + gj) * CIN;
        float* lp = tile + rr * RS + cc;
#pragma unroll
        for (int q = 0; q < CIN / 4; ++q) {
            float vv[4] = {0.f, 0.f, 0.f, 0.f};
            if (ok) {
                const float4 raw = reinterpret_cast<const float4*>(gp)[q];
                vv[0] = raw.x; vv[1] = raw.y; vv[2] = raw.z; vv[3] = raw.w;
#pragma unroll
                for (int u = 0; u < 4; ++u) {
                    const int ci = 4 * q + u;
                    vv[u] = fmaxf((vv[u] - prevStats[2 * ci]) *
                                  prevStats[2 * ci + 1], 0.f);
                }
            }
#pragma unroll
            for (int u = 0; u < 4; ++u)
                lp[(4 * q + u) * PLANE] = vv[u];
        }
    }
    __syncthreads();

    const int tx = t & (TS - 1), ty = t >> 4;
    float acc[COUT];
#pragma unroll
    for (int co = 0; co < COUT; ++co) acc[co] = bias[co];

#pragma unroll 2
    for (int ci = 0; ci < CIN; ++ci) {
        const float* pl = tile + ci * PLANE + ty * RS + tx;
        float v[9];
#pragma unroll
        for (int ky = 0; ky < 3; ++ky)
#pragma unroll
            for (int kx = 0; kx < 3; ++kx)
                v[ky * 3 + kx] = pl[ky * RS + kx];
        const float* wp = w2 + (size_t)ci * 9 * COUT;
#pragma unroll
        for (int k = 0; k < 9; ++k)
#pragma unroll
            for (int co = 0; co < COUT; ++co)
                acc[co] = fmaf(v[k], wp[k * COUT + co], acc[co]);
    }

    float mx = acc[0];
#pragma unroll
    for (int co = 1; co < COUT; ++co) mx = fmaxf(mx, acc[co]);
    float e[COUT], s = 0.f;
#pragma unroll
    for (int co = 0; co < COUT; ++co) { e[co] = __expf(acc[co] - mx); s += e[co]; }
    const float inv = 1.f / s;

    const int oi = ti * TS + ty, oj = tj * TS + tx;
    float2* fp2 = reinterpret_cast<float2*>(f + ((size_t)oi * W_ + oj) * 6);
    fp2[0] = make_float2(e[0] * inv, e[1] * inv);
    fp2[1] = make_float2(e[2] * inv, e[3] * inv);
    fp2[2] = make_float2(e[4] * inv, e[5] * inv);
}

// ---------------------------------------------------------------------------
// Integral images of x and x^2 (fp64), single sample.  ii[r][c] = sum x[<r][<c]
// ---------------------------------------------------------------------------
__global__ __launch_bounds__(BDIM) void rowscan(
    const float* __restrict__ x, double* __restrict__ ii1, double* __restrict__ ii2)
{
    const int gwave = (int)((blockIdx.x * (size_t)BDIM + threadIdx.x) >> 6);
    if (gwave >= IH) return;
    const int lane = threadIdx.x & 63;
    const int r = gwave;
    double* r1 = ii1 + (size_t)r * IW;
    double* r2 = ii2 + (size_t)r * IW;
    if (r == 0) {
        for (int j = lane; j < IW; j += 64) { r1[j] = 0.0; r2[j] = 0.0; }
        return;
    }
    const float* xr = x + (size_t)(r - 1) * W_;
    if (lane == 0) { r1[0] = 0.0; r2[0] = 0.0; }
    double c1 = 0.0, c2 = 0.0;
    for (int seg = 0; seg < W_ / 64; ++seg) {
        const float xv = xr[seg * 64 + lane];
        double v1 = (double)xv, v2 = (double)xv * (double)xv;
#pragma unroll
        for (int d = 1; d < 64; d <<= 1) {
            double t1 = __shfl_up(v1, d);
            double t2 = __shfl_up(v2, d);
            if (lane >= d) { v1 += t1; v2 += t2; }
        }
        v1 += c1; v2 += c2;
        r1[seg * 64 + lane + 1] = v1;
        r2[seg * 64 + lane + 1] = v2;
        c1 = __shfl(v1, 63);
        c2 = __shfl(v2, 63);
    }
}

__global__ __launch_bounds__(BDIM) void colscan(
    double* __restrict__ ii1, double* __restrict__ ii2)
{
    const int t = blockIdx.x * BDIM + threadIdx.x;
    if (t >= 2 * IW) return;
    const int which = t / IW;
    const int j = t - which * IW;
    double* p = which ? ii2 : ii1;
    double acc = p[(size_t)1 * IW + j];
    for (int i = 2; i <= H_; ++i) {
        acc += p[(size_t)i * IW + j];
        p[(size_t)i * IW + j] = acc;
    }
}

// ---------------------------------------------------------------------------
// Final: 6 Sauvola thresholds, softmax-weighted sum, out = (x - th1)*alpha
// ---------------------------------------------------------------------------
__global__ __launch_bounds__(BDIM) void sauvola_out(
    const float* __restrict__ x, const float* __restrict__ f,
    const double* __restrict__ ii1, const double* __restrict__ ii2,
    const float* __restrict__ kArr, const float* __restrict__ RArr,
    const float* __restrict__ alphaP, float* __restrict__ outp)
{
    const int pix = blockIdx.x * BDIM + threadIdx.x;  // [0, HW)
    const int i = pix / W_, j = pix - i * W_;
    const float xv = x[pix];
    const float* fp = f + (size_t)pix * 6;
    const float alpha = alphaP[0];

    const int wins[6] = {3, 5, 7, 11, 15, 19};
    float th1 = 0.f;
#pragma unroll
    for (int wi = 0; wi < 6; ++wi) {
        const int r = wins[wi] >> 1;
        const int r0 = max(i - r, 0), r1i = min(i + r, H_ - 1);
        const int c0 = max(j - r, 0), c1 = min(j + r, W_ - 1);
        const float cnt = (float)((r1i - r0 + 1) * (c1 - c0 + 1));
        const double* rt1 = ii1 + (size_t)r0 * IW;
        const double* rb1 = ii1 + (size_t)(r1i + 1) * IW;
        const double* rt2 = ii2 + (size_t)r0 * IW;
        const double* rb2 = ii2 + (size_t)(r1i + 1) * IW;
        const double s1 = rb1[c1 + 1] - rt1[c1 + 1] - rb1[c0] + rt1[c0];
        const double s2 = rb2[c1 + 1] - rt2[c1 + 1] - rb2[c0] + rt2[c0];
        const float invc = 1.f / cnt;
        const float Ex = (float)s1 * invc;
        const float Ex2 = (float)s2 * invc;
        const float dev = sqrtf(fmaxf(Ex2 - Ex * Ex, 1e-6f));
        const float th = Ex * (1.f + kArr[wi] * (dev / RArr[wi] - 1.f));
        th1 = fmaf(fp[wi], th, th1);
    }
    outp[pix] = (xv - th1) * alpha;
}

// ---------------------------------------------------------------------------
extern "C" void kernel_launch(void* const* d_in, const int* in_sizes, int n_in,
                              void* d_out, int out_size, void* d_ws, size_t ws_size,
                              hipStream_t stream) {
    const float* x   = (const float*)d_in[0];
    const float* w0  = (const float*)d_in[1];  const float* b0 = (const float*)d_in[2];
    const float* w1  = (const float*)d_in[3];  const float* b1 = (const float*)d_in[4];
    const float* w2  = (const float*)d_in[5];  const float* b2 = (const float*)d_in[6];
    const float* w3  = (const float*)d_in[7];  const float* b3 = (const float*)d_in[8];
    const float* w4  = (const float*)d_in[9];  const float* b4 = (const float*)d_in[10];
    const float* w5  = (const float*)d_in[11]; const float* b5 = (const float*)d_in[12];
    const float* wf  = (const float*)d_in[13]; const float* bf = (const float*)d_in[14];
    const float* kA  = (const float*)d_in[15];
    const float* RA  = (const float*)d_in[16];
    const float* alp = (const float*)d_in[17];
    float* out = (float*)d_out;
    (void)ws_size; (void)n_in; (void)in_sizes; (void)out_size;

    // -------- single-sample workspace (≈105 MB total) --------
    char* ws = (char*)d_ws;
    size_t off = 0;
    auto alloc = [&](size_t bytes) -> void* {
        void* p = ws + off;
        off += (bytes + 255) & ~(size_t)255;
        return p;
    };
    float* bufA     = (float*)alloc((size_t)HW_ * 20 * sizeof(float)); // C=4,12,20
    float* bufB     = (float*)alloc((size_t)HW_ * 24 * sizeof(float)); // C=8,16,24
    float* partials = (float*)alloc((size_t)NBLK * 48 * sizeof(float));
    float* stats    = (float*)alloc(48 * sizeof(float));
    // repacked weights [CIN][9][COUT]
    float* r0 = (float*)alloc(1  * 9 * 4  * sizeof(float));
    float* r1 = (float*)alloc(4  * 9 * 8  * sizeof(float));
    float* r2 = (float*)alloc(8  * 9 * 12 * sizeof(float));
    float* r3 = (float*)alloc(12 * 9 * 16 * sizeof(float));
    float* r4 = (float*)alloc(16 * 9 * 20 * sizeof(float));
    float* r5 = (float*)alloc(20 * 9 * 24 * sizeof(float));
    float* rf = (float*)alloc(24 * 9 * 6  * sizeof(float));
    // fbuf + integral images alias the dead bufA region after the last conv:
    float*  fbuf = bufA;                                               // 14.2 MB
    double* ii1  = (double*)((char*)bufA + 14155776);                  // 4.73 MB
    double* ii2  = (double*)((char*)bufA + 14155776 + 4731136);        // 4.73 MB

    const dim3 blk(BDIM);

    // weight repacks (once per call, before the batch loop)
    repack_w<1,  4 ><<<1, blk, 0, stream>>>(w0, r0);
    repack_w<4,  8 ><<<1, blk, 0, stream>>>(w1, r1);
    repack_w<8,  12><<<1, blk, 0, stream>>>(w2, r2);
    repack_w<12, 16><<<1, blk, 0, stream>>>(w3, r3);
    repack_w<16, 20><<<1, blk, 0, stream>>>(w4, r4);
    repack_w<20, 24><<<1, blk, 0, stream>>>(w5, r5);
    repack_w<24, 6 ><<<1, blk, 0, stream>>>(wf, rf);

    for (int b = 0; b < B_; ++b) {
        const float* xb   = x   + (size_t)b * HW_;
        float*       outb = out + (size_t)b * HW_;

        conv_tile<1, 4, 1, false><<<NBLK, blk, 0, stream>>>(xb, nullptr, r0, b0, bufA, partials);
        reduce_stats<4><<<4, blk, 0, stream>>>(partials, stats);

        conv_tile<4, 8, 2, true><<<NBLK, blk, 0, stream>>>(bufA, stats, r1, b1, bufB, partials);
        reduce_stats<8><<<8, blk, 0, stream>>>(partials, stats);

        conv_tile<8, 12, 2, true><<<NBLK, blk, 0, stream>>>(bufB, stats, r2, b2, bufA, partials);
        reduce_stats<12><<<12, blk, 0, stream>>>(partials, stats);

        conv_tile<12, 16, 2, true><<<NBLK, blk, 0, stream>>>(bufA, stats, r3, b3, bufB, partials);
        reduce_stats<16><<<16, blk, 0, stream>>>(partials, stats);

        conv_tile<16, 20, 2, true><<<NBLK, blk, 0, stream>>>(bufB, stats, r4, b4, bufA, partials);
        reduce_stats<20><<<20, blk, 0, stream>>>(partials, stats);

        conv_tile<20, 24, 2, true><<<NBLK, blk, 0, stream>>>(bufA, stats, r5, b5, bufB, partials);
        reduce_stats<24><<<24, blk, 0, stream>>>(partials, stats);

        // bufA region is now dead -> fbuf / ii1 / ii2 alias into it
        conv2_softmax_tile<<<NBLK, blk, 0, stream>>>(bufB, stats, rf, bf, fbuf);

        rowscan<<<(IH * 64 + BDIM - 1) / BDIM, blk, 0, stream>>>(xb, ii1, ii2);
        colscan<<<(2 * IW + BDIM - 1) / BDIM, blk, 0, stream>>>(ii1, ii2);

        sauvola_out<<<HW_ / BDIM, blk, 0, stream>>>(xb, fbuf, ii1, ii2, kA, RA, alp, outb);
    }
}

// Round 5
// 1267.618 us; speedup vs baseline: 5.3802x; 1.3314x over previous
//
#include <hip/hip_runtime.h>
#include <math.h>

#define BDIM 256
constexpr int B_ = 4, H_ = 768, W_ = 768;
constexpr int HW_ = H_ * W_;                 // 589824
constexpr int TS = 16;                       // conv tile side (16x16 px/block)
constexpr int NTB = W_ / TS;                 // 48 tiles per row
constexpr int NBLK = HW_ / (TS * TS);        // 2304 conv blocks per sample
constexpr int IH = H_ + 1, IW = W_ + 1;      // 769

// bufA per-sample region (20ch fp32) reused for fbuf + integral images:
constexpr size_t SA_BYTES = (size_t)HW_ * 20 * 4;        // 47185920
constexpr size_t OFF_II1  = (size_t)HW_ * 6 * 4;         // 14155776 (after fbuf)
constexpr size_t II_SPAN  = 4731136;                     // 769*769*8 rounded to 256
constexpr size_t OFF_II2  = OFF_II1 + II_SPAN;           // 18886912 (< SA_BYTES)

// ---------------------------------------------------------------------------
// Weight repack: [COUT][CIN][3][3] -> [CIN][9][COUT]; all 7 tensors in one
// launch (block b handles tensor b).
// ---------------------------------------------------------------------------
__device__ void repack_one(const float* __restrict__ src, float* __restrict__ dst,
                           int CIN, int COUT)
{
    const int n = CIN * COUT * 9;
    for (int idx = threadIdx.x; idx < n; idx += BDIM) {
        const int co = idx / (CIN * 9);
        const int r = idx - co * (CIN * 9);
        const int ci = r / 9, k = r - ci * 9;
        dst[(ci * 9 + k) * COUT + co] = src[idx];
    }
}

__global__ __launch_bounds__(BDIM) void repack_all(
    const float* w0, const float* w1, const float* w2, const float* w3,
    const float* w4, const float* w5, const float* wf,
    float* r0, float* r1, float* r2, float* r3, float* r4, float* r5, float* rf)
{
    switch (blockIdx.x) {
        case 0: repack_one(w0, r0, 1, 4);   break;
        case 1: repack_one(w1, r1, 4, 8);   break;
        case 2: repack_one(w2, r2, 8, 12);  break;
        case 3: repack_one(w3, r3, 12, 16); break;
        case 4: repack_one(w4, r4, 16, 20); break;
        case 5: repack_one(w5, r5, 20, 24); break;
        case 6: repack_one(wf, rf, 24, 6);  break;
    }
}

// ---------------------------------------------------------------------------
// LDS-staged conv 3x3 (dilated, SAME) + bias, NHWC, nb samples per launch
// (grid = nb*NBLK). 16x16 tile per block, 1 px/thread. Previous layer's
// InstanceNorm+ReLU applied while staging (OOB staged as 0 = pad-after-norm).
// Emits raw conv out + per-(sample,block) partial sums for InstanceNorm.
// ---------------------------------------------------------------------------
template <int CIN, int COUT, int DIL, bool NORM>
__global__ __launch_bounds__(BDIM) void conv_tile(
    const float* __restrict__ in,        // [nb][H][W][CIN] raw prev activations
    const float* __restrict__ prevStats, // [nb][CIN][2] (mean, invstd) or unused
    const float* __restrict__ w2,        // [CIN][9][COUT] repacked
    const float* __restrict__ bias,      // [COUT]
    float* __restrict__ y,               // [nb][H][W][COUT] raw out
    float* __restrict__ partials)        // [nb][NBLK][2*COUT]
{
    constexpr int TW = TS + 2 * DIL;     // staged tile side (18 or 20)
    constexpr int RS = 24;               // LDS row stride -> uniform 2 lanes/bank
    constexpr int PLANE = RS * TW;
    __shared__ float tile[CIN * PLANE];
    __shared__ float sred[4][2 * COUT];

    const int s = blockIdx.x / NBLK;
    const int blk = blockIdx.x - s * NBLK;
    const float* inS = in + (size_t)s * HW_ * CIN;
    const int ti = blk / NTB, tj = blk - ti * NTB;
    const int i0 = ti * TS - DIL, j0 = tj * TS - DIL;
    const int t = threadIdx.x;

    // ---- stage TWxTW x CIN (normalized) into LDS ----
    for (int loc = t; loc < TW * TW; loc += BDIM) {
        const int rr = loc / TW, cc = loc - rr * TW;
        const int gi = i0 + rr, gj = j0 + cc;
        const bool ok = (gi >= 0) & (gi < H_) & (gj >= 0) & (gj < W_);
        const float* gp = inS + ((size_t)gi * W_ + gj) * CIN;
        float* lp = tile + rr * RS + cc;
        if constexpr (CIN % 4 == 0) {
#pragma unroll
            for (int q = 0; q < CIN / 4; ++q) {
                float vv[4] = {0.f, 0.f, 0.f, 0.f};
                if (ok) {
                    const float4 raw = reinterpret_cast<const float4*>(gp)[q];
                    vv[0] = raw.x; vv[1] = raw.y; vv[2] = raw.z; vv[3] = raw.w;
                    if constexpr (NORM) {
                        const float* ps = prevStats + (size_t)s * 2 * CIN;
#pragma unroll
                        for (int u = 0; u < 4; ++u) {
                            const int ci = 4 * q + u;
                            vv[u] = fmaxf((vv[u] - ps[2 * ci]) * ps[2 * ci + 1], 0.f);
                        }
                    }
                }
#pragma unroll
                for (int u = 0; u < 4; ++u)
                    lp[(4 * q + u) * PLANE] = vv[u];
            }
        } else {  // CIN == 1 (first layer, no norm)
            float v = 0.f;
            if (ok) v = gp[0];
            lp[0] = v;
        }
    }
    __syncthreads();

    // ---- compute: 1 px/thread, all COUT channels ----
    const int tx = t & (TS - 1), ty = t >> 4;
    float acc[COUT];
#pragma unroll
    for (int co = 0; co < COUT; ++co) acc[co] = bias[co];

#pragma unroll 2
    for (int ci = 0; ci < CIN; ++ci) {
        const float* pl = tile + ci * PLANE + ty * RS + tx;
        float v[9];
#pragma unroll
        for (int ky = 0; ky < 3; ++ky)
#pragma unroll
            for (int kx = 0; kx < 3; ++kx)
                v[ky * 3 + kx] = pl[(ky * DIL) * RS + kx * DIL];
        const float* wp = w2 + (size_t)ci * 9 * COUT;
#pragma unroll
        for (int k = 0; k < 9; ++k)
#pragma unroll
            for (int co = 0; co < COUT; ++co)
                acc[co] = fmaf(v[k], wp[k * COUT + co], acc[co]);
    }

    // ---- write raw out ----
    const int oi = ti * TS + ty, oj = tj * TS + tx;
    float* yp = y + (size_t)s * HW_ * COUT + ((size_t)oi * W_ + oj) * COUT;
#pragma unroll
    for (int q = 0; q < COUT / 4; ++q) {
        float4 o;
        o.x = acc[4 * q]; o.y = acc[4 * q + 1];
        o.z = acc[4 * q + 2]; o.w = acc[4 * q + 3];
        reinterpret_cast<float4*>(yp)[q] = o;
    }

    // ---- per-block partial sums for this layer's InstanceNorm ----
    const int lane = t & 63, wave = t >> 6;
#pragma unroll
    for (int co = 0; co < COUT; ++co) {
        float s1 = acc[co], s2 = acc[co] * acc[co];
#pragma unroll
        for (int off = 32; off; off >>= 1) {
            s1 += __shfl_xor(s1, off);
            s2 += __shfl_xor(s2, off);
        }
        if (lane == 0) { sred[wave][co] = s1; sred[wave][COUT + co] = s2; }
    }
    __syncthreads();
    if (t < 2 * COUT) {
        float v = sred[0][t] + sred[1][t] + sred[2][t] + sred[3][t];
        partials[((size_t)s * NBLK + blk) * (2 * COUT) + t] = v;
    }
}

// ---------------------------------------------------------------------------
// Reduce per-block partials -> mean, invstd per (sample, channel).
// grid = nb*COUT.
// ---------------------------------------------------------------------------
template <int COUT>
__global__ __launch_bounds__(BDIM) void reduce_stats(
    const float* __restrict__ partials, float* __restrict__ stats)  // [nb][COUT][2]
{
    const int s = blockIdx.x / COUT;
    const int co = blockIdx.x - s * COUT;
    const float* P = partials + (size_t)s * NBLK * (2 * COUT);
    float s1 = 0.f, s2 = 0.f;
    for (int k = threadIdx.x; k < NBLK; k += BDIM) {
        const float* p = P + (size_t)k * (2 * COUT);
        s1 += p[co];
        s2 += p[COUT + co];
    }
#pragma unroll
    for (int off = 32; off; off >>= 1) {
        s1 += __shfl_xor(s1, off);
        s2 += __shfl_xor(s2, off);
    }
    __shared__ float l1[4], l2[4];
    const int lane = threadIdx.x & 63, wave = threadIdx.x >> 6;
    if (lane == 0) { l1[wave] = s1; l2[wave] = s2; }
    __syncthreads();
    if (threadIdx.x == 0) {
        float t1 = l1[0] + l1[1] + l1[2] + l1[3];
        float t2 = l2[0] + l2[1] + l2[2] + l2[3];
        float m = t1 / (float)HW_;
        float var = t2 / (float)HW_ - m * m;
        stats[((size_t)s * COUT + co) * 2 + 0] = m;
        stats[((size_t)s * COUT + co) * 2 + 1] = rsqrtf(var + 1e-5f);
    }
}

// ---------------------------------------------------------------------------
// conv2 (24->6, dil 1) with folded InstanceNorm+ReLU of layer 5 + channel
// softmax -> f at wsA + s*SA_BYTES. grid = nb*NBLK.
// ---------------------------------------------------------------------------
__global__ __launch_bounds__(BDIM) void conv2_softmax_tile(
    const float* __restrict__ in, const float* __restrict__ prevStats,
    const float* __restrict__ w2, const float* __restrict__ bias,
    char* __restrict__ wsA)
{
    constexpr int CIN = 24, COUT = 6, DIL = 1;
    constexpr int TW = TS + 2 * DIL;     // 18
    constexpr int RS = 24;
    constexpr int PLANE = RS * TW;
    __shared__ float tile[CIN * PLANE];

    const int s = blockIdx.x / NBLK;
    const int blk = blockIdx.x - s * NBLK;
    const float* inS = in + (size_t)s * HW_ * CIN;
    const float* ps = prevStats + (size_t)s * 2 * CIN;
    float* f = (float*)(wsA + (size_t)s * SA_BYTES);
    const int ti = blk / NTB, tj = blk - ti * NTB;
    const int i0 = ti * TS - DIL, j0 = tj * TS - DIL;
    const int t = threadIdx.x;

    for (int loc = t; loc < TW * TW; loc += BDIM) {
        const int rr = loc / TW, cc = loc - rr * TW;
        const int gi = i0 + rr, gj = j0 + cc;
        const bool ok = (gi >= 0) & (gi < H_) & (gj >= 0) & (gj < W_);
        const float* gp = inS + ((size_t)gi * W_ + gj) * CIN;
        float* lp = tile + rr * RS + cc;
#pragma unroll
        for (int q = 0; q < CIN / 4; ++q) {
            float vv[4] = {0.f, 0.f, 0.f, 0.f};
            if (ok) {
                const float4 raw = reinterpret_cast<const float4*>(gp)[q];
                vv[0] = raw.x; vv[1] = raw.y; vv[2] = raw.z; vv[3] = raw.w;
#pragma unroll
                for (int u = 0; u < 4; ++u) {
                    const int ci = 4 * q + u;
                    vv[u] = fmaxf((vv[u] - ps[2 * ci]) * ps[2 * ci + 1], 0.f);
                }
            }
#pragma unroll
            for (int u = 0; u < 4; ++u)
                lp[(4 * q + u) * PLANE] = vv[u];
        }
    }
    __syncthreads();

    const int tx = t & (TS - 1), ty = t >> 4;
    float acc[COUT];
#pragma unroll
    for (int co = 0; co < COUT; ++co) acc[co] = bias[co];

#pragma unroll 2
    for (int ci = 0; ci < CIN; ++ci) {
        const float* pl = tile + ci * PLANE + ty * RS + tx;
        float v[9];
#pragma unroll
        for (int ky = 0; ky < 3; ++ky)
#pragma unroll
            for (int kx = 0; kx < 3; ++kx)
                v[ky * 3 + kx] = pl[ky * RS + kx];
        const float* wp = w2 + (size_t)ci * 9 * COUT;
#pragma unroll
        for (int k = 0; k < 9; ++k)
#pragma unroll
            for (int co = 0; co < COUT; ++co)
                acc[co] = fmaf(v[k], wp[k * COUT + co], acc[co]);
    }

    float mx = acc[0];
#pragma unroll
    for (int co = 1; co < COUT; ++co) mx = fmaxf(mx, acc[co]);
    float e[COUT], sm = 0.f;
#pragma unroll
    for (int co = 0; co < COUT; ++co) { e[co] = __expf(acc[co] - mx); sm += e[co]; }
    const float inv = 1.f / sm;

    const int oi = ti * TS + ty, oj = tj * TS + tx;
    float2* fp2 = reinterpret_cast<float2*>(f + ((size_t)oi * W_ + oj) * 6);
    fp2[0] = make_float2(e[0] * inv, e[1] * inv);
    fp2[1] = make_float2(e[2] * inv, e[3] * inv);
    fp2[2] = make_float2(e[4] * inv, e[5] * inv);
}

// ---------------------------------------------------------------------------
// Integral images of x and x^2 (fp64) for nb samples; ii at wsA+s*SA_BYTES+OFF.
// ---------------------------------------------------------------------------
__global__ __launch_bounds__(BDIM) void rowscan(
    const float* __restrict__ x, char* __restrict__ wsA, int nwaves)
{
    const int gwave = (int)((blockIdx.x * (size_t)BDIM + threadIdx.x) >> 6);
    if (gwave >= nwaves) return;
    const int s = gwave / IH;
    const int r = gwave - s * IH;
    const int lane = threadIdx.x & 63;
    double* r1 = (double*)(wsA + (size_t)s * SA_BYTES + OFF_II1) + (size_t)r * IW;
    double* r2 = (double*)(wsA + (size_t)s * SA_BYTES + OFF_II2) + (size_t)r * IW;
    if (r == 0) {
        for (int j = lane; j < IW; j += 64) { r1[j] = 0.0; r2[j] = 0.0; }
        return;
    }
    const float* xr = x + (size_t)s * HW_ + (size_t)(r - 1) * W_;
    if (lane == 0) { r1[0] = 0.0; r2[0] = 0.0; }
    double c1 = 0.0, c2 = 0.0;
    for (int seg = 0; seg < W_ / 64; ++seg) {
        const float xv = xr[seg * 64 + lane];
        double v1 = (double)xv, v2 = (double)xv * (double)xv;
#pragma unroll
        for (int d = 1; d < 64; d <<= 1) {
            double t1 = __shfl_up(v1, d);
            double t2 = __shfl_up(v2, d);
            if (lane >= d) { v1 += t1; v2 += t2; }
        }
        v1 += c1; v2 += c2;
        r1[seg * 64 + lane + 1] = v1;
        r2[seg * 64 + lane + 1] = v2;
        c1 = __shfl(v1, 63);
        c2 = __shfl(v2, 63);
    }
}

__global__ __launch_bounds__(BDIM) void colscan(
    char* __restrict__ wsA, int total)   // total = nb*2*IW
{
    const int t = blockIdx.x * BDIM + threadIdx.x;
    if (t >= total) return;
    const int s = t / (2 * IW);
    const int rem = t - s * (2 * IW);
    const int which = rem / IW;
    const int j = rem - which * IW;
    double* p = (double*)(wsA + (size_t)s * SA_BYTES + (which ? OFF_II2 : OFF_II1));
    double acc = p[(size_t)1 * IW + j];
    for (int i = 2; i <= H_; ++i) {
        acc += p[(size_t)i * IW + j];
        p[(size_t)i * IW + j] = acc;
    }
}

// ---------------------------------------------------------------------------
// Final: 6 Sauvola thresholds, softmax-weighted sum, out = (x - th1)*alpha
// grid = nb*HW/BDIM.
// ---------------------------------------------------------------------------
__global__ __launch_bounds__(BDIM) void sauvola_out(
    const float* __restrict__ x, const char* __restrict__ wsA,
    const float* __restrict__ kArr, const float* __restrict__ RArr,
    const float* __restrict__ alphaP, float* __restrict__ outp)
{
    const int gid = blockIdx.x * BDIM + threadIdx.x;
    const int s = gid / HW_;
    const int pix = gid - s * HW_;
    const int i = pix / W_, j = pix - i * W_;
    const float xv = x[gid];
    const float* fp = (const float*)(wsA + (size_t)s * SA_BYTES) + (size_t)pix * 6;
    const double* ii1 = (const double*)(wsA + (size_t)s * SA_BYTES + OFF_II1);
    const double* ii2 = (const double*)(wsA + (size_t)s * SA_BYTES + OFF_II2);
    const float alpha = alphaP[0];

    const int wins[6] = {3, 5, 7, 11, 15, 19};
    float th1 = 0.f;
#pragma unroll
    for (int wi = 0; wi < 6; ++wi) {
        const int r = wins[wi] >> 1;
        const int r0 = max(i - r, 0), r1i = min(i + r, H_ - 1);
        const int c0 = max(j - r, 0), c1 = min(j + r, W_ - 1);
        const float cnt = (float)((r1i - r0 + 1) * (c1 - c0 + 1));
        const double* rt1 = ii1 + (size_t)r0 * IW;
        const double* rb1 = ii1 + (size_t)(r1i + 1) * IW;
        const double* rt2 = ii2 + (size_t)r0 * IW;
        const double* rb2 = ii2 + (size_t)(r1i + 1) * IW;
        const double s1 = rb1[c1 + 1] - rt1[c1 + 1] - rb1[c0] + rt1[c0];
        const double s2 = rb2[c1 + 1] - rt2[c1 + 1] - rb2[c0] + rt2[c0];
        const float invc = 1.f / cnt;
        const float Ex = (float)s1 * invc;
        const float Ex2 = (float)s2 * invc;
        const float dev = sqrtf(fmaxf(Ex2 - Ex * Ex, 1e-6f));
        const float th = Ex * (1.f + kArr[wi] * (dev / RArr[wi] - 1.f));
        th1 = fmaf(fp[wi], th, th1);
    }
    outp[gid] = (xv - th1) * alpha;
}

// ---------------------------------------------------------------------------
extern "C" void kernel_launch(void* const* d_in, const int* in_sizes, int n_in,
                              void* d_out, int out_size, void* d_ws, size_t ws_size,
                              hipStream_t stream) {
    const float* x   = (const float*)d_in[0];
    const float* w0  = (const float*)d_in[1];  const float* b0 = (const float*)d_in[2];
    const float* w1  = (const float*)d_in[3];  const float* b1 = (const float*)d_in[4];
    const float* w2  = (const float*)d_in[5];  const float* b2 = (const float*)d_in[6];
    const float* w3  = (const float*)d_in[7];  const float* b3 = (const float*)d_in[8];
    const float* w4  = (const float*)d_in[9];  const float* b4 = (const float*)d_in[10];
    const float* w5  = (const float*)d_in[11]; const float* b5 = (const float*)d_in[12];
    const float* wf  = (const float*)d_in[13]; const float* bf = (const float*)d_in[14];
    const float* kA  = (const float*)d_in[15];
    const float* RA  = (const float*)d_in[16];
    const float* alp = (const float*)d_in[17];
    float* out = (float*)d_out;
    (void)n_in; (void)in_sizes; (void)out_size;

    // ---- choose samples-per-launch from ws_size (deterministic) ----
    auto need = [](int nb) -> size_t {
        size_t o = 0;
        auto al = [&](size_t bytes) { o += (bytes + 255) & ~(size_t)255; };
        al((size_t)nb * HW_ * 20 * 4);          // bufA
        al((size_t)nb * HW_ * 24 * 4);          // bufB
        al((size_t)nb * NBLK * 48 * 4);         // partials
        al((size_t)nb * 48 * 4);                // stats
        al(36 * 4); al(288 * 4); al(864 * 4); al(1728 * 4);
        al(2880 * 4); al(4320 * 4); al(1296 * 4);
        return o;
    };
    int nb = 1;
    if (ws_size >= need(4)) nb = 4;
    else if (ws_size >= need(2)) nb = 2;

    char* ws = (char*)d_ws;
    size_t off = 0;
    auto alloc = [&](size_t bytes) -> void* {
        void* p = ws + off;
        off += (bytes + 255) & ~(size_t)255;
        return p;
    };
    float* bufA     = (float*)alloc((size_t)nb * HW_ * 20 * 4);
    float* bufB     = (float*)alloc((size_t)nb * HW_ * 24 * 4);
    float* partials = (float*)alloc((size_t)nb * NBLK * 48 * 4);
    float* stats    = (float*)alloc((size_t)nb * 48 * 4);
    float* r0 = (float*)alloc(36 * 4);
    float* r1 = (float*)alloc(288 * 4);
    float* r2 = (float*)alloc(864 * 4);
    float* r3 = (float*)alloc(1728 * 4);
    float* r4 = (float*)alloc(2880 * 4);
    float* r5 = (float*)alloc(4320 * 4);
    float* rf = (float*)alloc(1296 * 4);
    char* wsA = (char*)bufA;   // fbuf/ii1/ii2 carved from dead bufA per sample

    const dim3 blk(BDIM);
    const int cg = nb * NBLK;

    repack_all<<<7, blk, 0, stream>>>(w0, w1, w2, w3, w4, w5, wf,
                                      r0, r1, r2, r3, r4, r5, rf);

    for (int it = 0; it < B_ / nb; ++it) {
        const float* xc   = x   + (size_t)it * nb * HW_;
        float*       outc = out + (size_t)it * nb * HW_;

        conv_tile<1, 4, 1, false><<<cg, blk, 0, stream>>>(xc, nullptr, r0, b0, bufA, partials);
        reduce_stats<4><<<nb * 4, blk, 0, stream>>>(partials, stats);

        conv_tile<4, 8, 2, true><<<cg, blk, 0, stream>>>(bufA, stats, r1, b1, bufB, partials);
        reduce_stats<8><<<nb * 8, blk, 0, stream>>>(partials, stats);

        conv_tile<8, 12, 2, true><<<cg, blk, 0, stream>>>(bufB, stats, r2, b2, bufA, partials);
        reduce_stats<12><<<nb * 12, blk, 0, stream>>>(partials, stats);

        conv_tile<12, 16, 2, true><<<cg, blk, 0, stream>>>(bufA, stats, r3, b3, bufB, partials);
        reduce_stats<16><<<nb * 16, blk, 0, stream>>>(partials, stats);

        conv_tile<16, 20, 2, true><<<cg, blk, 0, stream>>>(bufB, stats, r4, b4, bufA, partials);
        reduce_stats<20><<<nb * 20, blk, 0, stream>>>(partials, stats);

        conv_tile<20, 24, 2, true><<<cg, blk, 0, stream>>>(bufA, stats, r5, b5, bufB, partials);
        reduce_stats<24><<<nb * 24, blk, 0, stream>>>(partials, stats);

        // bufA region now dead -> fbuf / ii1 / ii2 alias into it per sample
        conv2_softmax_tile<<<cg, blk, 0, stream>>>(bufB, stats, rf, bf, wsA);

        rowscan<<<(nb * IH * 64 + BDIM - 1) / BDIM, blk, 0, stream>>>(xc, wsA, nb * IH);
        colscan<<<(nb * 2 * IW + BDIM - 1) / BDIM, blk, 0, stream>>>(wsA, nb * 2 * IW);

        sauvola_out<<<nb * HW_ / BDIM, blk, 0, stream>>>(xc, wsA, kA, RA, alp, outc);
    }
}

// Round 6
// 581.380 us; speedup vs baseline: 11.7308x; 2.1804x over previous
//
#include <hip/hip_runtime.h>
#include <math.h>

#define BDIM 256
typedef __bf16 bf16;
typedef __bf16 bf16x4 __attribute__((ext_vector_type(4)));
typedef __bf16 bf16x8 __attribute__((ext_vector_type(8)));
typedef float f32x4 __attribute__((ext_vector_type(4)));

constexpr int B_ = 4, H_ = 768, W_ = 768;
constexpr int HW_ = H_ * W_;                 // 589824
constexpr int TS = 16;                       // spatial tile 16x16 px/block
constexpr int NTB = W_ / TS;                 // 48
constexpr int NBLK = HW_ / (TS * TS);        // 2304 blocks per sample
constexpr int IH = H_ + 1, IW = W_ + 1;      // 769

// per-sample span of bufA (20ch bf16); fbuf(bf16 [HW][6]) + fp64 integral
// images alias into it after the last conv consumes bufA.
constexpr size_t SA_BYTES = (size_t)HW_ * 20 * 2;   // 23,592,960
constexpr size_t OFF_II1  = (size_t)HW_ * 6 * 2;    // 7,077,888 (after fbuf)
constexpr size_t II_SPAN  = 4731136;                // 769*769*8 rounded to 256
constexpr size_t OFF_II2  = OFF_II1 + II_SPAN;      // 11,809,024 (+II_SPAN < SA)

// ---------------------------------------------------------------------------
// Weight repack: [COUT][CIN][3][3] fp32 -> padded bf16 [NT*16][KPP],
// k = tap*CINP + ci, zero everywhere outside (n<COUT, tap<9, ci<CIN).
// ---------------------------------------------------------------------------
__device__ void repack_one(const float* __restrict__ src, bf16* __restrict__ dst,
                           int CIN, int CINP, int COUT, int NT16, int KPP)
{
    const int n_ = NT16 * KPP;
    for (int idx = threadIdx.x; idx < n_; idx += BDIM) {
        const int n = idx / KPP, k = idx - n * KPP;
        const int tap = k / CINP, ci = k - tap * CINP;
        float v = 0.f;
        if (n < COUT && tap < 9 && ci < CIN)
            v = src[(n * CIN + ci) * 9 + tap];
        dst[idx] = (bf16)v;
    }
}

__global__ __launch_bounds__(BDIM) void repack_all(
    const float* w0, const float* w1, const float* w2, const float* w3,
    const float* w4, const float* w5, const float* wf,
    bf16* r0, bf16* r1, bf16* r2, bf16* r3, bf16* r4, bf16* r5, bf16* rf)
{
    switch (blockIdx.x) {
        case 0: repack_one(w0, r0, 1,  8,  4,  16, 104); break;
        case 1: repack_one(w1, r1, 4,  8,  8,  16, 104); break;
        case 2: repack_one(w2, r2, 8,  8,  12, 16, 104); break;
        case 3: repack_one(w3, r3, 12, 16, 16, 16, 168); break;
        case 4: repack_one(w4, r4, 16, 16, 20, 32, 168); break;
        case 5: repack_one(w5, r5, 20, 24, 24, 32, 232); break;
        case 6: repack_one(wf, rf, 24, 24, 6,  16, 232); break;
    }
}

// ---------------------------------------------------------------------------
// bf16-MFMA conv 3x3 (dilated, SAME) + bias, NHWC, nb samples (grid=nb*NBLK).
// Per block: 16x16 px tile. Halo tile staged channel-innermost bf16 with the
// previous layer's InstanceNorm+ReLU applied (OOB -> exact 0). GEMM view:
// M=256 px (16 M-tiles of 16), N=COUT (NT tiles of 16), K=9*CINP (KS*32).
// A-frag = one ds_read_b128 (8 contiguous ci at one tap). fp32 accum; bias +
// per-block stats from fp32; y stored bf16.
// ---------------------------------------------------------------------------
template <int CIN, int CINP, int COUT, int DIL, bool NORM, bool FIRST>
__global__ __launch_bounds__(BDIM) void conv_mfma(
    const void* __restrict__ inv,        // FIRST: fp32 x; else bf16 y_prev
    const float* __restrict__ prevStats, // [nb][CIN][2] (mean, invstd)
    const bf16* __restrict__ wp,         // packed [NT*16][KPP]
    const float* __restrict__ bias,      // [COUT] fp32
    bf16* __restrict__ y,                // [nb][H][W][COUT]
    float* __restrict__ partials)        // [nb][NBLK][2*COUT]
{
    constexpr int TW = TS + 2 * DIL;
    constexpr int KP = ((9 * CINP + 31) / 32) * 32;
    constexpr int KPP = KP + 8;                    // bank-friendly row pad
    constexpr int NT = (COUT + 15) / 16;
    constexpr int KS = KP / 32;
    constexpr int CSTR = (CINP == 16) ? 24 : CINP; // cell stride (bank-friendly)
    __shared__ __align__(16) bf16 tile[TW * TW * CSTR];
    __shared__ __align__(16) bf16 wlds[NT * 16 * KPP];
    __shared__ float sred[4][2 * COUT];

    const int s = blockIdx.x / NBLK;
    const int blk = blockIdx.x - s * NBLK;
    const int ti = blk / NTB, tj = blk - ti * NTB;
    const int i0 = ti * TS - DIL, j0 = tj * TS - DIL;
    const int t = threadIdx.x;

    // ---- weights -> LDS (flat uint copy; wp is pre-padded) ----
    {
        const unsigned int* wsrc = (const unsigned int*)wp;
        unsigned int* wdst = (unsigned int*)wlds;
        for (int i = t; i < NT * 16 * KPP / 2; i += BDIM) wdst[i] = wsrc[i];
    }

    // ---- stage halo tile, channel-innermost bf16, norm+relu fused ----
    for (int loc = t; loc < TW * TW; loc += BDIM) {
        const int rr = loc / TW, cc = loc - rr * TW;
        const int gi = i0 + rr, gj = j0 + cc;
        const bool ok = (gi >= 0) & (gi < H_) & (gj >= 0) & (gj < W_);
        bf16* lp = tile + loc * CSTR;
        if constexpr (FIRST) {
            const float* xg = (const float*)inv + (size_t)s * HW_;
            float v = ok ? xg[(size_t)gi * W_ + gj] : 0.f;
            lp[0] = (bf16)v;
#pragma unroll
            for (int c = 1; c < CINP; ++c) lp[c] = (bf16)0.f;
        } else {
            const bf16* ing = (const bf16*)inv +
                              ((size_t)s * HW_ + (size_t)gi * W_ + gj) * CIN;
            const float* ps = prevStats + s * 2 * CIN;
#pragma unroll
            for (int qq = 0; qq < CIN / 4; ++qq) {
                float vv[4] = {0.f, 0.f, 0.f, 0.f};
                if (ok) {
                    bf16x4 raw = ((const bf16x4*)ing)[qq];
#pragma unroll
                    for (int u = 0; u < 4; ++u) {
                        const int ci = 4 * qq + u;
                        vv[u] = fmaxf(((float)raw[u] - ps[2 * ci]) * ps[2 * ci + 1], 0.f);
                    }
                }
#pragma unroll
                for (int u = 0; u < 4; ++u) lp[4 * qq + u] = (bf16)vv[u];
            }
#pragma unroll
            for (int c = CIN; c < CINP; ++c) lp[c] = (bf16)0.f;
        }
    }
    __syncthreads();

    // ---- MFMA K-loop ----
    const int wave = t >> 6, lane = t & 63, q = lane >> 4, ln = lane & 15;
    f32x4 acc[4][NT];
#pragma unroll
    for (int mt = 0; mt < 4; ++mt)
#pragma unroll
        for (int u = 0; u < NT; ++u) acc[mt][u] = (f32x4){0.f, 0.f, 0.f, 0.f};

#pragma unroll
    for (int ks = 0; ks < KS; ++ks) {
        bf16x8 bfr[NT];
#pragma unroll
        for (int u = 0; u < NT; ++u)
            bfr[u] = *(const bf16x8*)&wlds[(u * 16 + ln) * KPP + ks * 32 + q * 8];
        int k0 = ks * 32 + q * 8;
        int tap = k0 / CINP;
        int ci0 = k0 - tap * CINP;
        if (tap > 8) { tap = 0; ci0 = 0; }   // padded k: B rows are zero
        const int ky = tap / 3, kx = tap - 3 * ky;
        const int aoff = (ky * DIL * TW + kx * DIL) * CSTR + ci0;
#pragma unroll
        for (int mt = 0; mt < 4; ++mt) {
            const bf16x8 af = *(const bf16x8*)
                &tile[((wave * 4 + mt) * TW + ln) * CSTR + aoff];
#pragma unroll
            for (int u = 0; u < NT; ++u)
                acc[mt][u] = __builtin_amdgcn_mfma_f32_16x16x32_bf16(
                    af, bfr[u], acc[mt][u], 0, 0, 0);
        }
    }

    // ---- bias + store bf16 + per-block stats (fp32) ----
#pragma unroll
    for (int u = 0; u < NT; ++u) {
        const int n = u * 16 + ln;
        const float bv = (n < COUT) ? bias[n] : 0.f;
        float s1 = 0.f, s2 = 0.f;
#pragma unroll
        for (int mt = 0; mt < 4; ++mt) {
#pragma unroll
            for (int r = 0; r < 4; ++r) {
                const float v = acc[mt][u][r] + bv;
                s1 += v; s2 += v * v;
                if (n < COUT) {
                    const int prow = ti * TS + wave * 4 + mt;  // D row = M idx = col? no: Mtile=row
                    const int pcol = tj * TS + q * 4 + r;      // D reg -> column within tile
                    y[(size_t)s * HW_ * COUT +
                      ((size_t)prow * W_ + pcol) * COUT + n] = (bf16)v;
                }
            }
        }
        s1 += __shfl_xor(s1, 16); s1 += __shfl_xor(s1, 32);
        s2 += __shfl_xor(s2, 16); s2 += __shfl_xor(s2, 32);
        if (lane < 16 && n < COUT) { sred[wave][n] = s1; sred[wave][COUT + n] = s2; }
    }
    __syncthreads();
    if (t < 2 * COUT) {
        partials[((size_t)s * NBLK + blk) * (2 * COUT) + t] =
            sred[0][t] + sred[1][t] + sred[2][t] + sred[3][t];
    }
}

// ---------------------------------------------------------------------------
// Reduce per-block partials -> mean, invstd per (sample, channel)
// ---------------------------------------------------------------------------
template <int COUT>
__global__ __launch_bounds__(BDIM) void reduce_stats(
    const float* __restrict__ partials, float* __restrict__ stats)
{
    const int s = blockIdx.x / COUT;
    const int co = blockIdx.x - s * COUT;
    const float* P = partials + (size_t)s * NBLK * (2 * COUT);
    float s1 = 0.f, s2 = 0.f;
    for (int k = threadIdx.x; k < NBLK; k += BDIM) {
        const float* p = P + (size_t)k * (2 * COUT);
        s1 += p[co];
        s2 += p[COUT + co];
    }
#pragma unroll
    for (int off = 32; off; off >>= 1) {
        s1 += __shfl_xor(s1, off);
        s2 += __shfl_xor(s2, off);
    }
    __shared__ float l1[4], l2[4];
    const int lane = threadIdx.x & 63, wave = threadIdx.x >> 6;
    if (lane == 0) { l1[wave] = s1; l2[wave] = s2; }
    __syncthreads();
    if (threadIdx.x == 0) {
        float t1 = l1[0] + l1[1] + l1[2] + l1[3];
        float t2 = l2[0] + l2[1] + l2[2] + l2[3];
        float m = t1 / (float)HW_;
        float var = t2 / (float)HW_ - m * m;
        stats[((size_t)s * COUT + co) * 2 + 0] = m;
        stats[((size_t)s * COUT + co) * 2 + 1] = rsqrtf(var + 1e-5f);
    }
}

// ---------------------------------------------------------------------------
// conv2 (24->6, dil 1) MFMA + folded norm of layer 5 + channel softmax.
// Logits round-trip through LDS (tile reuse) so each thread owns one pixel's
// 6 couts. f stored bf16 [H][W][6] into wsA.
// ---------------------------------------------------------------------------
__global__ __launch_bounds__(BDIM) void conv2_softmax_mfma(
    const bf16* __restrict__ in, const float* __restrict__ prevStats,
    const bf16* __restrict__ wp, const float* __restrict__ bias,
    char* __restrict__ wsA)
{
    constexpr int CIN = 24, CINP = 24, COUT = 6, DIL = 1;
    constexpr int TW = TS + 2 * DIL;      // 18
    constexpr int KP = 224, KPP = 232, KS = 7, CSTR = 24;
    __shared__ __align__(16) bf16 tile[TW * TW * CSTR];   // 15552 B
    __shared__ __align__(16) bf16 wlds[16 * KPP];

    const int s = blockIdx.x / NBLK;
    const int blk = blockIdx.x - s * NBLK;
    const int ti = blk / NTB, tj = blk - ti * NTB;
    const int i0 = ti * TS - DIL, j0 = tj * TS - DIL;
    const int t = threadIdx.x;

    {
        const unsigned int* wsrc = (const unsigned int*)wp;
        unsigned int* wdst = (unsigned int*)wlds;
        for (int i = t; i < 16 * KPP / 2; i += BDIM) wdst[i] = wsrc[i];
    }
    const float* ps = prevStats + s * 2 * CIN;
    for (int loc = t; loc < TW * TW; loc += BDIM) {
        const int rr = loc / TW, cc = loc - rr * TW;
        const int gi = i0 + rr, gj = j0 + cc;
        const bool ok = (gi >= 0) & (gi < H_) & (gj >= 0) & (gj < W_);
        const bf16* ing = in + ((size_t)s * HW_ + (size_t)gi * W_ + gj) * CIN;
        bf16* lp = tile + loc * CSTR;
#pragma unroll
        for (int qq = 0; qq < CIN / 4; ++qq) {
            float vv[4] = {0.f, 0.f, 0.f, 0.f};
            if (ok) {
                bf16x4 raw = ((const bf16x4*)ing)[qq];
#pragma unroll
                for (int u = 0; u < 4; ++u) {
                    const int ci = 4 * qq + u;
                    vv[u] = fmaxf(((float)raw[u] - ps[2 * ci]) * ps[2 * ci + 1], 0.f);
                }
            }
#pragma unroll
            for (int u = 0; u < 4; ++u) lp[4 * qq + u] = (bf16)vv[u];
        }
    }
    __syncthreads();

    const int wave = t >> 6, lane = t & 63, q = lane >> 4, ln = lane & 15;
    f32x4 acc[4];
#pragma unroll
    for (int mt = 0; mt < 4; ++mt) acc[mt] = (f32x4){0.f, 0.f, 0.f, 0.f};

#pragma unroll
    for (int ks = 0; ks < KS; ++ks) {
        const bf16x8 bfr = *(const bf16x8*)&wlds[ln * KPP + ks * 32 + q * 8];
        int k0 = ks * 32 + q * 8;
        int tap = k0 / CINP;
        int ci0 = k0 - tap * CINP;
        if (tap > 8) { tap = 0; ci0 = 0; }
        const int ky = tap / 3, kx = tap - 3 * ky;
        const int aoff = (ky * DIL * TW + kx * DIL) * CSTR + ci0;
#pragma unroll
        for (int mt = 0; mt < 4; ++mt) {
            const bf16x8 af = *(const bf16x8*)
                &tile[((wave * 4 + mt) * TW + ln) * CSTR + aoff];
            acc[mt] = __builtin_amdgcn_mfma_f32_16x16x32_bf16(af, bfr, acc[mt], 0, 0, 0);
        }
    }

    __syncthreads();                       // done reading tile -> reuse as logits
    float* slog = (float*)tile;            // 256*6*4 = 6144 B <= 15552 B
    const float bv = (ln < COUT) ? bias[ln] : 0.f;
#pragma unroll
    for (int mt = 0; mt < 4; ++mt)
#pragma unroll
        for (int r = 0; r < 4; ++r)
            if (ln < COUT) {
                const int pl = (wave * 4 + mt) * 16 + q * 4 + r;
                slog[pl * COUT + ln] = acc[mt][r] + bv;
            }
    __syncthreads();

    float e[COUT];
    float mx = slog[t * COUT];
#pragma unroll
    for (int co = 1; co < COUT; ++co) mx = fmaxf(mx, slog[t * COUT + co]);
    float sm = 0.f;
#pragma unroll
    for (int co = 0; co < COUT; ++co) { e[co] = __expf(slog[t * COUT + co] - mx); sm += e[co]; }
    const float inv = 1.f / sm;
    bf16* f = (bf16*)(wsA + (size_t)s * SA_BYTES);
    const int prow = ti * TS + (t >> 4), pcol = tj * TS + (t & 15);
    bf16* fp = f + ((size_t)prow * W_ + pcol) * 6;
#pragma unroll
    for (int co = 0; co < COUT; ++co) fp[co] = (bf16)(e[co] * inv);
}

// ---------------------------------------------------------------------------
// Integral images of x and x^2 (fp64), nb samples.
// ---------------------------------------------------------------------------
__global__ __launch_bounds__(BDIM) void rowscan(
    const float* __restrict__ x, char* __restrict__ wsA, int nwaves)
{
    const int gwave = (int)((blockIdx.x * (size_t)BDIM + threadIdx.x) >> 6);
    if (gwave >= nwaves) return;
    const int s = gwave / IH;
    const int r = gwave - s * IH;
    const int lane = threadIdx.x & 63;
    double* r1 = (double*)(wsA + (size_t)s * SA_BYTES + OFF_II1) + (size_t)r * IW;
    double* r2 = (double*)(wsA + (size_t)s * SA_BYTES + OFF_II2) + (size_t)r * IW;
    if (r == 0) {
        for (int j = lane; j < IW; j += 64) { r1[j] = 0.0; r2[j] = 0.0; }
        return;
    }
    const float* xr = x + (size_t)s * HW_ + (size_t)(r - 1) * W_;
    if (lane == 0) { r1[0] = 0.0; r2[0] = 0.0; }
    double c1 = 0.0, c2 = 0.0;
    for (int seg = 0; seg < W_ / 64; ++seg) {
        const float xv = xr[seg * 64 + lane];
        double v1 = (double)xv, v2 = (double)xv * (double)xv;
#pragma unroll
        for (int d = 1; d < 64; d <<= 1) {
            double t1 = __shfl_up(v1, d);
            double t2 = __shfl_up(v2, d);
            if (lane >= d) { v1 += t1; v2 += t2; }
        }
        v1 += c1; v2 += c2;
        r1[seg * 64 + lane + 1] = v1;
        r2[seg * 64 + lane + 1] = v2;
        c1 = __shfl(v1, 63);
        c2 = __shfl(v2, 63);
    }
}

__global__ __launch_bounds__(BDIM) void colscan(
    char* __restrict__ wsA, int total)   // total = nb*2*IW
{
    const int t = blockIdx.x * BDIM + threadIdx.x;
    if (t >= total) return;
    const int s = t / (2 * IW);
    const int rem = t - s * (2 * IW);
    const int which = rem / IW;
    const int j = rem - which * IW;
    double* p = (double*)(wsA + (size_t)s * SA_BYTES + (which ? OFF_II2 : OFF_II1));
    double acc = p[(size_t)1 * IW + j];
    for (int i = 2; i <= H_; ++i) {
        acc += p[(size_t)i * IW + j];
        p[(size_t)i * IW + j] = acc;
    }
}

// ---------------------------------------------------------------------------
// Final: 6 Sauvola thresholds, softmax-weighted sum, out = (x - th1)*alpha
// ---------------------------------------------------------------------------
__global__ __launch_bounds__(BDIM) void sauvola_out(
    const float* __restrict__ x, const char* __restrict__ wsA,
    const float* __restrict__ kArr, const float* __restrict__ RArr,
    const float* __restrict__ alphaP, float* __restrict__ outp)
{
    const int gid = blockIdx.x * BDIM + threadIdx.x;
    const int s = gid / HW_;
    const int pix = gid - s * HW_;
    const int i = pix / W_, j = pix - i * W_;
    const float xv = x[gid];
    const bf16* fp = (const bf16*)(wsA + (size_t)s * SA_BYTES) + (size_t)pix * 6;
    const double* ii1 = (const double*)(wsA + (size_t)s * SA_BYTES + OFF_II1);
    const double* ii2 = (const double*)(wsA + (size_t)s * SA_BYTES + OFF_II2);
    const float alpha = alphaP[0];

    const int wins[6] = {3, 5, 7, 11, 15, 19};
    float th1 = 0.f;
#pragma unroll
    for (int wi = 0; wi < 6; ++wi) {
        const int r = wins[wi] >> 1;
        const int r0 = max(i - r, 0), r1i = min(i + r, H_ - 1);
        const int c0 = max(j - r, 0), c1 = min(j + r, W_ - 1);
        const float cnt = (float)((r1i - r0 + 1) * (c1 - c0 + 1));
        const double* rt1 = ii1 + (size_t)r0 * IW;
        const double* rb1 = ii1 + (size_t)(r1i + 1) * IW;
        const double* rt2 = ii2 + (size_t)r0 * IW;
        const double* rb2 = ii2 + (size_t)(r1i + 1) * IW;
        const double s1 = rb1[c1 + 1] - rt1[c1 + 1] - rb1[c0] + rt1[c0];
        const double s2 = rb2[c1 + 1] - rt2[c1 + 1] - rb2[c0] + rt2[c0];
        const float invc = 1.f / cnt;
        const float Ex = (float)s1 * invc;
        const float Ex2 = (float)s2 * invc;
        const float dev = sqrtf(fmaxf(Ex2 - Ex * Ex, 1e-6f));
        const float th = Ex * (1.f + kArr[wi] * (dev / RArr[wi] - 1.f));
        th1 = fmaf((float)fp[wi], th, th1);
    }
    outp[gid] = (xv - th1) * alpha;
}

// ---------------------------------------------------------------------------
extern "C" void kernel_launch(void* const* d_in, const int* in_sizes, int n_in,
                              void* d_out, int out_size, void* d_ws, size_t ws_size,
                              hipStream_t stream) {
    const float* x   = (const float*)d_in[0];
    const float* w0  = (const float*)d_in[1];  const float* b0 = (const float*)d_in[2];
    const float* w1  = (const float*)d_in[3];  const float* b1 = (const float*)d_in[4];
    const float* w2  = (const float*)d_in[5];  const float* b2 = (const float*)d_in[6];
    const float* w3  = (const float*)d_in[7];  const float* b3 = (const float*)d_in[8];
    const float* w4  = (const float*)d_in[9];  const float* b4 = (const float*)d_in[10];
    const float* w5  = (const float*)d_in[11]; const float* b5 = (const float*)d_in[12];
    const float* wf  = (const float*)d_in[13]; const float* bf = (const float*)d_in[14];
    const float* kA  = (const float*)d_in[15];
    const float* RA  = (const float*)d_in[16];
    const float* alp = (const float*)d_in[17];
    float* out = (float*)d_out;
    (void)n_in; (void)in_sizes; (void)out_size;

    // ---- choose samples-per-launch from ws_size (deterministic) ----
    auto need = [](int nb) -> size_t {
        size_t o = 0;
        auto al = [&](size_t bytes) { o += (bytes + 255) & ~(size_t)255; };
        al((size_t)nb * HW_ * 20 * 2);          // bufA (bf16)
        al((size_t)nb * HW_ * 24 * 2);          // bufB (bf16)
        al((size_t)nb * NBLK * 48 * 4);         // partials
        al((size_t)nb * 48 * 4);                // stats
        al(1664 * 2); al(1664 * 2); al(1664 * 2); al(2688 * 2);
        al(5376 * 2); al(7424 * 2); al(3712 * 2);
        return o;
    };
    int nb = 1;
    if (ws_size >= need(4)) nb = 4;
    else if (ws_size >= need(2)) nb = 2;

    char* ws = (char*)d_ws;
    size_t off = 0;
    auto alloc = [&](size_t bytes) -> void* {
        void* p = ws + off;
        off += (bytes + 255) & ~(size_t)255;
        return p;
    };
    bf16*  bufA     = (bf16*)alloc((size_t)nb * HW_ * 20 * 2);
    bf16*  bufB     = (bf16*)alloc((size_t)nb * HW_ * 24 * 2);
    float* partials = (float*)alloc((size_t)nb * NBLK * 48 * 4);
    float* stats    = (float*)alloc((size_t)nb * 48 * 4);
    bf16* r0 = (bf16*)alloc(1664 * 2);
    bf16* r1 = (bf16*)alloc(1664 * 2);
    bf16* r2 = (bf16*)alloc(1664 * 2);
    bf16* r3 = (bf16*)alloc(2688 * 2);
    bf16* r4 = (bf16*)alloc(5376 * 2);
    bf16* r5 = (bf16*)alloc(7424 * 2);
    bf16* rf = (bf16*)alloc(3712 * 2);
    char* wsA = (char*)bufA;   // fbuf(bf16)/ii1/ii2 carved per sample

    const dim3 blk(BDIM);
    const int cg = nb * NBLK;

    repack_all<<<7, blk, 0, stream>>>(w0, w1, w2, w3, w4, w5, wf,
                                      r0, r1, r2, r3, r4, r5, rf);

    for (int it = 0; it < B_ / nb; ++it) {
        const float* xc   = x   + (size_t)it * nb * HW_;
        float*       outc = out + (size_t)it * nb * HW_;

        conv_mfma<1, 8, 4, 1, false, true><<<cg, blk, 0, stream>>>(xc, nullptr, r0, b0, bufA, partials);
        reduce_stats<4><<<nb * 4, blk, 0, stream>>>(partials, stats);

        conv_mfma<4, 8, 8, 2, true, false><<<cg, blk, 0, stream>>>(bufA, stats, r1, b1, bufB, partials);
        reduce_stats<8><<<nb * 8, blk, 0, stream>>>(partials, stats);

        conv_mfma<8, 8, 12, 2, true, false><<<cg, blk, 0, stream>>>(bufB, stats, r2, b2, bufA, partials);
        reduce_stats<12><<<nb * 12, blk, 0, stream>>>(partials, stats);

        conv_mfma<12, 16, 16, 2, true, false><<<cg, blk, 0, stream>>>(bufA, stats, r3, b3, bufB, partials);
        reduce_stats<16><<<nb * 16, blk, 0, stream>>>(partials, stats);

        conv_mfma<16, 16, 20, 2, true, false><<<cg, blk, 0, stream>>>(bufB, stats, r4, b4, bufA, partials);
        reduce_stats<20><<<nb * 20, blk, 0, stream>>>(partials, stats);

        conv_mfma<20, 24, 24, 2, true, false><<<cg, blk, 0, stream>>>(bufA, stats, r5, b5, bufB, partials);
        reduce_stats<24><<<nb * 24, blk, 0, stream>>>(partials, stats);

        // bufA region now dead -> fbuf / ii1 / ii2 alias into it per sample
        conv2_softmax_mfma<<<cg, blk, 0, stream>>>(bufB, stats, rf, bf, wsA);

        rowscan<<<(nb * IH * 64 + BDIM - 1) / BDIM, blk, 0, stream>>>(xc, wsA, nb * IH);
        colscan<<<(nb * 2 * IW + BDIM - 1) / BDIM, blk, 0, stream>>>(wsA, nb * 2 * IW);

        sauvola_out<<<nb * HW_ / BDIM, blk, 0, stream>>>(xc, wsA, kA, RA, alp, outc);
    }
}

// Round 7
// 544.445 us; speedup vs baseline: 12.5267x; 1.0678x over previous
//
#include <hip/hip_runtime.h>
#include <math.h>

#define BDIM 256
typedef __bf16 bf16;
typedef __bf16 bf16x4 __attribute__((ext_vector_type(4)));
typedef __bf16 bf16x8 __attribute__((ext_vector_type(8)));
typedef float f32x4 __attribute__((ext_vector_type(4)));

constexpr int B_ = 4, H_ = 768, W_ = 768;
constexpr int HW_ = H_ * W_;                 // 589824
constexpr int TS = 16;                       // spatial tile 16x16 px/block
constexpr int NTB = W_ / TS;                 // 48
constexpr int NBLK = HW_ / (TS * TS);        // 2304 blocks per sample
constexpr int IH = H_ + 1, IW = W_ + 1;      // 769

// per-sample span of bufA (20ch bf16); fbuf(bf16 [HW][6]) + fp64 integral
// images alias into it after the last conv consumes bufA.
constexpr size_t SA_BYTES = (size_t)HW_ * 20 * 2;   // 23,592,960
constexpr size_t OFF_II1  = (size_t)HW_ * 6 * 2;    // 7,077,888 (after fbuf)
constexpr size_t II_SPAN  = 4731136;                // 769*769*8 rounded to 256
constexpr size_t OFF_II2  = OFF_II1 + II_SPAN;      // 11,809,024 (+II_SPAN < SA)

// scratch carved from the TAIL of d_out (written before read each iteration;
// the final sauvola_out of the last chunk overwrites it after last use):
constexpr int PMAX_FLOATS = 4 * NBLK * 48;          // 442368
constexpr int OUT_ELEMS   = B_ * HW_;               // 2359296

// ---------------------------------------------------------------------------
// Weight repack: [COUT][CIN][3][3] fp32 -> padded bf16 [NT*16][KPP],
// k = tap*CINP + ci, zero everywhere outside (n<COUT, tap<9, ci<CIN).
// ---------------------------------------------------------------------------
__device__ void repack_one(const float* __restrict__ src, bf16* __restrict__ dst,
                           int CIN, int CINP, int COUT, int NT16, int KPP)
{
    const int n_ = NT16 * KPP;
    for (int idx = threadIdx.x; idx < n_; idx += BDIM) {
        const int n = idx / KPP, k = idx - n * KPP;
        const int tap = k / CINP, ci = k - tap * CINP;
        float v = 0.f;
        if (n < COUT && tap < 9 && ci < CIN)
            v = src[(n * CIN + ci) * 9 + tap];
        dst[idx] = (bf16)v;
    }
}

__global__ __launch_bounds__(BDIM) void repack_all(
    const float* w0, const float* w1, const float* w2, const float* w3,
    const float* w4, const float* w5, const float* wf,
    bf16* r0, bf16* r1, bf16* r2, bf16* r3, bf16* r4, bf16* r5, bf16* rf)
{
    switch (blockIdx.x) {
        case 0: repack_one(w0, r0, 1,  8,  4,  16, 104); break;
        case 1: repack_one(w1, r1, 4,  8,  8,  16, 104); break;
        case 2: repack_one(w2, r2, 8,  8,  12, 16, 104); break;
        case 3: repack_one(w3, r3, 12, 16, 16, 16, 168); break;
        case 4: repack_one(w4, r4, 16, 16, 20, 32, 168); break;
        case 5: repack_one(w5, r5, 20, 24, 24, 32, 232); break;
        case 6: repack_one(wf, rf, 24, 24, 6,  16, 232); break;
    }
}

// ---------------------------------------------------------------------------
// bf16-MFMA conv 3x3 (dilated, SAME) + bias, NHWC, nb samples (grid=nb*NBLK).
// Halo tile staged channel-innermost bf16 (prev-layer norm+relu fused, OOB=0).
// GEMM: M=256 px, N=COUT (NT x16), K=9*CINP (KS x32). fp32 accum. Epilogue
// round-trips through LDS so global stores are contiguous per-pixel vectors.
// ---------------------------------------------------------------------------
template <int CIN, int CINP, int COUT, int DIL, bool FIRST>
__global__ __launch_bounds__(BDIM) void conv_mfma(
    const void* __restrict__ inv,        // FIRST: fp32 x; else bf16 y_prev
    const float* __restrict__ prevStats, // [nb][CIN][2] (mean, invstd)
    const bf16* __restrict__ wp,         // packed [NT*16][KPP]
    const float* __restrict__ bias,      // [COUT] fp32
    bf16* __restrict__ y,                // [nb][H][W][COUT]
    float* __restrict__ partials)        // [nb][NBLK][2*COUT]
{
    constexpr int TW = TS + 2 * DIL;
    constexpr int KP = ((9 * CINP + 31) / 32) * 32;
    constexpr int KPP = KP + 8;
    constexpr int NT = (COUT + 15) / 16;
    constexpr int KS = KP / 32;
    constexpr int CSTR = (CINP == 16) ? 24 : CINP;   // multiple of 8 (b128 align)
    __shared__ __align__(16) bf16 tile[TW * TW * CSTR];
    __shared__ __align__(16) bf16 wlds[NT * 16 * KPP];
    __shared__ float sred[4][2 * COUT];

    const int s = blockIdx.x / NBLK;
    const int blk = blockIdx.x - s * NBLK;
    const int ti = blk / NTB, tj = blk - ti * NTB;
    const int i0 = ti * TS - DIL, j0 = tj * TS - DIL;
    const int t = threadIdx.x;

    // ---- weights -> LDS ----
    {
        const unsigned int* wsrc = (const unsigned int*)wp;
        unsigned int* wdst = (unsigned int*)wlds;
        for (int i = t; i < NT * 16 * KPP / 2; i += BDIM) wdst[i] = wsrc[i];
    }

    // ---- stage halo tile (vector loads, b64 LDS writes) ----
    for (int loc = t; loc < TW * TW; loc += BDIM) {
        const int rr = loc / TW, cc = loc - rr * TW;
        const int gi = i0 + rr, gj = j0 + cc;
        const bool ok = (gi >= 0) & (gi < H_) & (gj >= 0) & (gj < W_);
        float lv[CSTR];
#pragma unroll
        for (int c = 0; c < CSTR; ++c) lv[c] = 0.f;
        if (ok) {
            if constexpr (FIRST) {
                const float* xg = (const float*)inv + (size_t)s * HW_;
                lv[0] = xg[(size_t)gi * W_ + gj];
            } else {
                const bf16* ing = (const bf16*)inv +
                                  ((size_t)s * HW_ + (size_t)gi * W_ + gj) * CIN;
                const float* ps = prevStats + s * 2 * CIN;
                if constexpr (CIN % 8 == 0) {
#pragma unroll
                    for (int qq = 0; qq < CIN / 8; ++qq) {
                        bf16x8 raw = ((const bf16x8*)ing)[qq];
#pragma unroll
                        for (int u = 0; u < 8; ++u) {
                            const int ci = 8 * qq + u;
                            lv[ci] = fmaxf(((float)raw[u] - ps[2 * ci]) * ps[2 * ci + 1], 0.f);
                        }
                    }
                } else {
#pragma unroll
                    for (int qq = 0; qq < CIN / 4; ++qq) {
                        bf16x4 raw = ((const bf16x4*)ing)[qq];
#pragma unroll
                        for (int u = 0; u < 4; ++u) {
                            const int ci = 4 * qq + u;
                            lv[ci] = fmaxf(((float)raw[u] - ps[2 * ci]) * ps[2 * ci + 1], 0.f);
                        }
                    }
                }
            }
        }
        bf16* lp = tile + loc * CSTR;
#pragma unroll
        for (int g = 0; g < CSTR / 4; ++g) {
            bf16x4 pk = { (bf16)lv[4 * g], (bf16)lv[4 * g + 1],
                          (bf16)lv[4 * g + 2], (bf16)lv[4 * g + 3] };
            *(bf16x4*)(lp + 4 * g) = pk;
        }
    }
    __syncthreads();

    // ---- MFMA K-loop ----
    const int wave = t >> 6, lane = t & 63, q = lane >> 4, ln = lane & 15;
    f32x4 acc[4][NT];
#pragma unroll
    for (int mt = 0; mt < 4; ++mt)
#pragma unroll
        for (int u = 0; u < NT; ++u) acc[mt][u] = (f32x4){0.f, 0.f, 0.f, 0.f};

#pragma unroll
    for (int ks = 0; ks < KS; ++ks) {
        bf16x8 bfr[NT];
#pragma unroll
        for (int u = 0; u < NT; ++u)
            bfr[u] = *(const bf16x8*)&wlds[(u * 16 + ln) * KPP + ks * 32 + q * 8];
        int k0 = ks * 32 + q * 8;
        int tap = k0 / CINP;
        int ci0 = k0 - tap * CINP;
        if (tap > 8) { tap = 0; ci0 = 0; }   // padded k: B rows are zero
        const int ky = tap / 3, kx = tap - 3 * ky;
        const int aoff = (ky * DIL * TW + kx * DIL) * CSTR + ci0;
#pragma unroll
        for (int mt = 0; mt < 4; ++mt) {
            const bf16x8 af = *(const bf16x8*)
                &tile[((wave * 4 + mt) * TW + ln) * CSTR + aoff];
#pragma unroll
            for (int u = 0; u < NT; ++u)
                acc[mt][u] = __builtin_amdgcn_mfma_f32_16x16x32_bf16(
                    af, bfr[u], acc[mt][u], 0, 0, 0);
        }
    }

    // ---- bias + stats (registers), sred ----
#pragma unroll
    for (int u = 0; u < NT; ++u) {
        const int n = u * 16 + ln;
        const float bv = (n < COUT) ? bias[n] : 0.f;
        float s1 = 0.f, s2 = 0.f;
#pragma unroll
        for (int mt = 0; mt < 4; ++mt)
#pragma unroll
            for (int r = 0; r < 4; ++r) {
                const float v = acc[mt][u][r] + bv;
                acc[mt][u][r] = v;
                s1 += v; s2 += v * v;
            }
        s1 += __shfl_xor(s1, 16); s1 += __shfl_xor(s1, 32);
        s2 += __shfl_xor(s2, 16); s2 += __shfl_xor(s2, 32);
        if (lane < 16 && n < COUT) { sred[wave][n] = s1; sred[wave][COUT + n] = s2; }
    }
    __syncthreads();   // K-loop tile reads complete + sred visible
    if (t < 2 * COUT) {
        partials[((size_t)s * NBLK + blk) * (2 * COUT) + t] =
            sred[0][t] + sred[1][t] + sred[2][t] + sred[3][t];
    }

    // ---- out-stage into LDS (reuse tile), then coalesced global stores ----
    bf16* ost = tile;   // 256*COUT bf16 <= tile capacity for all layers
#pragma unroll
    for (int u = 0; u < NT; ++u) {
        const int n = u * 16 + ln;
        if (n < COUT) {
#pragma unroll
            for (int mt = 0; mt < 4; ++mt)
#pragma unroll
                for (int r = 0; r < 4; ++r) {
                    const int pl = (wave * 4 + mt) * 16 + q * 4 + r;
                    ost[pl * COUT + n] = (bf16)acc[mt][u][r];
                }
        }
    }
    __syncthreads();

    const int lr = t >> 4, lc = t & 15;
    bf16* yp = y + (size_t)s * HW_ * COUT +
               ((size_t)(ti * TS + lr) * W_ + (tj * TS + lc)) * COUT;
    const bf16* sp = ost + t * COUT;
    if constexpr (COUT % 8 == 0) {
#pragma unroll
        for (int g = 0; g < COUT / 8; ++g)
            ((bf16x8*)yp)[g] = ((const bf16x8*)sp)[g];
    } else {
#pragma unroll
        for (int g = 0; g < COUT / 4; ++g)
            ((bf16x4*)yp)[g] = ((const bf16x4*)sp)[g];
    }
}

// ---------------------------------------------------------------------------
// Reduce per-block partials -> mean, invstd per (sample, channel)
// ---------------------------------------------------------------------------
template <int COUT>
__global__ __launch_bounds__(BDIM) void reduce_stats(
    const float* __restrict__ partials, float* __restrict__ stats)
{
    const int s = blockIdx.x / COUT;
    const int co = blockIdx.x - s * COUT;
    const float* P = partials + (size_t)s * NBLK * (2 * COUT);
    float s1 = 0.f, s2 = 0.f;
    for (int k = threadIdx.x; k < NBLK; k += BDIM) {
        const float* p = P + (size_t)k * (2 * COUT);
        s1 += p[co];
        s2 += p[COUT + co];
    }
#pragma unroll
    for (int off = 32; off; off >>= 1) {
        s1 += __shfl_xor(s1, off);
        s2 += __shfl_xor(s2, off);
    }
    __shared__ float l1[4], l2[4];
    const int lane = threadIdx.x & 63, wave = threadIdx.x >> 6;
    if (lane == 0) { l1[wave] = s1; l2[wave] = s2; }
    __syncthreads();
    if (threadIdx.x == 0) {
        float t1 = l1[0] + l1[1] + l1[2] + l1[3];
        float t2 = l2[0] + l2[1] + l2[2] + l2[3];
        float m = t1 / (float)HW_;
        float var = t2 / (float)HW_ - m * m;
        stats[((size_t)s * COUT + co) * 2 + 0] = m;
        stats[((size_t)s * COUT + co) * 2 + 1] = rsqrtf(var + 1e-5f);
    }
}

// ---------------------------------------------------------------------------
// conv2 (24->6, dil 1) MFMA + folded norm of layer 5 + channel softmax.
// ---------------------------------------------------------------------------
__global__ __launch_bounds__(BDIM) void conv2_softmax_mfma(
    const bf16* __restrict__ in, const float* __restrict__ prevStats,
    const bf16* __restrict__ wp, const float* __restrict__ bias,
    char* __restrict__ wsA)
{
    constexpr int CIN = 24, CINP = 24, COUT = 6, DIL = 1;
    constexpr int TW = TS + 2 * DIL;      // 18
    constexpr int KP = 224, KPP = 232, KS = 7, CSTR = 24;
    __shared__ __align__(16) bf16 tile[TW * TW * CSTR];   // 15552 B
    __shared__ __align__(16) bf16 wlds[16 * KPP];

    const int s = blockIdx.x / NBLK;
    const int blk = blockIdx.x - s * NBLK;
    const int ti = blk / NTB, tj = blk - ti * NTB;
    const int i0 = ti * TS - DIL, j0 = tj * TS - DIL;
    const int t = threadIdx.x;

    {
        const unsigned int* wsrc = (const unsigned int*)wp;
        unsigned int* wdst = (unsigned int*)wlds;
        for (int i = t; i < 16 * KPP / 2; i += BDIM) wdst[i] = wsrc[i];
    }
    const float* ps = prevStats + s * 2 * CIN;
    for (int loc = t; loc < TW * TW; loc += BDIM) {
        const int rr = loc / TW, cc = loc - rr * TW;
        const int gi = i0 + rr, gj = j0 + cc;
        const bool ok = (gi >= 0) & (gi < H_) & (gj >= 0) & (gj < W_);
        float lv[CSTR];
#pragma unroll
        for (int c = 0; c < CSTR; ++c) lv[c] = 0.f;
        if (ok) {
            const bf16* ing = in + ((size_t)s * HW_ + (size_t)gi * W_ + gj) * CIN;
#pragma unroll
            for (int qq = 0; qq < CIN / 8; ++qq) {
                bf16x8 raw = ((const bf16x8*)ing)[qq];
#pragma unroll
                for (int u = 0; u < 8; ++u) {
                    const int ci = 8 * qq + u;
                    lv[ci] = fmaxf(((float)raw[u] - ps[2 * ci]) * ps[2 * ci + 1], 0.f);
                }
            }
        }
        bf16* lp = tile + loc * CSTR;
#pragma unroll
        for (int g = 0; g < CSTR / 4; ++g) {
            bf16x4 pk = { (bf16)lv[4 * g], (bf16)lv[4 * g + 1],
                          (bf16)lv[4 * g + 2], (bf16)lv[4 * g + 3] };
            *(bf16x4*)(lp + 4 * g) = pk;
        }
    }
    __syncthreads();

    const int wave = t >> 6, lane = t & 63, q = lane >> 4, ln = lane & 15;
    f32x4 acc[4];
#pragma unroll
    for (int mt = 0; mt < 4; ++mt) acc[mt] = (f32x4){0.f, 0.f, 0.f, 0.f};

#pragma unroll
    for (int ks = 0; ks < KS; ++ks) {
        const bf16x8 bfr = *(const bf16x8*)&wlds[ln * KPP + ks * 32 + q * 8];
        int k0 = ks * 32 + q * 8;
        int tap = k0 / CINP;
        int ci0 = k0 - tap * CINP;
        if (tap > 8) { tap = 0; ci0 = 0; }
        const int ky = tap / 3, kx = tap - 3 * ky;
        const int aoff = (ky * DIL * TW + kx * DIL) * CSTR + ci0;
#pragma unroll
        for (int mt = 0; mt < 4; ++mt) {
            const bf16x8 af = *(const bf16x8*)
                &tile[((wave * 4 + mt) * TW + ln) * CSTR + aoff];
            acc[mt] = __builtin_amdgcn_mfma_f32_16x16x32_bf16(af, bfr, acc[mt], 0, 0, 0);
        }
    }

    __syncthreads();                       // done reading tile -> reuse as logits
    float* slog = (float*)tile;            // 256*6*4 = 6144 B <= 15552 B
    const float bv = (ln < COUT) ? bias[ln] : 0.f;
#pragma unroll
    for (int mt = 0; mt < 4; ++mt)
#pragma unroll
        for (int r = 0; r < 4; ++r)
            if (ln < COUT) {
                const int pl = (wave * 4 + mt) * 16 + q * 4 + r;
                slog[pl * COUT + ln] = acc[mt][r] + bv;
            }
    __syncthreads();

    float e[COUT];
    float mx = slog[t * COUT];
#pragma unroll
    for (int co = 1; co < COUT; ++co) mx = fmaxf(mx, slog[t * COUT + co]);
    float sm = 0.f;
#pragma unroll
    for (int co = 0; co < COUT; ++co) { e[co] = __expf(slog[t * COUT + co] - mx); sm += e[co]; }
    const float inv = 1.f / sm;
    bf16* f = (bf16*)(wsA + (size_t)s * SA_BYTES);
    const int prow = ti * TS + (t >> 4), pcol = tj * TS + (t & 15);
    bf16* fp = f + ((size_t)prow * W_ + pcol) * 6;
#pragma unroll
    for (int co = 0; co < COUT; ++co) fp[co] = (bf16)(e[co] * inv);
}

// ---------------------------------------------------------------------------
// Integral images of x and x^2 (fp64), nb samples.
// ---------------------------------------------------------------------------
__global__ __launch_bounds__(BDIM) void rowscan(
    const float* __restrict__ x, char* __restrict__ wsA, int nwaves)
{
    const int gwave = (int)((blockIdx.x * (size_t)BDIM + threadIdx.x) >> 6);
    if (gwave >= nwaves) return;
    const int s = gwave / IH;
    const int r = gwave - s * IH;
    const int lane = threadIdx.x & 63;
    double* r1 = (double*)(wsA + (size_t)s * SA_BYTES + OFF_II1) + (size_t)r * IW;
    double* r2 = (double*)(wsA + (size_t)s * SA_BYTES + OFF_II2) + (size_t)r * IW;
    if (r == 0) {
        for (int j = lane; j < IW; j += 64) { r1[j] = 0.0; r2[j] = 0.0; }
        return;
    }
    const float* xr = x + (size_t)s * HW_ + (size_t)(r - 1) * W_;
    if (lane == 0) { r1[0] = 0.0; r2[0] = 0.0; }
    double c1 = 0.0, c2 = 0.0;
    for (int seg = 0; seg < W_ / 64; ++seg) {
        const float xv = xr[seg * 64 + lane];
        double v1 = (double)xv, v2 = (double)xv * (double)xv;
#pragma unroll
        for (int d = 1; d < 64; d <<= 1) {
            double t1 = __shfl_up(v1, d);
            double t2 = __shfl_up(v2, d);
            if (lane >= d) { v1 += t1; v2 += t2; }
        }
        v1 += c1; v2 += c2;
        r1[seg * 64 + lane + 1] = v1;
        r2[seg * 64 + lane + 1] = v2;
        c1 = __shfl(v1, 63);
        c2 = __shfl(v2, 63);
    }
}

__global__ __launch_bounds__(BDIM) void colscan(
    char* __restrict__ wsA, int total)   // total = nb*2*IW
{
    const int t = blockIdx.x * BDIM + threadIdx.x;
    if (t >= total) return;
    const int s = t / (2 * IW);
    const int rem = t - s * (2 * IW);
    const int which = rem / IW;
    const int j = rem - which * IW;
    double* p = (double*)(wsA + (size_t)s * SA_BYTES + (which ? OFF_II2 : OFF_II1));
    double acc = p[(size_t)1 * IW + j];
    for (int i = 2; i <= H_; ++i) {
        acc += p[(size_t)i * IW + j];
        p[(size_t)i * IW + j] = acc;
    }
}

// ---------------------------------------------------------------------------
// Final: 6 Sauvola thresholds, softmax-weighted sum, out = (x - th1)*alpha
// ---------------------------------------------------------------------------
__global__ __launch_bounds__(BDIM) void sauvola_out(
    const float* __restrict__ x, const char* __restrict__ wsA,
    const float* __restrict__ kArr, const float* __restrict__ RArr,
    const float* __restrict__ alphaP, float* __restrict__ outp)
{
    const int gid = blockIdx.x * BDIM + threadIdx.x;
    const int s = gid / HW_;
    const int pix = gid - s * HW_;
    const int i = pix / W_, j = pix - i * W_;
    const float xv = x[gid];
    const bf16* fp = (const bf16*)(wsA + (size_t)s * SA_BYTES) + (size_t)pix * 6;
    const double* ii1 = (const double*)(wsA + (size_t)s * SA_BYTES + OFF_II1);
    const double* ii2 = (const double*)(wsA + (size_t)s * SA_BYTES + OFF_II2);
    const float alpha = alphaP[0];

    const int wins[6] = {3, 5, 7, 11, 15, 19};
    float th1 = 0.f;
#pragma unroll
    for (int wi = 0; wi < 6; ++wi) {
        const int r = wins[wi] >> 1;
        const int r0 = max(i - r, 0), r1i = min(i + r, H_ - 1);
        const int c0 = max(j - r, 0), c1 = min(j + r, W_ - 1);
        const float cnt = (float)((r1i - r0 + 1) * (c1 - c0 + 1));
        const double* rt1 = ii1 + (size_t)r0 * IW;
        const double* rb1 = ii1 + (size_t)(r1i + 1) * IW;
        const double* rt2 = ii2 + (size_t)r0 * IW;
        const double* rb2 = ii2 + (size_t)(r1i + 1) * IW;
        const double s1 = rb1[c1 + 1] - rt1[c1 + 1] - rb1[c0] + rt1[c0];
        const double s2 = rb2[c1 + 1] - rt2[c1 + 1] - rb2[c0] + rt2[c0];
        const float invc = 1.f / cnt;
        const float Ex = (float)s1 * invc;
        const float Ex2 = (float)s2 * invc;
        const float dev = sqrtf(fmaxf(Ex2 - Ex * Ex, 1e-6f));
        const float th = Ex * (1.f + kArr[wi] * (dev / RArr[wi] - 1.f));
        th1 = fmaf((float)fp[wi], th, th1);
    }
    outp[gid] = (xv - th1) * alpha;
}

// ---------------------------------------------------------------------------
extern "C" void kernel_launch(void* const* d_in, const int* in_sizes, int n_in,
                              void* d_out, int out_size, void* d_ws, size_t ws_size,
                              hipStream_t stream) {
    const float* x   = (const float*)d_in[0];
    const float* w0  = (const float*)d_in[1];  const float* b0 = (const float*)d_in[2];
    const float* w1  = (const float*)d_in[3];  const float* b1 = (const float*)d_in[4];
    const float* w2  = (const float*)d_in[5];  const float* b2 = (const float*)d_in[6];
    const float* w3  = (const float*)d_in[7];  const float* b3 = (const float*)d_in[8];
    const float* w4  = (const float*)d_in[9];  const float* b4 = (const float*)d_in[10];
    const float* w5  = (const float*)d_in[11]; const float* b5 = (const float*)d_in[12];
    const float* wf  = (const float*)d_in[13]; const float* bf = (const float*)d_in[14];
    const float* kA  = (const float*)d_in[15];
    const float* RA  = (const float*)d_in[16];
    const float* alp = (const float*)d_in[17];
    float* out = (float*)d_out;
    (void)n_in; (void)in_sizes; (void)out_size;

    // partials + stats live in the TAIL of d_out: each iteration writes them
    // before reading; only the final chunk's sauvola_out overwrites the tail,
    // and that happens after the last partials/stats use. Valid for nb=1/2/4.
    float* partials = out + (OUT_ELEMS - PMAX_FLOATS - 256);
    float* stats    = out + (OUT_ELEMS - 224);

    // ---- choose samples-per-launch from ws_size (deterministic) ----
    auto need = [](int nb) -> size_t {
        size_t o = 0;
        auto al = [&](size_t bytes) { o += (bytes + 255) & ~(size_t)255; };
        al((size_t)nb * HW_ * 20 * 2);          // bufA (bf16)
        al((size_t)nb * HW_ * 24 * 2);          // bufB (bf16)
        al(1664 * 2); al(1664 * 2); al(1664 * 2); al(2688 * 2);
        al(5376 * 2); al(7424 * 2); al(3712 * 2);
        return o;
    };
    int nb = 1;
    if (ws_size >= need(4)) nb = 4;
    else if (ws_size >= need(2)) nb = 2;

    char* ws = (char*)d_ws;
    size_t off = 0;
    auto alloc = [&](size_t bytes) -> void* {
        void* p = ws + off;
        off += (bytes + 255) & ~(size_t)255;
        return p;
    };
    bf16*  bufA = (bf16*)alloc((size_t)nb * HW_ * 20 * 2);
    bf16*  bufB = (bf16*)alloc((size_t)nb * HW_ * 24 * 2);
    bf16* r0 = (bf16*)alloc(1664 * 2);
    bf16* r1 = (bf16*)alloc(1664 * 2);
    bf16* r2 = (bf16*)alloc(1664 * 2);
    bf16* r3 = (bf16*)alloc(2688 * 2);
    bf16* r4 = (bf16*)alloc(5376 * 2);
    bf16* r5 = (bf16*)alloc(7424 * 2);
    bf16* rf = (bf16*)alloc(3712 * 2);
    char* wsA = (char*)bufA;   // fbuf(bf16)/ii1/ii2 carved per sample

    const dim3 blk(BDIM);
    const int cg = nb * NBLK;

    repack_all<<<7, blk, 0, stream>>>(w0, w1, w2, w3, w4, w5, wf,
                                      r0, r1, r2, r3, r4, r5, rf);

    for (int it = 0; it < B_ / nb; ++it) {
        const float* xc   = x   + (size_t)it * nb * HW_;
        float*       outc = out + (size_t)it * nb * HW_;

        conv_mfma<1, 8, 4, 1, true><<<cg, blk, 0, stream>>>(xc, nullptr, r0, b0, bufA, partials);
        reduce_stats<4><<<nb * 4, blk, 0, stream>>>(partials, stats);

        conv_mfma<4, 8, 8, 2, false><<<cg, blk, 0, stream>>>(bufA, stats, r1, b1, bufB, partials);
        reduce_stats<8><<<nb * 8, blk, 0, stream>>>(partials, stats);

        conv_mfma<8, 8, 12, 2, false><<<cg, blk, 0, stream>>>(bufB, stats, r2, b2, bufA, partials);
        reduce_stats<12><<<nb * 12, blk, 0, stream>>>(partials, stats);

        conv_mfma<12, 16, 16, 2, false><<<cg, blk, 0, stream>>>(bufA, stats, r3, b3, bufB, partials);
        reduce_stats<16><<<nb * 16, blk, 0, stream>>>(partials, stats);

        conv_mfma<16, 16, 20, 2, false><<<cg, blk, 0, stream>>>(bufB, stats, r4, b4, bufA, partials);
        reduce_stats<20><<<nb * 20, blk, 0, stream>>>(partials, stats);

        conv_mfma<20, 24, 24, 2, false><<<cg, blk, 0, stream>>>(bufA, stats, r5, b5, bufB, partials);
        reduce_stats<24><<<nb * 24, blk, 0, stream>>>(partials, stats);

        // bufA region now dead -> fbuf / ii1 / ii2 alias into it per sample
        conv2_softmax_mfma<<<cg, blk, 0, stream>>>(bufB, stats, rf, bf, wsA);

        rowscan<<<(nb * IH * 64 + BDIM - 1) / BDIM, blk, 0, stream>>>(xc, wsA, nb * IH);
        colscan<<<(nb * 2 * IW + BDIM - 1) / BDIM, blk, 0, stream>>>(wsA, nb * 2 * IW);

        sauvola_out<<<nb * HW_ / BDIM, blk, 0, stream>>>(xc, wsA, kA, RA, alp, outc);
    }
}

// Round 8
// 514.576 us; speedup vs baseline: 13.2538x; 1.0580x over previous
//
#include <hip/hip_runtime.h>
#include <math.h>

#define BDIM 256
typedef __bf16 bf16;
typedef __bf16 bf16x4 __attribute__((ext_vector_type(4)));
typedef __bf16 bf16x8 __attribute__((ext_vector_type(8)));
typedef float f32x4 __attribute__((ext_vector_type(4)));

constexpr int B_ = 4, H_ = 768, W_ = 768;
constexpr int HW_ = H_ * W_;                 // 589824
constexpr int TS = 16;                       // spatial tile 16x16 px/block
constexpr int NTB = W_ / TS;                 // 48
constexpr int NBLK = HW_ / (TS * TS);        // 2304 blocks per sample
constexpr int IH = H_ + 1, IW = W_ + 1;      // 769

// per-sample span of bufA (20ch bf16); fbuf(bf16 [HW][6]) + fp64 integral
// images alias into it after the last conv consumes bufA.
constexpr size_t SA_BYTES = (size_t)HW_ * 20 * 2;   // 23,592,960
constexpr size_t OFF_II1  = (size_t)HW_ * 6 * 2;    // 7,077,888 (after fbuf)
constexpr size_t II_SPAN  = 4731136;                // 769*769*8 rounded to 256
constexpr size_t OFF_II2  = OFF_II1 + II_SPAN;      // 11,809,024 (+II_SPAN < SA)

// scratch carved from the TAIL of d_out (written before read each iteration;
// the final sauvola_out of the last chunk overwrites it after last use):
constexpr int PMAX_FLOATS = 4 * NBLK * 48;          // 442368
constexpr int OUT_ELEMS   = B_ * HW_;               // 2359296

// ---------------------------------------------------------------------------
// Weight repack: [COUT][CIN][3][3] fp32 -> padded bf16 [NT*16][KPP],
// k = tap*CINP + ci, zero everywhere outside (n<COUT, tap<9, ci<CIN).
// ---------------------------------------------------------------------------
__device__ void repack_one(const float* __restrict__ src, bf16* __restrict__ dst,
                           int CIN, int CINP, int COUT, int NT16, int KPP)
{
    const int n_ = NT16 * KPP;
    for (int idx = threadIdx.x; idx < n_; idx += BDIM) {
        const int n = idx / KPP, k = idx - n * KPP;
        const int tap = k / CINP, ci = k - tap * CINP;
        float v = 0.f;
        if (n < COUT && tap < 9 && ci < CIN)
            v = src[(n * CIN + ci) * 9 + tap];
        dst[idx] = (bf16)v;
    }
}

__global__ __launch_bounds__(BDIM) void repack_all(
    const float* w0, const float* w1, const float* w2, const float* w3,
    const float* w4, const float* w5, const float* wf,
    bf16* r0, bf16* r1, bf16* r2, bf16* r3, bf16* r4, bf16* r5, bf16* rf)
{
    switch (blockIdx.x) {
        case 0: repack_one(w0, r0, 1,  8,  4,  16, 104); break;
        case 1: repack_one(w1, r1, 4,  8,  8,  16, 104); break;
        case 2: repack_one(w2, r2, 8,  8,  12, 16, 104); break;
        case 3: repack_one(w3, r3, 12, 16, 16, 16, 168); break;
        case 4: repack_one(w4, r4, 16, 16, 20, 32, 168); break;
        case 5: repack_one(w5, r5, 20, 24, 24, 32, 232); break;
        case 6: repack_one(wf, rf, 24, 24, 6,  16, 232); break;
    }
}

// ---------------------------------------------------------------------------
// bf16-MFMA conv 3x3 (dilated, SAME) + bias, NHWC, nb samples (grid=nb*NBLK).
// Halo tile staged channel-innermost bf16 (prev-layer norm+relu fused, OOB=0).
// GEMM: M=256 px, N=COUT (NT x16), K=9*CINP (KS x32). fp32 accum.
// Weights are NOT staged in LDS: identical across all blocks -> L1-resident;
// B-fragments are loaded straight from global in the K-loop. This keeps LDS
// ~20 KB -> 8 blocks/CU instead of 4 (occupancy was the R7 limiter).
// Epilogue round-trips through LDS for contiguous per-pixel global stores.
// ---------------------------------------------------------------------------
template <int CIN, int CINP, int COUT, int DIL, bool FIRST>
__global__ __launch_bounds__(BDIM) void conv_mfma(
    const void* __restrict__ inv,        // FIRST: fp32 x; else bf16 y_prev
    const float* __restrict__ prevStats, // [nb][CIN][2] (mean, invstd)
    const bf16* __restrict__ wp,         // packed [NT*16][KPP]
    const float* __restrict__ bias,      // [COUT] fp32
    bf16* __restrict__ y,                // [nb][H][W][COUT]
    float* __restrict__ partials)        // [nb][NBLK][2*COUT]
{
    constexpr int TW = TS + 2 * DIL;
    constexpr int KP = ((9 * CINP + 31) / 32) * 32;
    constexpr int KPP = KP + 8;
    constexpr int NT = (COUT + 15) / 16;
    constexpr int KS = KP / 32;
    constexpr int CSTR = (CINP == 16) ? 24 : CINP;   // multiple of 8 (b128 align)
    __shared__ __align__(16) bf16 tile[TW * TW * CSTR];
    __shared__ float sred[4][2 * COUT];

    const int s = blockIdx.x / NBLK;
    const int blk = blockIdx.x - s * NBLK;
    const int ti = blk / NTB, tj = blk - ti * NTB;
    const int i0 = ti * TS - DIL, j0 = tj * TS - DIL;
    const int t = threadIdx.x;

    // ---- stage halo tile (vector loads, packed LDS writes) ----
    for (int loc = t; loc < TW * TW; loc += BDIM) {
        const int rr = loc / TW, cc = loc - rr * TW;
        const int gi = i0 + rr, gj = j0 + cc;
        const bool ok = (gi >= 0) & (gi < H_) & (gj >= 0) & (gj < W_);
        float lv[CSTR];
#pragma unroll
        for (int c = 0; c < CSTR; ++c) lv[c] = 0.f;
        if (ok) {
            if constexpr (FIRST) {
                const float* xg = (const float*)inv + (size_t)s * HW_;
                lv[0] = xg[(size_t)gi * W_ + gj];
            } else {
                const bf16* ing = (const bf16*)inv +
                                  ((size_t)s * HW_ + (size_t)gi * W_ + gj) * CIN;
                const float* ps = prevStats + s * 2 * CIN;
                if constexpr (CIN % 8 == 0) {
#pragma unroll
                    for (int qq = 0; qq < CIN / 8; ++qq) {
                        bf16x8 raw = ((const bf16x8*)ing)[qq];
#pragma unroll
                        for (int u = 0; u < 8; ++u) {
                            const int ci = 8 * qq + u;
                            lv[ci] = fmaxf(((float)raw[u] - ps[2 * ci]) * ps[2 * ci + 1], 0.f);
                        }
                    }
                } else {
#pragma unroll
                    for (int qq = 0; qq < CIN / 4; ++qq) {
                        bf16x4 raw = ((const bf16x4*)ing)[qq];
#pragma unroll
                        for (int u = 0; u < 4; ++u) {
                            const int ci = 4 * qq + u;
                            lv[ci] = fmaxf(((float)raw[u] - ps[2 * ci]) * ps[2 * ci + 1], 0.f);
                        }
                    }
                }
            }
        }
        bf16* lp = tile + loc * CSTR;
#pragma unroll
        for (int g = 0; g < CSTR / 4; ++g) {
            bf16x4 pk = { (bf16)lv[4 * g], (bf16)lv[4 * g + 1],
                          (bf16)lv[4 * g + 2], (bf16)lv[4 * g + 3] };
            *(bf16x4*)(lp + 4 * g) = pk;
        }
    }
    __syncthreads();

    // ---- MFMA K-loop (B-fragments from global/L1) ----
    const int wave = t >> 6, lane = t & 63, q = lane >> 4, ln = lane & 15;
    f32x4 acc[4][NT];
#pragma unroll
    for (int mt = 0; mt < 4; ++mt)
#pragma unroll
        for (int u = 0; u < NT; ++u) acc[mt][u] = (f32x4){0.f, 0.f, 0.f, 0.f};

#pragma unroll
    for (int ks = 0; ks < KS; ++ks) {
        bf16x8 bfr[NT];
#pragma unroll
        for (int u = 0; u < NT; ++u)
            bfr[u] = *(const bf16x8*)&wp[(u * 16 + ln) * KPP + ks * 32 + q * 8];
        int k0 = ks * 32 + q * 8;
        int tap = k0 / CINP;
        int ci0 = k0 - tap * CINP;
        if (tap > 8) { tap = 0; ci0 = 0; }   // padded k: B rows are zero
        const int ky = tap / 3, kx = tap - 3 * ky;
        const int aoff = (ky * DIL * TW + kx * DIL) * CSTR + ci0;
#pragma unroll
        for (int mt = 0; mt < 4; ++mt) {
            const bf16x8 af = *(const bf16x8*)
                &tile[((wave * 4 + mt) * TW + ln) * CSTR + aoff];
#pragma unroll
            for (int u = 0; u < NT; ++u)
                acc[mt][u] = __builtin_amdgcn_mfma_f32_16x16x32_bf16(
                    af, bfr[u], acc[mt][u], 0, 0, 0);
        }
    }

    // ---- bias + stats (registers), sred ----
#pragma unroll
    for (int u = 0; u < NT; ++u) {
        const int n = u * 16 + ln;
        const float bv = (n < COUT) ? bias[n] : 0.f;
        float s1 = 0.f, s2 = 0.f;
#pragma unroll
        for (int mt = 0; mt < 4; ++mt)
#pragma unroll
            for (int r = 0; r < 4; ++r) {
                const float v = acc[mt][u][r] + bv;
                acc[mt][u][r] = v;
                s1 += v; s2 += v * v;
            }
        s1 += __shfl_xor(s1, 16); s1 += __shfl_xor(s1, 32);
        s2 += __shfl_xor(s2, 16); s2 += __shfl_xor(s2, 32);
        if (lane < 16 && n < COUT) { sred[wave][n] = s1; sred[wave][COUT + n] = s2; }
    }
    __syncthreads();   // K-loop tile reads complete + sred visible
    if (t < 2 * COUT) {
        partials[((size_t)s * NBLK + blk) * (2 * COUT) + t] =
            sred[0][t] + sred[1][t] + sred[2][t] + sred[3][t];
    }

    // ---- out-stage into LDS (reuse tile), then coalesced global stores ----
    bf16* ost = tile;   // 256*COUT bf16 <= tile capacity for all layers
#pragma unroll
    for (int u = 0; u < NT; ++u) {
        const int n = u * 16 + ln;
        if (n < COUT) {
#pragma unroll
            for (int mt = 0; mt < 4; ++mt)
#pragma unroll
                for (int r = 0; r < 4; ++r) {
                    const int pl = (wave * 4 + mt) * 16 + q * 4 + r;
                    ost[pl * COUT + n] = (bf16)acc[mt][u][r];
                }
        }
    }
    __syncthreads();

    const int lr = t >> 4, lc = t & 15;
    bf16* yp = y + (size_t)s * HW_ * COUT +
               ((size_t)(ti * TS + lr) * W_ + (tj * TS + lc)) * COUT;
    const bf16* sp = ost + t * COUT;
    if constexpr (COUT % 8 == 0) {
#pragma unroll
        for (int g = 0; g < COUT / 8; ++g)
            ((bf16x8*)yp)[g] = ((const bf16x8*)sp)[g];
    } else {
#pragma unroll
        for (int g = 0; g < COUT / 4; ++g)
            ((bf16x4*)yp)[g] = ((const bf16x4*)sp)[g];
    }
}

// ---------------------------------------------------------------------------
// Reduce per-block partials -> mean, invstd per (sample, channel)
// ---------------------------------------------------------------------------
template <int COUT>
__global__ __launch_bounds__(BDIM) void reduce_stats(
    const float* __restrict__ partials, float* __restrict__ stats)
{
    const int s = blockIdx.x / COUT;
    const int co = blockIdx.x - s * COUT;
    const float* P = partials + (size_t)s * NBLK * (2 * COUT);
    float s1 = 0.f, s2 = 0.f;
    for (int k = threadIdx.x; k < NBLK; k += BDIM) {
        const float* p = P + (size_t)k * (2 * COUT);
        s1 += p[co];
        s2 += p[COUT + co];
    }
#pragma unroll
    for (int off = 32; off; off >>= 1) {
        s1 += __shfl_xor(s1, off);
        s2 += __shfl_xor(s2, off);
    }
    __shared__ float l1[4], l2[4];
    const int lane = threadIdx.x & 63, wave = threadIdx.x >> 6;
    if (lane == 0) { l1[wave] = s1; l2[wave] = s2; }
    __syncthreads();
    if (threadIdx.x == 0) {
        float t1 = l1[0] + l1[1] + l1[2] + l1[3];
        float t2 = l2[0] + l2[1] + l2[2] + l2[3];
        float m = t1 / (float)HW_;
        float var = t2 / (float)HW_ - m * m;
        stats[((size_t)s * COUT + co) * 2 + 0] = m;
        stats[((size_t)s * COUT + co) * 2 + 1] = rsqrtf(var + 1e-5f);
    }
}

// ---------------------------------------------------------------------------
// conv2 (24->6, dil 1) MFMA + folded norm of layer 5 + channel softmax.
// Weights from global/L1 (no LDS staging).
// ---------------------------------------------------------------------------
__global__ __launch_bounds__(BDIM) void conv2_softmax_mfma(
    const bf16* __restrict__ in, const float* __restrict__ prevStats,
    const bf16* __restrict__ wp, const float* __restrict__ bias,
    char* __restrict__ wsA)
{
    constexpr int CIN = 24, CINP = 24, COUT = 6, DIL = 1;
    constexpr int TW = TS + 2 * DIL;      // 18
    constexpr int KPP = 232, KS = 7, CSTR = 24;
    __shared__ __align__(16) bf16 tile[TW * TW * CSTR];   // 15552 B

    const int s = blockIdx.x / NBLK;
    const int blk = blockIdx.x - s * NBLK;
    const int ti = blk / NTB, tj = blk - ti * NTB;
    const int i0 = ti * TS - DIL, j0 = tj * TS - DIL;
    const int t = threadIdx.x;

    const float* ps = prevStats + s * 2 * CIN;
    for (int loc = t; loc < TW * TW; loc += BDIM) {
        const int rr = loc / TW, cc = loc - rr * TW;
        const int gi = i0 + rr, gj = j0 + cc;
        const bool ok = (gi >= 0) & (gi < H_) & (gj >= 0) & (gj < W_);
        float lv[CSTR];
#pragma unroll
        for (int c = 0; c < CSTR; ++c) lv[c] = 0.f;
        if (ok) {
            const bf16* ing = in + ((size_t)s * HW_ + (size_t)gi * W_ + gj) * CIN;
#pragma unroll
            for (int qq = 0; qq < CIN / 8; ++qq) {
                bf16x8 raw = ((const bf16x8*)ing)[qq];
#pragma unroll
                for (int u = 0; u < 8; ++u) {
                    const int ci = 8 * qq + u;
                    lv[ci] = fmaxf(((float)raw[u] - ps[2 * ci]) * ps[2 * ci + 1], 0.f);
                }
            }
        }
        bf16* lp = tile + loc * CSTR;
#pragma unroll
        for (int g = 0; g < CSTR / 4; ++g) {
            bf16x4 pk = { (bf16)lv[4 * g], (bf16)lv[4 * g + 1],
                          (bf16)lv[4 * g + 2], (bf16)lv[4 * g + 3] };
            *(bf16x4*)(lp + 4 * g) = pk;
        }
    }
    __syncthreads();

    const int wave = t >> 6, lane = t & 63, q = lane >> 4, ln = lane & 15;
    f32x4 acc[4];
#pragma unroll
    for (int mt = 0; mt < 4; ++mt) acc[mt] = (f32x4){0.f, 0.f, 0.f, 0.f};

#pragma unroll
    for (int ks = 0; ks < KS; ++ks) {
        const bf16x8 bfr = *(const bf16x8*)&wp[ln * KPP + ks * 32 + q * 8];
        int k0 = ks * 32 + q * 8;
        int tap = k0 / CINP;
        int ci0 = k0 - tap * CINP;
        if (tap > 8) { tap = 0; ci0 = 0; }
        const int ky = tap / 3, kx = tap - 3 * ky;
        const int aoff = (ky * DIL * TW + kx * DIL) * CSTR + ci0;
#pragma unroll
        for (int mt = 0; mt < 4; ++mt) {
            const bf16x8 af = *(const bf16x8*)
                &tile[((wave * 4 + mt) * TW + ln) * CSTR + aoff];
            acc[mt] = __builtin_amdgcn_mfma_f32_16x16x32_bf16(af, bfr, acc[mt], 0, 0, 0);
        }
    }

    __syncthreads();                       // done reading tile -> reuse as logits
    float* slog = (float*)tile;            // 256*6*4 = 6144 B <= 15552 B
    const float bv = (ln < COUT) ? bias[ln] : 0.f;
#pragma unroll
    for (int mt = 0; mt < 4; ++mt)
#pragma unroll
        for (int r = 0; r < 4; ++r)
            if (ln < COUT) {
                const int pl = (wave * 4 + mt) * 16 + q * 4 + r;
                slog[pl * COUT + ln] = acc[mt][r] + bv;
            }
    __syncthreads();

    float e[COUT];
    float mx = slog[t * COUT];
#pragma unroll
    for (int co = 1; co < COUT; ++co) mx = fmaxf(mx, slog[t * COUT + co]);
    float sm = 0.f;
#pragma unroll
    for (int co = 0; co < COUT; ++co) { e[co] = __expf(slog[t * COUT + co] - mx); sm += e[co]; }
    const float inv = 1.f / sm;
    bf16* f = (bf16*)(wsA + (size_t)s * SA_BYTES);
    const int prow = ti * TS + (t >> 4), pcol = tj * TS + (t & 15);
    bf16* fp = f + ((size_t)prow * W_ + pcol) * 6;
#pragma unroll
    for (int co = 0; co < COUT; ++co) fp[co] = (bf16)(e[co] * inv);
}

// ---------------------------------------------------------------------------
// Integral images of x and x^2 (fp64), nb samples.
// ---------------------------------------------------------------------------
__global__ __launch_bounds__(BDIM) void rowscan(
    const float* __restrict__ x, char* __restrict__ wsA, int nwaves)
{
    const int gwave = (int)((blockIdx.x * (size_t)BDIM + threadIdx.x) >> 6);
    if (gwave >= nwaves) return;
    const int s = gwave / IH;
    const int r = gwave - s * IH;
    const int lane = threadIdx.x & 63;
    double* r1 = (double*)(wsA + (size_t)s * SA_BYTES + OFF_II1) + (size_t)r * IW;
    double* r2 = (double*)(wsA + (size_t)s * SA_BYTES + OFF_II2) + (size_t)r * IW;
    if (r == 0) {
        for (int j = lane; j < IW; j += 64) { r1[j] = 0.0; r2[j] = 0.0; }
        return;
    }
    const float* xr = x + (size_t)s * HW_ + (size_t)(r - 1) * W_;
    if (lane == 0) { r1[0] = 0.0; r2[0] = 0.0; }
    double c1 = 0.0, c2 = 0.0;
    for (int seg = 0; seg < W_ / 64; ++seg) {
        const float xv = xr[seg * 64 + lane];
        double v1 = (double)xv, v2 = (double)xv * (double)xv;
#pragma unroll
        for (int d = 1; d < 64; d <<= 1) {
            double t1 = __shfl_up(v1, d);
            double t2 = __shfl_up(v2, d);
            if (lane >= d) { v1 += t1; v2 += t2; }
        }
        v1 += c1; v2 += c2;
        r1[seg * 64 + lane + 1] = v1;
        r2[seg * 64 + lane + 1] = v2;
        c1 = __shfl(v1, 63);
        c2 = __shfl(v2, 63);
    }
}

__global__ __launch_bounds__(BDIM) void colscan(
    char* __restrict__ wsA, int total)   // total = nb*2*IW
{
    const int t = blockIdx.x * BDIM + threadIdx.x;
    if (t >= total) return;
    const int s = t / (2 * IW);
    const int rem = t - s * (2 * IW);
    const int which = rem / IW;
    const int j = rem - which * IW;
    double* p = (double*)(wsA + (size_t)s * SA_BYTES + (which ? OFF_II2 : OFF_II1));
    double acc = p[(size_t)1 * IW + j];
    for (int i = 2; i <= H_; ++i) {
        acc += p[(size_t)i * IW + j];
        p[(size_t)i * IW + j] = acc;
    }
}

// ---------------------------------------------------------------------------
// Final: 6 Sauvola thresholds, softmax-weighted sum, out = (x - th1)*alpha
// ---------------------------------------------------------------------------
__global__ __launch_bounds__(BDIM) void sauvola_out(
    const float* __restrict__ x, const char* __restrict__ wsA,
    const float* __restrict__ kArr, const float* __restrict__ RArr,
    const float* __restrict__ alphaP, float* __restrict__ outp)
{
    const int gid = blockIdx.x * BDIM + threadIdx.x;
    const int s = gid / HW_;
    const int pix = gid - s * HW_;
    const int i = pix / W_, j = pix - i * W_;
    const float xv = x[gid];
    const bf16* fp = (const bf16*)(wsA + (size_t)s * SA_BYTES) + (size_t)pix * 6;
    const double* ii1 = (const double*)(wsA + (size_t)s * SA_BYTES + OFF_II1);
    const double* ii2 = (const double*)(wsA + (size_t)s * SA_BYTES + OFF_II2);
    const float alpha = alphaP[0];

    const int wins[6] = {3, 5, 7, 11, 15, 19};
    float th1 = 0.f;
#pragma unroll
    for (int wi = 0; wi < 6; ++wi) {
        const int r = wins[wi] >> 1;
        const int r0 = max(i - r, 0), r1i = min(i + r, H_ - 1);
        const int c0 = max(j - r, 0), c1 = min(j + r, W_ - 1);
        const float cnt = (float)((r1i - r0 + 1) * (c1 - c0 + 1));
        const double* rt1 = ii1 + (size_t)r0 * IW;
        const double* rb1 = ii1 + (size_t)(r1i + 1) * IW;
        const double* rt2 = ii2 + (size_t)r0 * IW;
        const double* rb2 = ii2 + (size_t)(r1i + 1) * IW;
        const double s1 = rb1[c1 + 1] - rt1[c1 + 1] - rb1[c0] + rt1[c0];
        const double s2 = rb2[c1 + 1] - rt2[c1 + 1] - rb2[c0] + rt2[c0];
        const float invc = 1.f / cnt;
        const float Ex = (float)s1 * invc;
        const float Ex2 = (float)s2 * invc;
        const float dev = sqrtf(fmaxf(Ex2 - Ex * Ex, 1e-6f));
        const float th = Ex * (1.f + kArr[wi] * (dev / RArr[wi] - 1.f));
        th1 = fmaf((float)fp[wi], th, th1);
    }
    outp[gid] = (xv - th1) * alpha;
}

// ---------------------------------------------------------------------------
extern "C" void kernel_launch(void* const* d_in, const int* in_sizes, int n_in,
                              void* d_out, int out_size, void* d_ws, size_t ws_size,
                              hipStream_t stream) {
    const float* x   = (const float*)d_in[0];
    const float* w0  = (const float*)d_in[1];  const float* b0 = (const float*)d_in[2];
    const float* w1  = (const float*)d_in[3];  const float* b1 = (const float*)d_in[4];
    const float* w2  = (const float*)d_in[5];  const float* b2 = (const float*)d_in[6];
    const float* w3  = (const float*)d_in[7];  const float* b3 = (const float*)d_in[8];
    const float* w4  = (const float*)d_in[9];  const float* b4 = (const float*)d_in[10];
    const float* w5  = (const float*)d_in[11]; const float* b5 = (const float*)d_in[12];
    const float* wf  = (const float*)d_in[13]; const float* bf = (const float*)d_in[14];
    const float* kA  = (const float*)d_in[15];
    const float* RA  = (const float*)d_in[16];
    const float* alp = (const float*)d_in[17];
    float* out = (float*)d_out;
    (void)n_in; (void)in_sizes; (void)out_size;

    // partials + stats live in the TAIL of d_out: each iteration writes them
    // before reading; only the final chunk's sauvola_out overwrites the tail,
    // and that happens after the last partials/stats use. Valid for nb=1/2/4.
    float* partials = out + (OUT_ELEMS - PMAX_FLOATS - 256);
    float* stats    = out + (OUT_ELEMS - 224);

    // ---- choose samples-per-launch from ws_size (deterministic) ----
    auto need = [](int nb) -> size_t {
        size_t o = 0;
        auto al = [&](size_t bytes) { o += (bytes + 255) & ~(size_t)255; };
        al((size_t)nb * HW_ * 20 * 2);          // bufA (bf16)
        al((size_t)nb * HW_ * 24 * 2);          // bufB (bf16)
        al(1664 * 2); al(1664 * 2); al(1664 * 2); al(2688 * 2);
        al(5376 * 2); al(7424 * 2); al(3712 * 2);
        return o;
    };
    int nb = 1;
    if (ws_size >= need(4)) nb = 4;
    else if (ws_size >= need(2)) nb = 2;

    char* ws = (char*)d_ws;
    size_t off = 0;
    auto alloc = [&](size_t bytes) -> void* {
        void* p = ws + off;
        off += (bytes + 255) & ~(size_t)255;
        return p;
    };
    bf16*  bufA = (bf16*)alloc((size_t)nb * HW_ * 20 * 2);
    bf16*  bufB = (bf16*)alloc((size_t)nb * HW_ * 24 * 2);
    bf16* r0 = (bf16*)alloc(1664 * 2);
    bf16* r1 = (bf16*)alloc(1664 * 2);
    bf16* r2 = (bf16*)alloc(1664 * 2);
    bf16* r3 = (bf16*)alloc(2688 * 2);
    bf16* r4 = (bf16*)alloc(5376 * 2);
    bf16* r5 = (bf16*)alloc(7424 * 2);
    bf16* rf = (bf16*)alloc(3712 * 2);
    char* wsA = (char*)bufA;   // fbuf(bf16)/ii1/ii2 carved per sample

    const dim3 blk(BDIM);
    const int cg = nb * NBLK;

    repack_all<<<7, blk, 0, stream>>>(w0, w1, w2, w3, w4, w5, wf,
                                      r0, r1, r2, r3, r4, r5, rf);

    for (int it = 0; it < B_ / nb; ++it) {
        const float* xc   = x   + (size_t)it * nb * HW_;
        float*       outc = out + (size_t)it * nb * HW_;

        conv_mfma<1, 8, 4, 1, true><<<cg, blk, 0, stream>>>(xc, nullptr, r0, b0, bufA, partials);
        reduce_stats<4><<<nb * 4, blk, 0, stream>>>(partials, stats);

        conv_mfma<4, 8, 8, 2, false><<<cg, blk, 0, stream>>>(bufA, stats, r1, b1, bufB, partials);
        reduce_stats<8><<<nb * 8, blk, 0, stream>>>(partials, stats);

        conv_mfma<8, 8, 12, 2, false><<<cg, blk, 0, stream>>>(bufB, stats, r2, b2, bufA, partials);
        reduce_stats<12><<<nb * 12, blk, 0, stream>>>(partials, stats);

        conv_mfma<12, 16, 16, 2, false><<<cg, blk, 0, stream>>>(bufA, stats, r3, b3, bufB, partials);
        reduce_stats<16><<<nb * 16, blk, 0, stream>>>(partials, stats);

        conv_mfma<16, 16, 20, 2, false><<<cg, blk, 0, stream>>>(bufB, stats, r4, b4, bufA, partials);
        reduce_stats<20><<<nb * 20, blk, 0, stream>>>(partials, stats);

        conv_mfma<20, 24, 24, 2, false><<<cg, blk, 0, stream>>>(bufA, stats, r5, b5, bufB, partials);
        reduce_stats<24><<<nb * 24, blk, 0, stream>>>(partials, stats);

        // bufA region now dead -> fbuf / ii1 / ii2 alias into it per sample
        conv2_softmax_mfma<<<cg, blk, 0, stream>>>(bufB, stats, rf, bf, wsA);

        rowscan<<<(nb * IH * 64 + BDIM - 1) / BDIM, blk, 0, stream>>>(xc, wsA, nb * IH);
        colscan<<<(nb * 2 * IW + BDIM - 1) / BDIM, blk, 0, stream>>>(wsA, nb * 2 * IW);

        sauvola_out<<<nb * HW_ / BDIM, blk, 0, stream>>>(xc, wsA, kA, RA, alp, outc);
    }
}

// Round 9
// 498.162 us; speedup vs baseline: 13.6905x; 1.0330x over previous
//
#include <hip/hip_runtime.h>
#include <math.h>

#define BDIM 256
typedef __bf16 bf16;
typedef __bf16 bf16x4 __attribute__((ext_vector_type(4)));
typedef __bf16 bf16x8 __attribute__((ext_vector_type(8)));
typedef float f32x4 __attribute__((ext_vector_type(4)));

constexpr int B_ = 4, H_ = 768, W_ = 768;
constexpr int HW_ = H_ * W_;                 // 589824
constexpr int TS = 16;                       // spatial tile 16x16 px/block
constexpr int NTB = W_ / TS;                 // 48
constexpr int NBLK = HW_ / (TS * TS);        // 2304 blocks per sample
constexpr int IH = H_ + 1, IW = W_ + 1;      // 769

// per-sample span of bufA (20ch bf16); fbuf(bf16 [HW][6]) + fp64 integral
// images alias into it after the last conv consumes bufA.
constexpr size_t SA_BYTES = (size_t)HW_ * 20 * 2;   // 23,592,960
constexpr size_t OFF_II1  = (size_t)HW_ * 6 * 2;    // 7,077,888 (after fbuf)
constexpr size_t II_SPAN  = 4731136;                // 769*769*8 rounded to 256
constexpr size_t OFF_II2  = OFF_II1 + II_SPAN;      // 11,809,024 (+II_SPAN < SA)

// scratch carved from the TAIL of d_out (written before read each iteration;
// the final sauvola_out of the last chunk overwrites it after last use):
constexpr int PMAX_FLOATS = 4 * NBLK * 48;          // 442368
constexpr int OUT_ELEMS   = B_ * HW_;               // 2359296

// ---------------------------------------------------------------------------
// Weight repack: [COUT][CIN][3][3] fp32 -> padded bf16 [NT*16][KPP],
// k = tap*CINP + ci, zero everywhere outside (n<COUT, tap<9, ci<CIN).
// ---------------------------------------------------------------------------
__device__ void repack_one(const float* __restrict__ src, bf16* __restrict__ dst,
                           int CIN, int CINP, int COUT, int NT16, int KPP)
{
    const int n_ = NT16 * KPP;
    for (int idx = threadIdx.x; idx < n_; idx += BDIM) {
        const int n = idx / KPP, k = idx - n * KPP;
        const int tap = k / CINP, ci = k - tap * CINP;
        float v = 0.f;
        if (n < COUT && tap < 9 && ci < CIN)
            v = src[(n * CIN + ci) * 9 + tap];
        dst[idx] = (bf16)v;
    }
}

__global__ __launch_bounds__(BDIM) void repack_all(
    const float* w0, const float* w1, const float* w2, const float* w3,
    const float* w4, const float* w5, const float* wf,
    bf16* r0, bf16* r1, bf16* r2, bf16* r3, bf16* r4, bf16* r5, bf16* rf)
{
    switch (blockIdx.x) {
        case 0: repack_one(w0, r0, 1,  8,  4,  16, 104); break;
        case 1: repack_one(w1, r1, 4,  8,  8,  16, 104); break;
        case 2: repack_one(w2, r2, 8,  8,  12, 16, 104); break;
        case 3: repack_one(w3, r3, 12, 16, 16, 16, 168); break;
        case 4: repack_one(w4, r4, 16, 16, 20, 32, 168); break;
        case 5: repack_one(w5, r5, 20, 24, 24, 32, 232); break;
        case 6: repack_one(wf, rf, 24, 24, 6,  16, 232); break;
    }
}

// ---------------------------------------------------------------------------
// bf16-MFMA conv 3x3 (dilated, SAME) + bias, NHWC, nb samples (grid=nb*NBLK).
// Halo tile staged channel-innermost bf16 (prev-layer norm+relu fused, OOB=0).
// GEMM: M=256 px, N=COUT (NT x16), K=9*CINP (KS x32). fp32 accum.
// Weights from global/L1 (identical across blocks). K-loop is software-
// pipelined one ks ahead (B from global, A from LDS) so MFMA of step k
// overlaps the ~200-cyc loads of step k+1 (R8 stall diagnosis).
// Epilogue round-trips through LDS for contiguous per-pixel global stores.
// ---------------------------------------------------------------------------
template <int CIN, int CINP, int COUT, int DIL, bool FIRST>
__global__ __launch_bounds__(BDIM) void conv_mfma(
    const void* __restrict__ inv,        // FIRST: fp32 x; else bf16 y_prev
    const float* __restrict__ prevStats, // [nb][CIN][2] (mean, invstd)
    const bf16* __restrict__ wp,         // packed [NT*16][KPP]
    const float* __restrict__ bias,      // [COUT] fp32
    bf16* __restrict__ y,                // [nb][H][W][COUT]
    float* __restrict__ partials)        // [nb][NBLK][2*COUT]
{
    constexpr int TW = TS + 2 * DIL;
    constexpr int KP = ((9 * CINP + 31) / 32) * 32;
    constexpr int KPP = KP + 8;
    constexpr int NT = (COUT + 15) / 16;
    constexpr int KS = KP / 32;
    constexpr int CSTR = (CINP == 16) ? 24 : CINP;   // multiple of 8 (b128 align)
    __shared__ __align__(16) bf16 tile[TW * TW * CSTR];
    __shared__ float sred[4][2 * COUT];

    const int s = blockIdx.x / NBLK;
    const int blk = blockIdx.x - s * NBLK;
    const int ti = blk / NTB, tj = blk - ti * NTB;
    const int i0 = ti * TS - DIL, j0 = tj * TS - DIL;
    const int t = threadIdx.x;

    // ---- stage halo tile (vector loads, packed LDS writes) ----
    for (int loc = t; loc < TW * TW; loc += BDIM) {
        const int rr = loc / TW, cc = loc - rr * TW;
        const int gi = i0 + rr, gj = j0 + cc;
        const bool ok = (gi >= 0) & (gi < H_) & (gj >= 0) & (gj < W_);
        float lv[CSTR];
#pragma unroll
        for (int c = 0; c < CSTR; ++c) lv[c] = 0.f;
        if (ok) {
            if constexpr (FIRST) {
                const float* xg = (const float*)inv + (size_t)s * HW_;
                lv[0] = xg[(size_t)gi * W_ + gj];
            } else {
                const bf16* ing = (const bf16*)inv +
                                  ((size_t)s * HW_ + (size_t)gi * W_ + gj) * CIN;
                const float* ps = prevStats + s * 2 * CIN;
                if constexpr (CIN % 8 == 0) {
#pragma unroll
                    for (int qq = 0; qq < CIN / 8; ++qq) {
                        bf16x8 raw = ((const bf16x8*)ing)[qq];
#pragma unroll
                        for (int u = 0; u < 8; ++u) {
                            const int ci = 8 * qq + u;
                            lv[ci] = fmaxf(((float)raw[u] - ps[2 * ci]) * ps[2 * ci + 1], 0.f);
                        }
                    }
                } else {
#pragma unroll
                    for (int qq = 0; qq < CIN / 4; ++qq) {
                        bf16x4 raw = ((const bf16x4*)ing)[qq];
#pragma unroll
                        for (int u = 0; u < 4; ++u) {
                            const int ci = 4 * qq + u;
                            lv[ci] = fmaxf(((float)raw[u] - ps[2 * ci]) * ps[2 * ci + 1], 0.f);
                        }
                    }
                }
            }
        }
        bf16* lp = tile + loc * CSTR;
#pragma unroll
        for (int g = 0; g < CSTR / 4; ++g) {
            bf16x4 pk = { (bf16)lv[4 * g], (bf16)lv[4 * g + 1],
                          (bf16)lv[4 * g + 2], (bf16)lv[4 * g + 3] };
            *(bf16x4*)(lp + 4 * g) = pk;
        }
    }
    __syncthreads();

    // ---- MFMA K-loop, software-pipelined 1 ks ahead ----
    const int wave = t >> 6, lane = t & 63, q = lane >> 4, ln = lane & 15;
    f32x4 acc[4][NT];
#pragma unroll
    for (int mt = 0; mt < 4; ++mt)
#pragma unroll
        for (int u = 0; u < NT; ++u) acc[mt][u] = (f32x4){0.f, 0.f, 0.f, 0.f};

    auto aOff = [&](int ks) -> int {
        int k0 = ks * 32 + q * 8;
        int tap = k0 / CINP;
        int ci0 = k0 - tap * CINP;
        if (tap > 8) { tap = 0; ci0 = 0; }   // padded k: B rows are zero
        const int ky = tap / 3, kx = tap - 3 * ky;
        return (ky * DIL * TW + kx * DIL) * CSTR + ci0;
    };

    bf16x8 bfr[NT], bfrN[NT];
    bf16x8 af[4], afN[4];
#pragma unroll
    for (int u = 0; u < NT; ++u)
        bfr[u] = *(const bf16x8*)&wp[(u * 16 + ln) * KPP + q * 8];
    {
        const int ao = aOff(0);
#pragma unroll
        for (int mt = 0; mt < 4; ++mt)
            af[mt] = *(const bf16x8*)&tile[((wave * 4 + mt) * TW + ln) * CSTR + ao];
    }

#pragma unroll
    for (int ks = 0; ks < KS; ++ks) {
        if (ks + 1 < KS) {
#pragma unroll
            for (int u = 0; u < NT; ++u)
                bfrN[u] = *(const bf16x8*)&wp[(u * 16 + ln) * KPP + (ks + 1) * 32 + q * 8];
            const int ao = aOff(ks + 1);
#pragma unroll
            for (int mt = 0; mt < 4; ++mt)
                afN[mt] = *(const bf16x8*)&tile[((wave * 4 + mt) * TW + ln) * CSTR + ao];
        }
#pragma unroll
        for (int mt = 0; mt < 4; ++mt)
#pragma unroll
            for (int u = 0; u < NT; ++u)
                acc[mt][u] = __builtin_amdgcn_mfma_f32_16x16x32_bf16(
                    af[mt], bfr[u], acc[mt][u], 0, 0, 0);
#pragma unroll
        for (int u = 0; u < NT; ++u) bfr[u] = bfrN[u];
#pragma unroll
        for (int mt = 0; mt < 4; ++mt) af[mt] = afN[mt];
    }

    // ---- bias + stats (registers), sred ----
#pragma unroll
    for (int u = 0; u < NT; ++u) {
        const int n = u * 16 + ln;
        const float bv = (n < COUT) ? bias[n] : 0.f;
        float s1 = 0.f, s2 = 0.f;
#pragma unroll
        for (int mt = 0; mt < 4; ++mt)
#pragma unroll
            for (int r = 0; r < 4; ++r) {
                const float v = acc[mt][u][r] + bv;
                acc[mt][u][r] = v;
                s1 += v; s2 += v * v;
            }
        s1 += __shfl_xor(s1, 16); s1 += __shfl_xor(s1, 32);
        s2 += __shfl_xor(s2, 16); s2 += __shfl_xor(s2, 32);
        if (lane < 16 && n < COUT) { sred[wave][n] = s1; sred[wave][COUT + n] = s2; }
    }
    __syncthreads();   // K-loop tile reads complete + sred visible
    if (t < 2 * COUT) {
        partials[((size_t)s * NBLK + blk) * (2 * COUT) + t] =
            sred[0][t] + sred[1][t] + sred[2][t] + sred[3][t];
    }

    // ---- out-stage into LDS (reuse tile), then coalesced global stores ----
    bf16* ost = tile;   // 256*COUT bf16 <= tile capacity for all layers
#pragma unroll
    for (int u = 0; u < NT; ++u) {
        const int n = u * 16 + ln;
        if (n < COUT) {
#pragma unroll
            for (int mt = 0; mt < 4; ++mt)
#pragma unroll
                for (int r = 0; r < 4; ++r) {
                    const int pl = (wave * 4 + mt) * 16 + q * 4 + r;
                    ost[pl * COUT + n] = (bf16)acc[mt][u][r];
                }
        }
    }
    __syncthreads();

    const int lr = t >> 4, lc = t & 15;
    bf16* yp = y + (size_t)s * HW_ * COUT +
               ((size_t)(ti * TS + lr) * W_ + (tj * TS + lc)) * COUT;
    const bf16* sp = ost + t * COUT;
    if constexpr (COUT % 8 == 0) {
#pragma unroll
        for (int g = 0; g < COUT / 8; ++g)
            ((bf16x8*)yp)[g] = ((const bf16x8*)sp)[g];
    } else {
#pragma unroll
        for (int g = 0; g < COUT / 4; ++g)
            ((bf16x4*)yp)[g] = ((const bf16x4*)sp)[g];
    }
}

// ---------------------------------------------------------------------------
// Reduce per-block partials -> mean, invstd per (sample, channel)
// ---------------------------------------------------------------------------
template <int COUT>
__global__ __launch_bounds__(BDIM) void reduce_stats(
    const float* __restrict__ partials, float* __restrict__ stats)
{
    const int s = blockIdx.x / COUT;
    const int co = blockIdx.x - s * COUT;
    const float* P = partials + (size_t)s * NBLK * (2 * COUT);
    float s1 = 0.f, s2 = 0.f;
    for (int k = threadIdx.x; k < NBLK; k += BDIM) {
        const float* p = P + (size_t)k * (2 * COUT);
        s1 += p[co];
        s2 += p[COUT + co];
    }
#pragma unroll
    for (int off = 32; off; off >>= 1) {
        s1 += __shfl_xor(s1, off);
        s2 += __shfl_xor(s2, off);
    }
    __shared__ float l1[4], l2[4];
    const int lane = threadIdx.x & 63, wave = threadIdx.x >> 6;
    if (lane == 0) { l1[wave] = s1; l2[wave] = s2; }
    __syncthreads();
    if (threadIdx.x == 0) {
        float t1 = l1[0] + l1[1] + l1[2] + l1[3];
        float t2 = l2[0] + l2[1] + l2[2] + l2[3];
        float m = t1 / (float)HW_;
        float var = t2 / (float)HW_ - m * m;
        stats[((size_t)s * COUT + co) * 2 + 0] = m;
        stats[((size_t)s * COUT + co) * 2 + 1] = rsqrtf(var + 1e-5f);
    }
}

// ---------------------------------------------------------------------------
// conv2 (24->6, dil 1) MFMA + folded norm of layer 5 + channel softmax.
// Weights from global/L1; K-loop pipelined like conv_mfma.
// ---------------------------------------------------------------------------
__global__ __launch_bounds__(BDIM) void conv2_softmax_mfma(
    const bf16* __restrict__ in, const float* __restrict__ prevStats,
    const bf16* __restrict__ wp, const float* __restrict__ bias,
    char* __restrict__ wsA)
{
    constexpr int CIN = 24, CINP = 24, COUT = 6, DIL = 1;
    constexpr int TW = TS + 2 * DIL;      // 18
    constexpr int KPP = 232, KS = 7, CSTR = 24;
    __shared__ __align__(16) bf16 tile[TW * TW * CSTR];   // 15552 B

    const int s = blockIdx.x / NBLK;
    const int blk = blockIdx.x - s * NBLK;
    const int ti = blk / NTB, tj = blk - ti * NTB;
    const int i0 = ti * TS - DIL, j0 = tj * TS - DIL;
    const int t = threadIdx.x;

    const float* ps = prevStats + s * 2 * CIN;
    for (int loc = t; loc < TW * TW; loc += BDIM) {
        const int rr = loc / TW, cc = loc - rr * TW;
        const int gi = i0 + rr, gj = j0 + cc;
        const bool ok = (gi >= 0) & (gi < H_) & (gj >= 0) & (gj < W_);
        float lv[CSTR];
#pragma unroll
        for (int c = 0; c < CSTR; ++c) lv[c] = 0.f;
        if (ok) {
            const bf16* ing = in + ((size_t)s * HW_ + (size_t)gi * W_ + gj) * CIN;
#pragma unroll
            for (int qq = 0; qq < CIN / 8; ++qq) {
                bf16x8 raw = ((const bf16x8*)ing)[qq];
#pragma unroll
                for (int u = 0; u < 8; ++u) {
                    const int ci = 8 * qq + u;
                    lv[ci] = fmaxf(((float)raw[u] - ps[2 * ci]) * ps[2 * ci + 1], 0.f);
                }
            }
        }
        bf16* lp = tile + loc * CSTR;
#pragma unroll
        for (int g = 0; g < CSTR / 4; ++g) {
            bf16x4 pk = { (bf16)lv[4 * g], (bf16)lv[4 * g + 1],
                          (bf16)lv[4 * g + 2], (bf16)lv[4 * g + 3] };
            *(bf16x4*)(lp + 4 * g) = pk;
        }
    }
    __syncthreads();

    const int wave = t >> 6, lane = t & 63, q = lane >> 4, ln = lane & 15;
    f32x4 acc[4];
#pragma unroll
    for (int mt = 0; mt < 4; ++mt) acc[mt] = (f32x4){0.f, 0.f, 0.f, 0.f};

    auto aOff = [&](int ks) -> int {
        int k0 = ks * 32 + q * 8;
        int tap = k0 / CINP;
        int ci0 = k0 - tap * CINP;
        if (tap > 8) { tap = 0; ci0 = 0; }
        const int ky = tap / 3, kx = tap - 3 * ky;
        return (ky * DIL * TW + kx * DIL) * CSTR + ci0;
    };

    bf16x8 bfr, bfrN;
    bf16x8 af[4], afN[4];
    bfr = *(const bf16x8*)&wp[ln * KPP + q * 8];
    {
        const int ao = aOff(0);
#pragma unroll
        for (int mt = 0; mt < 4; ++mt)
            af[mt] = *(const bf16x8*)&tile[((wave * 4 + mt) * TW + ln) * CSTR + ao];
    }
#pragma unroll
    for (int ks = 0; ks < KS; ++ks) {
        if (ks + 1 < KS) {
            bfrN = *(const bf16x8*)&wp[ln * KPP + (ks + 1) * 32 + q * 8];
            const int ao = aOff(ks + 1);
#pragma unroll
            for (int mt = 0; mt < 4; ++mt)
                afN[mt] = *(const bf16x8*)&tile[((wave * 4 + mt) * TW + ln) * CSTR + ao];
        }
#pragma unroll
        for (int mt = 0; mt < 4; ++mt)
            acc[mt] = __builtin_amdgcn_mfma_f32_16x16x32_bf16(af[mt], bfr, acc[mt], 0, 0, 0);
        bfr = bfrN;
#pragma unroll
        for (int mt = 0; mt < 4; ++mt) af[mt] = afN[mt];
    }

    __syncthreads();                       // done reading tile -> reuse as logits
    float* slog = (float*)tile;            // 256*6*4 = 6144 B <= 15552 B
    const float bv = (ln < COUT) ? bias[ln] : 0.f;
#pragma unroll
    for (int mt = 0; mt < 4; ++mt)
#pragma unroll
        for (int r = 0; r < 4; ++r)
            if (ln < COUT) {
                const int pl = (wave * 4 + mt) * 16 + q * 4 + r;
                slog[pl * COUT + ln] = acc[mt][r] + bv;
            }
    __syncthreads();

    float e[COUT];
    float mx = slog[t * COUT];
#pragma unroll
    for (int co = 1; co < COUT; ++co) mx = fmaxf(mx, slog[t * COUT + co]);
    float sm = 0.f;
#pragma unroll
    for (int co = 0; co < COUT; ++co) { e[co] = __expf(slog[t * COUT + co] - mx); sm += e[co]; }
    const float inv = 1.f / sm;
    bf16* f = (bf16*)(wsA + (size_t)s * SA_BYTES);
    const int prow = ti * TS + (t >> 4), pcol = tj * TS + (t & 15);
    bf16* fp = f + ((size_t)prow * W_ + pcol) * 6;
#pragma unroll
    for (int co = 0; co < COUT; ++co) fp[co] = (bf16)(e[co] * inv);
}

// ---------------------------------------------------------------------------
// Integral images of x and x^2 (fp64), nb samples.
// ---------------------------------------------------------------------------
__global__ __launch_bounds__(BDIM) void rowscan(
    const float* __restrict__ x, char* __restrict__ wsA, int nwaves)
{
    const int gwave = (int)((blockIdx.x * (size_t)BDIM + threadIdx.x) >> 6);
    if (gwave >= nwaves) return;
    const int s = gwave / IH;
    const int r = gwave - s * IH;
    const int lane = threadIdx.x & 63;
    double* r1 = (double*)(wsA + (size_t)s * SA_BYTES + OFF_II1) + (size_t)r * IW;
    double* r2 = (double*)(wsA + (size_t)s * SA_BYTES + OFF_II2) + (size_t)r * IW;
    if (r == 0) {
        for (int j = lane; j < IW; j += 64) { r1[j] = 0.0; r2[j] = 0.0; }
        return;
    }
    const float* xr = x + (size_t)s * HW_ + (size_t)(r - 1) * W_;
    if (lane == 0) { r1[0] = 0.0; r2[0] = 0.0; }
    double c1 = 0.0, c2 = 0.0;
    for (int seg = 0; seg < W_ / 64; ++seg) {
        const float xv = xr[seg * 64 + lane];
        double v1 = (double)xv, v2 = (double)xv * (double)xv;
#pragma unroll
        for (int d = 1; d < 64; d <<= 1) {
            double t1 = __shfl_up(v1, d);
            double t2 = __shfl_up(v2, d);
            if (lane >= d) { v1 += t1; v2 += t2; }
        }
        v1 += c1; v2 += c2;
        r1[seg * 64 + lane + 1] = v1;
        r2[seg * 64 + lane + 1] = v2;
        c1 = __shfl(v1, 63);
        c2 = __shfl(v2, 63);
    }
}

__global__ __launch_bounds__(BDIM) void colscan(
    char* __restrict__ wsA, int total)   // total = nb*2*IW
{
    const int t = blockIdx.x * BDIM + threadIdx.x;
    if (t >= total) return;
    const int s = t / (2 * IW);
    const int rem = t - s * (2 * IW);
    const int which = rem / IW;
    const int j = rem - which * IW;
    double* p = (double*)(wsA + (size_t)s * SA_BYTES + (which ? OFF_II2 : OFF_II1));
    double acc = p[(size_t)1 * IW + j];
    for (int i = 2; i <= H_; ++i) {
        acc += p[(size_t)i * IW + j];
        p[(size_t)i * IW + j] = acc;
    }
}

// ---------------------------------------------------------------------------
// Final: 6 Sauvola thresholds, softmax-weighted sum, out = (x - th1)*alpha
// ---------------------------------------------------------------------------
__global__ __launch_bounds__(BDIM) void sauvola_out(
    const float* __restrict__ x, const char* __restrict__ wsA,
    const float* __restrict__ kArr, const float* __restrict__ RArr,
    const float* __restrict__ alphaP, float* __restrict__ outp)
{
    const int gid = blockIdx.x * BDIM + threadIdx.x;
    const int s = gid / HW_;
    const int pix = gid - s * HW_;
    const int i = pix / W_, j = pix - i * W_;
    const float xv = x[gid];
    const bf16* fp = (const bf16*)(wsA + (size_t)s * SA_BYTES) + (size_t)pix * 6;
    const double* ii1 = (const double*)(wsA + (size_t)s * SA_BYTES + OFF_II1);
    const double* ii2 = (const double*)(wsA + (size_t)s * SA_BYTES + OFF_II2);
    const float alpha = alphaP[0];

    const int wins[6] = {3, 5, 7, 11, 15, 19};
    float th1 = 0.f;
#pragma unroll
    for (int wi = 0; wi < 6; ++wi) {
        const int r = wins[wi] >> 1;
        const int r0 = max(i - r, 0), r1i = min(i + r, H_ - 1);
        const int c0 = max(j - r, 0), c1 = min(j + r, W_ - 1);
        const float cnt = (float)((r1i - r0 + 1) * (c1 - c0 + 1));
        const double* rt1 = ii1 + (size_t)r0 * IW;
        const double* rb1 = ii1 + (size_t)(r1i + 1) * IW;
        const double* rt2 = ii2 + (size_t)r0 * IW;
        const double* rb2 = ii2 + (size_t)(r1i + 1) * IW;
        const double s1 = rb1[c1 + 1] - rt1[c1 + 1] - rb1[c0] + rt1[c0];
        const double s2 = rb2[c1 + 1] - rt2[c1 + 1] - rb2[c0] + rt2[c0];
        const float invc = 1.f / cnt;
        const float Ex = (float)s1 * invc;
        const float Ex2 = (float)s2 * invc;
        const float dev = sqrtf(fmaxf(Ex2 - Ex * Ex, 1e-6f));
        const float th = Ex * (1.f + kArr[wi] * (dev / RArr[wi] - 1.f));
        th1 = fmaf((float)fp[wi], th, th1);
    }
    outp[gid] = (xv - th1) * alpha;
}

// ---------------------------------------------------------------------------
extern "C" void kernel_launch(void* const* d_in, const int* in_sizes, int n_in,
                              void* d_out, int out_size, void* d_ws, size_t ws_size,
                              hipStream_t stream) {
    const float* x   = (const float*)d_in[0];
    const float* w0  = (const float*)d_in[1];  const float* b0 = (const float*)d_in[2];
    const float* w1  = (const float*)d_in[3];  const float* b1 = (const float*)d_in[4];
    const float* w2  = (const float*)d_in[5];  const float* b2 = (const float*)d_in[6];
    const float* w3  = (const float*)d_in[7];  const float* b3 = (const float*)d_in[8];
    const float* w4  = (const float*)d_in[9];  const float* b4 = (const float*)d_in[10];
    const float* w5  = (const float*)d_in[11]; const float* b5 = (const float*)d_in[12];
    const float* wf  = (const float*)d_in[13]; const float* bf = (const float*)d_in[14];
    const float* kA  = (const float*)d_in[15];
    const float* RA  = (const float*)d_in[16];
    const float* alp = (const float*)d_in[17];
    float* out = (float*)d_out;
    (void)n_in; (void)in_sizes; (void)out_size;

    // partials + stats live in the TAIL of d_out: each iteration writes them
    // before reading; only the final chunk's sauvola_out overwrites the tail,
    // and that happens after the last partials/stats use. Valid for nb=1/2/4.
    float* partials = out + (OUT_ELEMS - PMAX_FLOATS - 256);
    float* stats    = out + (OUT_ELEMS - 224);

    // ---- choose samples-per-launch from ws_size (deterministic) ----
    auto need = [](int nb) -> size_t {
        size_t o = 0;
        auto al = [&](size_t bytes) { o += (bytes + 255) & ~(size_t)255; };
        al((size_t)nb * HW_ * 20 * 2);          // bufA (bf16)
        al((size_t)nb * HW_ * 24 * 2);          // bufB (bf16)
        al(1664 * 2); al(1664 * 2); al(1664 * 2); al(2688 * 2);
        al(5376 * 2); al(7424 * 2); al(3712 * 2);
        return o;
    };
    int nb = 1;
    if (ws_size >= need(4)) nb = 4;
    else if (ws_size >= need(2)) nb = 2;

    char* ws = (char*)d_ws;
    size_t off = 0;
    auto alloc = [&](size_t bytes) -> void* {
        void* p = ws + off;
        off += (bytes + 255) & ~(size_t)255;
        return p;
    };
    bf16*  bufA = (bf16*)alloc((size_t)nb * HW_ * 20 * 2);
    bf16*  bufB = (bf16*)alloc((size_t)nb * HW_ * 24 * 2);
    bf16* r0 = (bf16*)alloc(1664 * 2);
    bf16* r1 = (bf16*)alloc(1664 * 2);
    bf16* r2 = (bf16*)alloc(1664 * 2);
    bf16* r3 = (bf16*)alloc(2688 * 2);
    bf16* r4 = (bf16*)alloc(5376 * 2);
    bf16* r5 = (bf16*)alloc(7424 * 2);
    bf16* rf = (bf16*)alloc(3712 * 2);
    char* wsA = (char*)bufA;   // fbuf(bf16)/ii1/ii2 carved per sample

    const dim3 blk(BDIM);
    const int cg = nb * NBLK;

    repack_all<<<7, blk, 0, stream>>>(w0, w1, w2, w3, w4, w5, wf,
                                      r0, r1, r2, r3, r4, r5, rf);

    for (int it = 0; it < B_ / nb; ++it) {
        const float* xc   = x   + (size_t)it * nb * HW_;
        float*       outc = out + (size_t)it * nb * HW_;

        conv_mfma<1, 8, 4, 1, true><<<cg, blk, 0, stream>>>(xc, nullptr, r0, b0, bufA, partials);
        reduce_stats<4><<<nb * 4, blk, 0, stream>>>(partials, stats);

        conv_mfma<4, 8, 8, 2, false><<<cg, blk, 0, stream>>>(bufA, stats, r1, b1, bufB, partials);
        reduce_stats<8><<<nb * 8, blk, 0, stream>>>(partials, stats);

        conv_mfma<8, 8, 12, 2, false><<<cg, blk, 0, stream>>>(bufB, stats, r2, b2, bufA, partials);
        reduce_stats<12><<<nb * 12, blk, 0, stream>>>(partials, stats);

        conv_mfma<12, 16, 16, 2, false><<<cg, blk, 0, stream>>>(bufA, stats, r3, b3, bufB, partials);
        reduce_stats<16><<<nb * 16, blk, 0, stream>>>(partials, stats);

        conv_mfma<16, 16, 20, 2, false><<<cg, blk, 0, stream>>>(bufB, stats, r4, b4, bufA, partials);
        reduce_stats<20><<<nb * 20, blk, 0, stream>>>(partials, stats);

        conv_mfma<20, 24, 24, 2, false><<<cg, blk, 0, stream>>>(bufA, stats, r5, b5, bufB, partials);
        reduce_stats<24><<<nb * 24, blk, 0, stream>>>(partials, stats);

        // bufA region now dead -> fbuf / ii1 / ii2 alias into it per sample
        conv2_softmax_mfma<<<cg, blk, 0, stream>>>(bufB, stats, rf, bf, wsA);

        rowscan<<<(nb * IH * 64 + BDIM - 1) / BDIM, blk, 0, stream>>>(xc, wsA, nb * IH);
        colscan<<<(nb * 2 * IW + BDIM - 1) / BDIM, blk, 0, stream>>>(wsA, nb * 2 * IW);

        sauvola_out<<<nb * HW_ / BDIM, blk, 0, stream>>>(xc, wsA, kA, RA, alp, outc);
    }
}

// Round 10
// 416.662 us; speedup vs baseline: 16.3684x; 1.1956x over previous
//
#include <hip/hip_runtime.h>
#include <math.h>

#define BDIM 256
typedef __bf16 bf16;
typedef __bf16 bf16x4 __attribute__((ext_vector_type(4)));
typedef __bf16 bf16x8 __attribute__((ext_vector_type(8)));
typedef float f32x4 __attribute__((ext_vector_type(4)));

constexpr int B_ = 4, H_ = 768, W_ = 768;
constexpr int HW_ = H_ * W_;                 // 589824
constexpr int TS = 16;                       // spatial tile 16x16 px/block
constexpr int NTB = W_ / TS;                 // 48
constexpr int NBLK = HW_ / (TS * TS);        // 2304 blocks per sample
constexpr int IH = H_ + 1, IW = W_ + 1;      // 769

// per-sample span of bufA (20ch bf16); fbuf(bf16 [HW][6]) aliases into it
// after the last conv consumes bufA.
constexpr size_t SA_BYTES = (size_t)HW_ * 20 * 2;   // 23,592,960

// scratch carved from the TAIL of d_out (written before read each iteration;
// the final sauvola of the last chunk overwrites it after last use):
constexpr int PMAX_FLOATS = 4 * NBLK * 48;          // 442368
constexpr int OUT_ELEMS   = B_ * HW_;               // 2359296

// ---------------------------------------------------------------------------
// Weight repack: [COUT][CIN][3][3] fp32 -> padded bf16 [NT*16][KPP],
// k = tap*CINP + ci, zero everywhere outside (n<COUT, tap<9, ci<CIN).
// ---------------------------------------------------------------------------
__device__ void repack_one(const float* __restrict__ src, bf16* __restrict__ dst,
                           int CIN, int CINP, int COUT, int NT16, int KPP)
{
    const int n_ = NT16 * KPP;
    for (int idx = threadIdx.x; idx < n_; idx += BDIM) {
        const int n = idx / KPP, k = idx - n * KPP;
        const int tap = k / CINP, ci = k - tap * CINP;
        float v = 0.f;
        if (n < COUT && tap < 9 && ci < CIN)
            v = src[(n * CIN + ci) * 9 + tap];
        dst[idx] = (bf16)v;
    }
}

__global__ __launch_bounds__(BDIM) void repack_all(
    const float* w0, const float* w1, const float* w2, const float* w3,
    const float* w4, const float* w5, const float* wf,
    bf16* r0, bf16* r1, bf16* r2, bf16* r3, bf16* r4, bf16* r5, bf16* rf)
{
    switch (blockIdx.x) {
        case 0: repack_one(w0, r0, 1,  8,  4,  16, 104); break;
        case 1: repack_one(w1, r1, 4,  8,  8,  16, 104); break;
        case 2: repack_one(w2, r2, 8,  8,  12, 16, 104); break;
        case 3: repack_one(w3, r3, 12, 16, 16, 16, 168); break;
        case 4: repack_one(w4, r4, 16, 16, 20, 32, 168); break;
        case 5: repack_one(w5, r5, 20, 24, 24, 32, 232); break;
        case 6: repack_one(wf, rf, 24, 24, 6,  16, 232); break;
    }
}

// ---------------------------------------------------------------------------
// bf16-MFMA conv 3x3 (dilated, SAME) + bias, NHWC, nb samples (grid=nb*NBLK).
// Halo tile staged channel-innermost bf16 (prev-layer norm+relu fused, OOB=0).
// GEMM: M=256 px, N=COUT (NT x16), K=9*CINP (KS x32). fp32 accum.
// Weights from global/L1; K-loop software-pipelined one ks ahead.
// Epilogue round-trips through LDS for contiguous per-pixel global stores.
// ---------------------------------------------------------------------------
template <int CIN, int CINP, int COUT, int DIL, bool FIRST>
__global__ __launch_bounds__(BDIM) void conv_mfma(
    const void* __restrict__ inv,        // FIRST: fp32 x; else bf16 y_prev
    const float* __restrict__ prevStats, // [nb][CIN][2] (mean, invstd)
    const bf16* __restrict__ wp,         // packed [NT*16][KPP]
    const float* __restrict__ bias,      // [COUT] fp32
    bf16* __restrict__ y,                // [nb][H][W][COUT]
    float* __restrict__ partials)        // [nb][NBLK][2*COUT]
{
    constexpr int TW = TS + 2 * DIL;
    constexpr int KP = ((9 * CINP + 31) / 32) * 32;
    constexpr int KPP = KP + 8;
    constexpr int NT = (COUT + 15) / 16;
    constexpr int KS = KP / 32;
    constexpr int CSTR = (CINP == 16) ? 24 : CINP;   // multiple of 8 (b128 align)
    __shared__ __align__(16) bf16 tile[TW * TW * CSTR];
    __shared__ float sred[4][2 * COUT];

    const int s = blockIdx.x / NBLK;
    const int blk = blockIdx.x - s * NBLK;
    const int ti = blk / NTB, tj = blk - ti * NTB;
    const int i0 = ti * TS - DIL, j0 = tj * TS - DIL;
    const int t = threadIdx.x;

    // ---- stage halo tile (vector loads, packed LDS writes) ----
    for (int loc = t; loc < TW * TW; loc += BDIM) {
        const int rr = loc / TW, cc = loc - rr * TW;
        const int gi = i0 + rr, gj = j0 + cc;
        const bool ok = (gi >= 0) & (gi < H_) & (gj >= 0) & (gj < W_);
        float lv[CSTR];
#pragma unroll
        for (int c = 0; c < CSTR; ++c) lv[c] = 0.f;
        if (ok) {
            if constexpr (FIRST) {
                const float* xg = (const float*)inv + (size_t)s * HW_;
                lv[0] = xg[(size_t)gi * W_ + gj];
            } else {
                const bf16* ing = (const bf16*)inv +
                                  ((size_t)s * HW_ + (size_t)gi * W_ + gj) * CIN;
                const float* ps = prevStats + s * 2 * CIN;
                if constexpr (CIN % 8 == 0) {
#pragma unroll
                    for (int qq = 0; qq < CIN / 8; ++qq) {
                        bf16x8 raw = ((const bf16x8*)ing)[qq];
#pragma unroll
                        for (int u = 0; u < 8; ++u) {
                            const int ci = 8 * qq + u;
                            lv[ci] = fmaxf(((float)raw[u] - ps[2 * ci]) * ps[2 * ci + 1], 0.f);
                        }
                    }
                } else {
#pragma unroll
                    for (int qq = 0; qq < CIN / 4; ++qq) {
                        bf16x4 raw = ((const bf16x4*)ing)[qq];
#pragma unroll
                        for (int u = 0; u < 4; ++u) {
                            const int ci = 4 * qq + u;
                            lv[ci] = fmaxf(((float)raw[u] - ps[2 * ci]) * ps[2 * ci + 1], 0.f);
                        }
                    }
                }
            }
        }
        bf16* lp = tile + loc * CSTR;
#pragma unroll
        for (int g = 0; g < CSTR / 4; ++g) {
            bf16x4 pk = { (bf16)lv[4 * g], (bf16)lv[4 * g + 1],
                          (bf16)lv[4 * g + 2], (bf16)lv[4 * g + 3] };
            *(bf16x4*)(lp + 4 * g) = pk;
        }
    }
    __syncthreads();

    // ---- MFMA K-loop, software-pipelined 1 ks ahead ----
    const int wave = t >> 6, lane = t & 63, q = lane >> 4, ln = lane & 15;
    f32x4 acc[4][NT];
#pragma unroll
    for (int mt = 0; mt < 4; ++mt)
#pragma unroll
        for (int u = 0; u < NT; ++u) acc[mt][u] = (f32x4){0.f, 0.f, 0.f, 0.f};

    auto aOff = [&](int ks) -> int {
        int k0 = ks * 32 + q * 8;
        int tap = k0 / CINP;
        int ci0 = k0 - tap * CINP;
        if (tap > 8) { tap = 0; ci0 = 0; }   // padded k: B rows are zero
        const int ky = tap / 3, kx = tap - 3 * ky;
        return (ky * DIL * TW + kx * DIL) * CSTR + ci0;
    };

    bf16x8 bfr[NT], bfrN[NT];
    bf16x8 af[4], afN[4];
#pragma unroll
    for (int u = 0; u < NT; ++u)
        bfr[u] = *(const bf16x8*)&wp[(u * 16 + ln) * KPP + q * 8];
    {
        const int ao = aOff(0);
#pragma unroll
        for (int mt = 0; mt < 4; ++mt)
            af[mt] = *(const bf16x8*)&tile[((wave * 4 + mt) * TW + ln) * CSTR + ao];
    }

#pragma unroll
    for (int ks = 0; ks < KS; ++ks) {
        if (ks + 1 < KS) {
#pragma unroll
            for (int u = 0; u < NT; ++u)
                bfrN[u] = *(const bf16x8*)&wp[(u * 16 + ln) * KPP + (ks + 1) * 32 + q * 8];
            const int ao = aOff(ks + 1);
#pragma unroll
            for (int mt = 0; mt < 4; ++mt)
                afN[mt] = *(const bf16x8*)&tile[((wave * 4 + mt) * TW + ln) * CSTR + ao];
        }
#pragma unroll
        for (int mt = 0; mt < 4; ++mt)
#pragma unroll
            for (int u = 0; u < NT; ++u)
                acc[mt][u] = __builtin_amdgcn_mfma_f32_16x16x32_bf16(
                    af[mt], bfr[u], acc[mt][u], 0, 0, 0);
#pragma unroll
        for (int u = 0; u < NT; ++u) bfr[u] = bfrN[u];
#pragma unroll
        for (int mt = 0; mt < 4; ++mt) af[mt] = afN[mt];
    }

    // ---- bias + stats (registers), sred ----
#pragma unroll
    for (int u = 0; u < NT; ++u) {
        const int n = u * 16 + ln;
        const float bv = (n < COUT) ? bias[n] : 0.f;
        float s1 = 0.f, s2 = 0.f;
#pragma unroll
        for (int mt = 0; mt < 4; ++mt)
#pragma unroll
            for (int r = 0; r < 4; ++r) {
                const float v = acc[mt][u][r] + bv;
                acc[mt][u][r] = v;
                s1 += v; s2 += v * v;
            }
        s1 += __shfl_xor(s1, 16); s1 += __shfl_xor(s1, 32);
        s2 += __shfl_xor(s2, 16); s2 += __shfl_xor(s2, 32);
        if (lane < 16 && n < COUT) { sred[wave][n] = s1; sred[wave][COUT + n] = s2; }
    }
    __syncthreads();   // K-loop tile reads complete + sred visible
    if (t < 2 * COUT) {
        partials[((size_t)s * NBLK + blk) * (2 * COUT) + t] =
            sred[0][t] + sred[1][t] + sred[2][t] + sred[3][t];
    }

    // ---- out-stage into LDS (reuse tile), then coalesced global stores ----
    bf16* ost = tile;   // 256*COUT bf16 <= tile capacity for all layers
#pragma unroll
    for (int u = 0; u < NT; ++u) {
        const int n = u * 16 + ln;
        if (n < COUT) {
#pragma unroll
            for (int mt = 0; mt < 4; ++mt)
#pragma unroll
                for (int r = 0; r < 4; ++r) {
                    const int pl = (wave * 4 + mt) * 16 + q * 4 + r;
                    ost[pl * COUT + n] = (bf16)acc[mt][u][r];
                }
        }
    }
    __syncthreads();

    const int lr = t >> 4, lc = t & 15;
    bf16* yp = y + (size_t)s * HW_ * COUT +
               ((size_t)(ti * TS + lr) * W_ + (tj * TS + lc)) * COUT;
    const bf16* sp = ost + t * COUT;
    if constexpr (COUT % 8 == 0) {
#pragma unroll
        for (int g = 0; g < COUT / 8; ++g)
            ((bf16x8*)yp)[g] = ((const bf16x8*)sp)[g];
    } else {
#pragma unroll
        for (int g = 0; g < COUT / 4; ++g)
            ((bf16x4*)yp)[g] = ((const bf16x4*)sp)[g];
    }
}

// ---------------------------------------------------------------------------
// Reduce per-block partials -> mean, invstd per (sample, channel)
// ---------------------------------------------------------------------------
template <int COUT>
__global__ __launch_bounds__(BDIM) void reduce_stats(
    const float* __restrict__ partials, float* __restrict__ stats)
{
    const int s = blockIdx.x / COUT;
    const int co = blockIdx.x - s * COUT;
    const float* P = partials + (size_t)s * NBLK * (2 * COUT);
    float s1 = 0.f, s2 = 0.f;
    for (int k = threadIdx.x; k < NBLK; k += BDIM) {
        const float* p = P + (size_t)k * (2 * COUT);
        s1 += p[co];
        s2 += p[COUT + co];
    }
#pragma unroll
    for (int off = 32; off; off >>= 1) {
        s1 += __shfl_xor(s1, off);
        s2 += __shfl_xor(s2, off);
    }
    __shared__ float l1[4], l2[4];
    const int lane = threadIdx.x & 63, wave = threadIdx.x >> 6;
    if (lane == 0) { l1[wave] = s1; l2[wave] = s2; }
    __syncthreads();
    if (threadIdx.x == 0) {
        float t1 = l1[0] + l1[1] + l1[2] + l1[3];
        float t2 = l2[0] + l2[1] + l2[2] + l2[3];
        float m = t1 / (float)HW_;
        float var = t2 / (float)HW_ - m * m;
        stats[((size_t)s * COUT + co) * 2 + 0] = m;
        stats[((size_t)s * COUT + co) * 2 + 1] = rsqrtf(var + 1e-5f);
    }
}

// ---------------------------------------------------------------------------
// conv2 (24->6, dil 1) MFMA + folded norm of layer 5 + channel softmax.
// Weights from global/L1; K-loop pipelined like conv_mfma.
// ---------------------------------------------------------------------------
__global__ __launch_bounds__(BDIM) void conv2_softmax_mfma(
    const bf16* __restrict__ in, const float* __restrict__ prevStats,
    const bf16* __restrict__ wp, const float* __restrict__ bias,
    char* __restrict__ wsA)
{
    constexpr int CIN = 24, CINP = 24, COUT = 6, DIL = 1;
    constexpr int TW = TS + 2 * DIL;      // 18
    constexpr int KPP = 232, KS = 7, CSTR = 24;
    __shared__ __align__(16) bf16 tile[TW * TW * CSTR];   // 15552 B

    const int s = blockIdx.x / NBLK;
    const int blk = blockIdx.x - s * NBLK;
    const int ti = blk / NTB, tj = blk - ti * NTB;
    const int i0 = ti * TS - DIL, j0 = tj * TS - DIL;
    const int t = threadIdx.x;

    const float* ps = prevStats + s * 2 * CIN;
    for (int loc = t; loc < TW * TW; loc += BDIM) {
        const int rr = loc / TW, cc = loc - rr * TW;
        const int gi = i0 + rr, gj = j0 + cc;
        const bool ok = (gi >= 0) & (gi < H_) & (gj >= 0) & (gj < W_);
        float lv[CSTR];
#pragma unroll
        for (int c = 0; c < CSTR; ++c) lv[c] = 0.f;
        if (ok) {
            const bf16* ing = in + ((size_t)s * HW_ + (size_t)gi * W_ + gj) * CIN;
#pragma unroll
            for (int qq = 0; qq < CIN / 8; ++qq) {
                bf16x8 raw = ((const bf16x8*)ing)[qq];
#pragma unroll
                for (int u = 0; u < 8; ++u) {
                    const int ci = 8 * qq + u;
                    lv[ci] = fmaxf(((float)raw[u] - ps[2 * ci]) * ps[2 * ci + 1], 0.f);
                }
            }
        }
        bf16* lp = tile + loc * CSTR;
#pragma unroll
        for (int g = 0; g < CSTR / 4; ++g) {
            bf16x4 pk = { (bf16)lv[4 * g], (bf16)lv[4 * g + 1],
                          (bf16)lv[4 * g + 2], (bf16)lv[4 * g + 3] };
            *(bf16x4*)(lp + 4 * g) = pk;
        }
    }
    __syncthreads();

    const int wave = t >> 6, lane = t & 63, q = lane >> 4, ln = lane & 15;
    f32x4 acc[4];
#pragma unroll
    for (int mt = 0; mt < 4; ++mt) acc[mt] = (f32x4){0.f, 0.f, 0.f, 0.f};

    auto aOff = [&](int ks) -> int {
        int k0 = ks * 32 + q * 8;
        int tap = k0 / CINP;
        int ci0 = k0 - tap * CINP;
        if (tap > 8) { tap = 0; ci0 = 0; }
        const int ky = tap / 3, kx = tap - 3 * ky;
        return (ky * DIL * TW + kx * DIL) * CSTR + ci0;
    };

    bf16x8 bfr, bfrN;
    bf16x8 af[4], afN[4];
    bfr = *(const bf16x8*)&wp[ln * KPP + q * 8];
    {
        const int ao = aOff(0);
#pragma unroll
        for (int mt = 0; mt < 4; ++mt)
            af[mt] = *(const bf16x8*)&tile[((wave * 4 + mt) * TW + ln) * CSTR + ao];
    }
#pragma unroll
    for (int ks = 0; ks < KS; ++ks) {
        if (ks + 1 < KS) {
            bfrN = *(const bf16x8*)&wp[ln * KPP + (ks + 1) * 32 + q * 8];
            const int ao = aOff(ks + 1);
#pragma unroll
            for (int mt = 0; mt < 4; ++mt)
                afN[mt] = *(const bf16x8*)&tile[((wave * 4 + mt) * TW + ln) * CSTR + ao];
        }
#pragma unroll
        for (int mt = 0; mt < 4; ++mt)
            acc[mt] = __builtin_amdgcn_mfma_f32_16x16x32_bf16(af[mt], bfr, acc[mt], 0, 0, 0);
        bfr = bfrN;
#pragma unroll
        for (int mt = 0; mt < 4; ++mt) af[mt] = afN[mt];
    }

    __syncthreads();                       // done reading tile -> reuse as logits
    float* slog = (float*)tile;            // 256*6*4 = 6144 B <= 15552 B
    const float bv = (ln < COUT) ? bias[ln] : 0.f;
#pragma unroll
    for (int mt = 0; mt < 4; ++mt)
#pragma unroll
        for (int r = 0; r < 4; ++r)
            if (ln < COUT) {
                const int pl = (wave * 4 + mt) * 16 + q * 4 + r;
                slog[pl * COUT + ln] = acc[mt][r] + bv;
            }
    __syncthreads();

    float e[COUT];
    float mx = slog[t * COUT];
#pragma unroll
    for (int co = 1; co < COUT; ++co) mx = fmaxf(mx, slog[t * COUT + co]);
    float sm = 0.f;
#pragma unroll
    for (int co = 0; co < COUT; ++co) { e[co] = __expf(slog[t * COUT + co] - mx); sm += e[co]; }
    const float inv = 1.f / sm;
    bf16* f = (bf16*)(wsA + (size_t)s * SA_BYTES);
    const int prow = ti * TS + (t >> 4), pcol = tj * TS + (t & 15);
    bf16* fp = f + ((size_t)prow * W_ + pcol) * 6;
#pragma unroll
    for (int co = 0; co < COUT; ++co) fp[co] = (bf16)(e[co] * inv);
}

// ---------------------------------------------------------------------------
// Fused Sauvola: per 16x16 tile, build LOCAL 35x35 fp32 integral images of x
// and x^2 in LDS (windows <= 19 => 34x34 halo suffices; OOB = 0 contributes
// nothing, counts are computed analytically from clipped bounds). Then 6
// windows x 4-corner lookups, softmax-weighted threshold, out=(x-th1)*alpha.
// Replaces the fp64 global integral images + serial colscan entirely.
// ---------------------------------------------------------------------------
__global__ __launch_bounds__(BDIM) void sauvola_fused(
    const float* __restrict__ x, const char* __restrict__ wsA,
    const float* __restrict__ kArr, const float* __restrict__ RArr,
    const float* __restrict__ alphaP, float* __restrict__ outp)
{
    constexpr int R9 = 9;                 // max radius (19>>1)
    constexpr int TSW = TS + 2 * R9;      // 34
    constexpr int PSTR = 36;              // LDS row stride (floats)
    __shared__ float I1[35 * PSTR];       // local ii of x   (35 rows)
    __shared__ float I2[35 * PSTR];       // local ii of x^2

    const int s = blockIdx.x / NBLK;
    const int blk = blockIdx.x - s * NBLK;
    const int ti = blk / NTB, tj = blk - ti * NTB;
    const int i0 = ti * TS - R9, j0 = tj * TS - R9;
    const int t = threadIdx.x;
    const float* xs = x + (size_t)s * HW_;

    // ---- stage 34x34 halo into rows/cols [1..34]; zero row 0 / col 0 ----
    for (int loc = t; loc < TSW * TSW; loc += BDIM) {
        const int rr = loc / TSW, cc = loc - rr * TSW;
        const int gi = i0 + rr, gj = j0 + cc;
        float v = 0.f;
        if ((gi >= 0) & (gi < H_) & (gj >= 0) & (gj < W_))
            v = xs[(size_t)gi * W_ + gj];
        I1[(rr + 1) * PSTR + cc + 1] = v;
        I2[(rr + 1) * PSTR + cc + 1] = v * v;
    }
    for (int idx = t; idx < 2 * (35 + 34); idx += BDIM) {
        const int arr = idx / (35 + 34);
        const int r2 = idx - arr * (35 + 34);
        float* P = arr ? I2 : I1;
        if (r2 < 35) P[r2] = 0.f;                       // row 0
        else P[(r2 - 35 + 1) * PSTR] = 0.f;             // col 0, rows 1..34
    }
    __syncthreads();

    // ---- row prefix: 34 rows x 2 arrays = 68 tasks ----
    if (t < 68) {
        float* P = (t >= 34) ? I2 : I1;
        float* row = P + ((t >= 34 ? t - 34 : t) + 1) * PSTR;
        float a = 0.f;
#pragma unroll 2
        for (int c = 1; c <= TSW; ++c) { a += row[c]; row[c] = a; }
    }
    __syncthreads();

    // ---- col prefix: 34 cols x 2 arrays = 68 tasks ----
    if (t < 68) {
        float* P = (t >= 34) ? I2 : I1;
        const int c = (t >= 34 ? t - 34 : t) + 1;
        float a = 0.f;
#pragma unroll 2
        for (int r = 1; r <= TSW; ++r) { a += P[r * PSTR + c]; P[r * PSTR + c] = a; }
    }
    __syncthreads();

    // ---- per-pixel Sauvola ----
    const int lr = t >> 4, lc = t & 15;
    const int gi = ti * TS + lr, gj = tj * TS + lc;
    const float xv = xs[(size_t)gi * W_ + gj];
    const bf16* fp = (const bf16*)(wsA + (size_t)s * SA_BYTES) +
                     ((size_t)gi * W_ + gj) * 6;
    const float alpha = alphaP[0];

    const int wins[6] = {3, 5, 7, 11, 15, 19};
    float th1 = 0.f;
#pragma unroll
    for (int wi = 0; wi < 6; ++wi) {
        const int r = wins[wi] >> 1;
        // counts from clipped global bounds (matches reference exactly)
        const int r0 = max(gi - r, 0), r1i = min(gi + r, H_ - 1);
        const int c0 = max(gj - r, 0), c1 = min(gj + r, W_ - 1);
        const float invc = 1.f / (float)((r1i - r0 + 1) * (c1 - c0 + 1));
        // sums from local ii (OOB staged as 0 -> unclipped lookups are exact)
        const int top = lr + R9 - r, bot = lr + R9 + r + 1;
        const int lef = lc + R9 - r, rig = lc + R9 + r + 1;
        const float s1 = I1[bot * PSTR + rig] - I1[top * PSTR + rig]
                       - I1[bot * PSTR + lef] + I1[top * PSTR + lef];
        const float s2 = I2[bot * PSTR + rig] - I2[top * PSTR + rig]
                       - I2[bot * PSTR + lef] + I2[top * PSTR + lef];
        const float Ex = s1 * invc;
        const float Ex2 = s2 * invc;
        const float dev = sqrtf(fmaxf(Ex2 - Ex * Ex, 1e-6f));
        const float th = Ex * (1.f + kArr[wi] * (dev / RArr[wi] - 1.f));
        th1 = fmaf((float)fp[wi], th, th1);
    }
    outp[(size_t)s * HW_ + (size_t)gi * W_ + gj] = (xv - th1) * alpha;
}

// ---------------------------------------------------------------------------
extern "C" void kernel_launch(void* const* d_in, const int* in_sizes, int n_in,
                              void* d_out, int out_size, void* d_ws, size_t ws_size,
                              hipStream_t stream) {
    const float* x   = (const float*)d_in[0];
    const float* w0  = (const float*)d_in[1];  const float* b0 = (const float*)d_in[2];
    const float* w1  = (const float*)d_in[3];  const float* b1 = (const float*)d_in[4];
    const float* w2  = (const float*)d_in[5];  const float* b2 = (const float*)d_in[6];
    const float* w3  = (const float*)d_in[7];  const float* b3 = (const float*)d_in[8];
    const float* w4  = (const float*)d_in[9];  const float* b4 = (const float*)d_in[10];
    const float* w5  = (const float*)d_in[11]; const float* b5 = (const float*)d_in[12];
    const float* wf  = (const float*)d_in[13]; const float* bf = (const float*)d_in[14];
    const float* kA  = (const float*)d_in[15];
    const float* RA  = (const float*)d_in[16];
    const float* alp = (const float*)d_in[17];
    float* out = (float*)d_out;
    (void)n_in; (void)in_sizes; (void)out_size;

    // partials + stats live in the TAIL of d_out: each iteration writes them
    // before reading; only the final chunk's sauvola_fused overwrites the
    // tail, and that happens after the last partials/stats use.
    float* partials = out + (OUT_ELEMS - PMAX_FLOATS - 256);
    float* stats    = out + (OUT_ELEMS - 224);

    // ---- choose samples-per-launch from ws_size (deterministic) ----
    auto need = [](int nb) -> size_t {
        size_t o = 0;
        auto al = [&](size_t bytes) { o += (bytes + 255) & ~(size_t)255; };
        al((size_t)nb * HW_ * 20 * 2);          // bufA (bf16)
        al((size_t)nb * HW_ * 24 * 2);          // bufB (bf16)
        al(1664 * 2); al(1664 * 2); al(1664 * 2); al(2688 * 2);
        al(5376 * 2); al(7424 * 2); al(3712 * 2);
        return o;
    };
    int nb = 1;
    if (ws_size >= need(4)) nb = 4;
    else if (ws_size >= need(2)) nb = 2;

    char* ws = (char*)d_ws;
    size_t off = 0;
    auto alloc = [&](size_t bytes) -> void* {
        void* p = ws + off;
        off += (bytes + 255) & ~(size_t)255;
        return p;
    };
    bf16*  bufA = (bf16*)alloc((size_t)nb * HW_ * 20 * 2);
    bf16*  bufB = (bf16*)alloc((size_t)nb * HW_ * 24 * 2);
    bf16* r0 = (bf16*)alloc(1664 * 2);
    bf16* r1 = (bf16*)alloc(1664 * 2);
    bf16* r2 = (bf16*)alloc(1664 * 2);
    bf16* r3 = (bf16*)alloc(2688 * 2);
    bf16* r4 = (bf16*)alloc(5376 * 2);
    bf16* r5 = (bf16*)alloc(7424 * 2);
    bf16* rf = (bf16*)alloc(3712 * 2);
    char* wsA = (char*)bufA;   // fbuf(bf16) carved per sample

    const dim3 blk(BDIM);
    const int cg = nb * NBLK;

    repack_all<<<7, blk, 0, stream>>>(w0, w1, w2, w3, w4, w5, wf,
                                      r0, r1, r2, r3, r4, r5, rf);

    for (int it = 0; it < B_ / nb; ++it) {
        const float* xc   = x   + (size_t)it * nb * HW_;
        float*       outc = out + (size_t)it * nb * HW_;

        conv_mfma<1, 8, 4, 1, true><<<cg, blk, 0, stream>>>(xc, nullptr, r0, b0, bufA, partials);
        reduce_stats<4><<<nb * 4, blk, 0, stream>>>(partials, stats);

        conv_mfma<4, 8, 8, 2, false><<<cg, blk, 0, stream>>>(bufA, stats, r1, b1, bufB, partials);
        reduce_stats<8><<<nb * 8, blk, 0, stream>>>(partials, stats);

        conv_mfma<8, 8, 12, 2, false><<<cg, blk, 0, stream>>>(bufB, stats, r2, b2, bufA, partials);
        reduce_stats<12><<<nb * 12, blk, 0, stream>>>(partials, stats);

        conv_mfma<12, 16, 16, 2, false><<<cg, blk, 0, stream>>>(bufA, stats, r3, b3, bufB, partials);
        reduce_stats<16><<<nb * 16, blk, 0, stream>>>(partials, stats);

        conv_mfma<16, 16, 20, 2, false><<<cg, blk, 0, stream>>>(bufB, stats, r4, b4, bufA, partials);
        reduce_stats<20><<<nb * 20, blk, 0, stream>>>(partials, stats);

        conv_mfma<20, 24, 24, 2, false><<<cg, blk, 0, stream>>>(bufA, stats, r5, b5, bufB, partials);
        reduce_stats<24><<<nb * 24, blk, 0, stream>>>(partials, stats);

        // bufA region now dead -> fbuf aliases into it per sample
        conv2_softmax_mfma<<<cg, blk, 0, stream>>>(bufB, stats, rf, bf, wsA);

        sauvola_fused<<<cg, blk, 0, stream>>>(xc, wsA, kA, RA, alp, outc);
    }
}